// Round 1
// baseline (1012.223 us; speedup 1.0000x reference)
//
#include <hip/hip_runtime.h>
#include <cstdint>
#include <cstddef>

// ---------------- helpers ----------------
__device__ __forceinline__ unsigned encf(float f) {
  unsigned u = __float_as_uint(f);
  return (u & 0x80000000u) ? ~u : (u | 0x80000000u);
}
__device__ __forceinline__ float decf(unsigned u) {
  return (u & 0x80000000u) ? __uint_as_float(u & 0x7FFFFFFFu) : __uint_as_float(~u);
}
__device__ __forceinline__ float lrelu02(float x) { return x > 0.f ? x : 0.2f * x; }

// ---------------- edge sort (counting sort by dst) ----------------
__global__ void zero_int_k(int* __restrict__ p, int n) {
  int i = blockIdx.x * 256 + threadIdx.x;
  if (i < n) p[i] = 0;
}

__global__ void hist_k(const int* __restrict__ ei, int E, int N, int* __restrict__ counts) {
  int i = blockIdx.x * 256 + threadIdx.x;
  int Eall = E + N;
  if (i >= Eall) return;
  int dst = (i < E) ? ei[E + i] : (i - E);
  atomicAdd(&counts[dst], 1);
}

__global__ __launch_bounds__(1024) void scan_k(const int* __restrict__ counts,
                                               int* __restrict__ offs, int N) {
  __shared__ int buf[1024];
  __shared__ int s_carry;
  int tid = threadIdx.x;
  if (tid == 0) { s_carry = 0; offs[0] = 0; }
  __syncthreads();
  for (int base = 0; base < N; base += 1024) {
    int i = base + tid;
    int v = (i < N) ? counts[i] : 0;
    buf[tid] = v;
    __syncthreads();
    for (int off = 1; off < 1024; off <<= 1) {
      int t = (tid >= off) ? buf[tid - off] : 0;
      __syncthreads();
      buf[tid] += t;
      __syncthreads();
    }
    int incl = buf[tid];
    int carry = s_carry;
    if (i < N) offs[i + 1] = carry + incl;
    __syncthreads();
    if (tid == 1023) s_carry = carry + buf[1023];
    __syncthreads();
  }
}

__global__ void copy_int_k(const int* __restrict__ a, int* __restrict__ b, int n) {
  int i = blockIdx.x * 256 + threadIdx.x;
  if (i < n) b[i] = a[i];
}

__global__ void scatter_k(const int* __restrict__ ei, int E, int N,
                          int* __restrict__ cursor, int* __restrict__ ssrc) {
  int i = blockIdx.x * 256 + threadIdx.x;
  int Eall = E + N;
  if (i >= Eall) return;
  int src, dst;
  if (i < E) { src = ei[i]; dst = ei[E + i]; }
  else       { src = i - E; dst = i - E; }
  int pos = atomicAdd(&cursor[dst], 1);
  ssrc[pos] = src;
}

// ---------------- fp32 tiled GEMM: C[M,Nc] = A[M,K] @ B[K,Nc] ----------------
#define BM 128
#define BN 64
#define BK 16
__global__ __launch_bounds__(256) void gemm_k(const float* __restrict__ A,
                                              const float* __restrict__ B,
                                              float* __restrict__ C,
                                              int M, int K, int Nc) {
  __shared__ float As[BK][BM + 4];  // transposed A tile, pitch 132 (16B-aligned rows)
  __shared__ float Bs[BK][BN + 4];  // pitch 68 (16B-aligned rows)
  const int tid = threadIdx.x;
  const int tx = tid & 15, ty = tid >> 4;
  const int row0 = blockIdx.x * BM, col0 = blockIdx.y * BN;
  float acc[8][4];
#pragma unroll
  for (int i = 0; i < 8; i++)
#pragma unroll
    for (int j = 0; j < 4; j++) acc[i][j] = 0.f;

  for (int k0 = 0; k0 < K; k0 += BK) {
    // A tile: 128x16 floats = 512 float4, 2 per thread, store transposed
#pragma unroll
    for (int i = 0; i < 2; i++) {
      int id = tid + i * 256;
      int r = id >> 2;
      int cv = (id & 3) * 4;
      int row = row0 + r;
      if (row >= M) row = M - 1;
      const float4 av = *reinterpret_cast<const float4*>(&A[(size_t)row * K + k0 + cv]);
      As[cv + 0][r] = av.x; As[cv + 1][r] = av.y;
      As[cv + 2][r] = av.z; As[cv + 3][r] = av.w;
    }
    {
      // B tile: 16x64 floats = 256 float4, 1 per thread
      int k = tid >> 4;
      int cv = (tid & 15) * 4;
      const float4 bv = *reinterpret_cast<const float4*>(&B[(size_t)(k0 + k) * Nc + col0 + cv]);
      *reinterpret_cast<float4*>(&Bs[k][cv]) = bv;
    }
    __syncthreads();
#pragma unroll
    for (int k = 0; k < BK; k++) {
      float a[8], b[4];
      const float4 a0 = *reinterpret_cast<const float4*>(&As[k][ty * 8]);
      const float4 a1 = *reinterpret_cast<const float4*>(&As[k][ty * 8 + 4]);
      a[0] = a0.x; a[1] = a0.y; a[2] = a0.z; a[3] = a0.w;
      a[4] = a1.x; a[5] = a1.y; a[6] = a1.z; a[7] = a1.w;
      const float4 b0 = *reinterpret_cast<const float4*>(&Bs[k][tx * 4]);
      b[0] = b0.x; b[1] = b0.y; b[2] = b0.z; b[3] = b0.w;
#pragma unroll
      for (int i = 0; i < 8; i++)
#pragma unroll
        for (int j = 0; j < 4; j++) acc[i][j] += a[i] * b[j];
    }
    __syncthreads();
  }
#pragma unroll
  for (int i = 0; i < 8; i++) {
    int row = row0 + ty * 8 + i;
    if (row >= M) continue;
    float4 v = make_float4(acc[i][0], acc[i][1], acc[i][2], acc[i][3]);
    *reinterpret_cast<float4*>(&C[(size_t)row * Nc + col0 + tx * 4]) = v;
  }
}

// ---------------- attention score dots ----------------
// layer 1: h [N,512] viewed as [N,4,128]; block=256 (wave per head), grid=N
__global__ __launch_bounds__(256) void attn_dots1_k(const float* __restrict__ h,
                                                    const float* __restrict__ att_s,
                                                    const float* __restrict__ att_d,
                                                    float* __restrict__ a_s,
                                                    float* __restrict__ a_d, int N) {
  int lane = threadIdx.x & 63, hh = threadIdx.x >> 6;
  int n = blockIdx.x;
  const float* row = h + (size_t)n * 512 + hh * 128;
  float v0 = row[lane], v1 = row[lane + 64];
  float ps = v0 * att_s[hh * 128 + lane] + v1 * att_s[hh * 128 + lane + 64];
  float pd = v0 * att_d[hh * 128 + lane] + v1 * att_d[hh * 128 + lane + 64];
#pragma unroll
  for (int o = 32; o; o >>= 1) { ps += __shfl_xor(ps, o); pd += __shfl_xor(pd, o); }
  if (lane == 0) { a_s[n * 4 + hh] = ps; a_d[n * 4 + hh] = pd; }
}

// layer 2: h [N,64]; block=256 (wave per node), grid=ceil(N/4)
__global__ __launch_bounds__(256) void attn_dots2_k(const float* __restrict__ h,
                                                    const float* __restrict__ att_s,
                                                    const float* __restrict__ att_d,
                                                    float* __restrict__ a_s,
                                                    float* __restrict__ a_d, int N) {
  int lane = threadIdx.x & 63, wave = threadIdx.x >> 6;
  int n = blockIdx.x * 4 + wave;
  if (n >= N) return;
  float v = h[(size_t)n * 64 + lane];
  float ps = v * att_s[lane], pd = v * att_d[lane];
#pragma unroll
  for (int o = 32; o; o >>= 1) { ps += __shfl_xor(ps, o); pd += __shfl_xor(pd, o); }
  if (lane == 0) { a_s[n] = ps; a_d[n] = pd; }
}

// ---------------- GAT layer 1 aggregation (block per dst node) ----------------
// out[n,f] = elu( sum_e alpha_e * hfeat[src_e, f] + b1[f] ),  f in [0,512)
__global__ __launch_bounds__(256) void gat_agg1_k(const float* __restrict__ hfeat,
                                                  const float* __restrict__ a_s,
                                                  const float* __restrict__ a_d,
                                                  const int* __restrict__ offs,
                                                  const int* __restrict__ ssrc,
                                                  const float* __restrict__ b1,
                                                  float* __restrict__ h1out, int N) {
  const int n = blockIdx.x;
  const int tid = threadIdx.x;
  const int lane = tid & 63, wave = tid >> 6;
  __shared__ int s_src[256];
  __shared__ float s_ex[256 * 4];
  __shared__ float s_red[16];
  __shared__ float s_m[4], s_sum[4];
  const int start = offs[n], end = offs[n + 1];
  const int len = end - start;
  float ad[4];
#pragma unroll
  for (int h = 0; h < 4; h++) ad[h] = a_d[n * 4 + h];

  // pass A: per-head segment max
  float mloc[4] = {-1e30f, -1e30f, -1e30f, -1e30f};
  for (int i = tid; i < len; i += 256) {
    int s = ssrc[start + i];
#pragma unroll
    for (int h = 0; h < 4; h++) mloc[h] = fmaxf(mloc[h], lrelu02(a_s[s * 4 + h] + ad[h]));
  }
#pragma unroll
  for (int h = 0; h < 4; h++)
#pragma unroll
    for (int o = 32; o; o >>= 1) mloc[h] = fmaxf(mloc[h], __shfl_xor(mloc[h], o));
  if (lane == 0)
#pragma unroll
    for (int h = 0; h < 4; h++) s_red[wave * 4 + h] = mloc[h];
  __syncthreads();
  if (tid < 4)
    s_m[tid] = fmaxf(fmaxf(s_red[tid], s_red[4 + tid]), fmaxf(s_red[8 + tid], s_red[12 + tid]));
  __syncthreads();
  float mm[4] = {s_m[0], s_m[1], s_m[2], s_m[3]};

  // pass B: chunked exp into LDS + register aggregation (unnormalized), then scale by 1/sum
  const int f0 = tid, f1 = tid + 256;
  const int h0 = f0 >> 7, h1 = f1 >> 7;
  float acc0 = 0.f, acc1 = 0.f;
  float sloc[4] = {0.f, 0.f, 0.f, 0.f};
  for (int base = 0; base < len; base += 256) {
    int cnt = min(256, len - base);
    if (tid < cnt) {
      int s = ssrc[start + base + tid];
      s_src[tid] = s;
#pragma unroll
      for (int h = 0; h < 4; h++) {
        float ex = __expf(lrelu02(a_s[s * 4 + h] + ad[h]) - mm[h]);
        s_ex[tid * 4 + h] = ex;
        sloc[h] += ex;
      }
    }
    __syncthreads();
    for (int j = 0; j < cnt; j++) {
      int s = s_src[j];
      acc0 += s_ex[j * 4 + h0] * hfeat[(size_t)s * 512 + f0];
      acc1 += s_ex[j * 4 + h1] * hfeat[(size_t)s * 512 + f1];
    }
    __syncthreads();
  }
#pragma unroll
  for (int h = 0; h < 4; h++)
#pragma unroll
    for (int o = 32; o; o >>= 1) sloc[h] += __shfl_xor(sloc[h], o);
  if (lane == 0)
#pragma unroll
    for (int h = 0; h < 4; h++) s_red[wave * 4 + h] = sloc[h];
  __syncthreads();
  if (tid < 4) s_sum[tid] = s_red[tid] + s_red[4 + tid] + s_red[8 + tid] + s_red[12 + tid];
  __syncthreads();
  float v0 = acc0 / (s_sum[h0] + 1e-16f) + b1[f0];
  float v1 = acc1 / (s_sum[h1] + 1e-16f) + b1[f1];
  v0 = v0 > 0.f ? v0 : (__expf(v0) - 1.f);
  v1 = v1 > 0.f ? v1 : (__expf(v1) - 1.f);
  h1out[(size_t)n * 512 + f0] = v0;
  h1out[(size_t)n * 512 + f1] = v1;
}

// ---------------- GAT layer 2 aggregation (wave per dst node) ----------------
__global__ __launch_bounds__(256) void gat_agg2_k(const float* __restrict__ h2pre,
                                                  const float* __restrict__ a_s,
                                                  const float* __restrict__ a_d,
                                                  const int* __restrict__ offs,
                                                  const int* __restrict__ ssrc,
                                                  const float* __restrict__ b2,
                                                  float* __restrict__ h2out, int N) {
  int lane = threadIdx.x & 63, wave = threadIdx.x >> 6;
  int n = blockIdx.x * 4 + wave;
  if (n >= N) return;
  int start = offs[n], end = offs[n + 1], len = end - start;
  float ad = a_d[n];
  float mloc = -1e30f;
  for (int i = lane; i < len; i += 64) {
    int s = ssrc[start + i];
    mloc = fmaxf(mloc, lrelu02(a_s[s] + ad));
  }
#pragma unroll
  for (int o = 32; o; o >>= 1) mloc = fmaxf(mloc, __shfl_xor(mloc, o));
  float acc = 0.f, ssum = 0.f;
  for (int base = 0; base < len; base += 64) {
    int i = base + lane;
    int s = 0; float ex = 0.f;
    if (i < len) {
      s = ssrc[start + i];
      ex = __expf(lrelu02(a_s[s] + ad) - mloc);
      ssum += ex;
    }
    int cnt = min(64, len - base);
    for (int j = 0; j < cnt; j++) {
      float exj = __shfl(ex, j);
      int sj = __shfl(s, j);
      acc += exj * h2pre[(size_t)sj * 64 + lane];
    }
  }
#pragma unroll
  for (int o = 32; o; o >>= 1) ssum += __shfl_xor(ssum, o);
  h2out[(size_t)n * 64 + lane] = acc / (ssum + 1e-16f) + b2[lane];
}

// ---------------- intra-attention score: tanh(h2@Wa+ba)@wv + bv ----------------
__global__ __launch_bounds__(256) void score_k(const float* __restrict__ h2,
                                               const float* __restrict__ Wa,
                                               const float* __restrict__ ba,
                                               const float* __restrict__ wv,
                                               const float* __restrict__ bv,
                                               float* __restrict__ scores, int N) {
  int lane = threadIdx.x & 63, wave = threadIdx.x >> 6;
  int n = blockIdx.x * 4 + wave;
  if (n >= N) return;
  float hv = h2[(size_t)n * 64 + lane];
  float t = ba[lane];
  for (int k = 0; k < 64; k++) {
    float hk = __shfl(hv, k);
    t += hk * Wa[k * 64 + lane];
  }
  t = tanhf(t);
  float p = t * wv[lane];
#pragma unroll
  for (int o = 32; o; o >>= 1) p += __shfl_xor(p, o);
  if (lane == 0) scores[n] = p + bv[0];
}

__global__ void red_init_k(unsigned* __restrict__ red) {
  if (threadIdx.x == 0) { red[0] = 0x007FFFFFu; /* enc(-inf) */ red[1] = 0u; }
}

__global__ void score_max_k(const float* __restrict__ scores, unsigned* __restrict__ red, int N) {
  int i = blockIdx.x * 256 + threadIdx.x;
  float m = (i < N) ? scores[i] : -1e30f;
#pragma unroll
  for (int o = 32; o; o >>= 1) m = fmaxf(m, __shfl_xor(m, o));
  if ((threadIdx.x & 63) == 0) atomicMax(&red[0], encf(m));
}

__global__ void score_sum_k(const float* __restrict__ scores, unsigned* __restrict__ red, int N) {
  float M = decf(red[0]);
  int i = blockIdx.x * 256 + threadIdx.x;
  float s = (i < N) ? __expf(scores[i] - M) : 0.f;
#pragma unroll
  for (int o = 32; o; o >>= 1) s += __shfl_xor(s, o);
  if ((threadIdx.x & 63) == 0) atomicAdd(reinterpret_cast<float*>(red) + 1, s);
}

// ---------------- normalize class_attn rows ----------------
__global__ void prep_cn_k(const float* __restrict__ ca, float* __restrict__ cn) {
  int lane = threadIdx.x & 63, c = threadIdx.x >> 6;
  float v = ca[c * 64 + lane];
  float p = v * v;
#pragma unroll
  for (int o = 32; o; o >>= 1) p += __shfl_xor(p, o);
  cn[c * 64 + lane] = v / fmaxf(sqrtf(p), 1e-12f);
}

// ---------------- finalize: xw, xn, inter, out ----------------
__global__ __launch_bounds__(256) void finalize_k(const float* __restrict__ h2,
                                                  const float* __restrict__ scores,
                                                  const unsigned* __restrict__ red,
                                                  const float* __restrict__ cn,
                                                  const float* __restrict__ Wc,
                                                  const float* __restrict__ bc,
                                                  float* __restrict__ out, int N) {
  int lane = threadIdx.x & 63, wave = threadIdx.x >> 6;
  int n = blockIdx.x * 4 + wave;
  if (n >= N) return;
  float M = decf(red[0]);
  float S = __uint_as_float(red[1]);
  float attw = __expf(scores[n] - M) / S;
  float xw = h2[(size_t)n * 64 + lane] * attw;
  float p = xw * xw;
#pragma unroll
  for (int o = 32; o; o >>= 1) p += __shfl_xor(p, o);
  float xn = xw / fmaxf(sqrtf(p), 1e-12f);
  float i0 = xn * cn[lane],       i1 = xn * cn[64 + lane];
  float i2 = xn * cn[128 + lane], i3 = xn * cn[192 + lane];
  float o0 = xw * Wc[lane * 4 + 0], o1 = xw * Wc[lane * 4 + 1];
  float o2 = xw * Wc[lane * 4 + 2], o3 = xw * Wc[lane * 4 + 3];
#pragma unroll
  for (int o = 32; o; o >>= 1) {
    i0 += __shfl_xor(i0, o); i1 += __shfl_xor(i1, o);
    i2 += __shfl_xor(i2, o); i3 += __shfl_xor(i3, o);
    o0 += __shfl_xor(o0, o); o1 += __shfl_xor(o1, o);
    o2 += __shfl_xor(o2, o); o3 += __shfl_xor(o3, o);
  }
  float* outp   = out;
  float* xwp    = out + (size_t)N * 4;
  float* interp = out + (size_t)N * 68;
  xwp[(size_t)n * 64 + lane] = xw;
  if (lane == 0) {
    outp[n * 4 + 0] = o0 + bc[0]; outp[n * 4 + 1] = o1 + bc[1];
    outp[n * 4 + 2] = o2 + bc[2]; outp[n * 4 + 3] = o3 + bc[3];
    interp[n * 4 + 0] = i0; interp[n * 4 + 1] = i1;
    interp[n * 4 + 2] = i2; interp[n * 4 + 3] = i3;
  }
}

// ---------------- launch ----------------
extern "C" void kernel_launch(void* const* d_in, const int* in_sizes, int n_in,
                              void* d_out, int out_size, void* d_ws, size_t ws_size,
                              hipStream_t stream) {
  const float* x        = (const float*)d_in[0];
  const int*   ei       = (const int*)d_in[1];
  const float* W1       = (const float*)d_in[2];
  const float* att_src1 = (const float*)d_in[3];
  const float* att_dst1 = (const float*)d_in[4];
  const float* b1       = (const float*)d_in[5];
  const float* W2       = (const float*)d_in[6];
  const float* att_src2 = (const float*)d_in[7];
  const float* att_dst2 = (const float*)d_in[8];
  const float* b2       = (const float*)d_in[9];
  const float* Wa       = (const float*)d_in[10];
  const float* ba       = (const float*)d_in[11];
  const float* wv       = (const float*)d_in[12];
  const float* bv       = (const float*)d_in[13];
  const float* class_attn = (const float*)d_in[14];
  const float* Wc       = (const float*)d_in[15];
  const float* bc       = (const float*)d_in[16];

  const int N = in_sizes[0] / 512;
  const int E = in_sizes[1] / 2;
  const int Eall = E + N;

  char* w = (char*)d_ws;
  size_t off = 0;
  auto alloc = [&](size_t bytes) -> void* {
    off = (off + 255) & ~((size_t)255);
    void* p = w + off;
    off += bytes;
    return p;
  };
  float* buf1   = (float*)alloc((size_t)N * 512 * 4);  // h (x@W1), later h2pre
  float* buf2   = (float*)alloc((size_t)N * 512 * 4);  // h1, later h2
  float* as1    = (float*)alloc((size_t)N * 4 * 4);
  float* ad1    = (float*)alloc((size_t)N * 4 * 4);
  float* as2    = (float*)alloc((size_t)N * 4);
  float* ad2    = (float*)alloc((size_t)N * 4);
  int*   counts = (int*)alloc((size_t)N * 4);
  int*   offs   = (int*)alloc((size_t)(N + 1) * 4);
  int*   cursor = (int*)alloc((size_t)N * 4);
  int*   ssrc   = (int*)alloc((size_t)Eall * 4);
  float* scores = (float*)alloc((size_t)N * 4);
  unsigned* red = (unsigned*)alloc(64);
  float* cn     = (float*)alloc(256 * 4);

  const int gN256  = (N + 255) / 256;
  const int gE256  = (Eall + 255) / 256;
  const int gNode4 = (N + 3) / 4;
  const int gM     = (N + BM - 1) / BM;

  // --- build CSR (sorted-by-dst edge list), reused by both layers ---
  zero_int_k<<<gN256, 256, 0, stream>>>(counts, N);
  hist_k<<<gE256, 256, 0, stream>>>(ei, E, N, counts);
  scan_k<<<1, 1024, 0, stream>>>(counts, offs, N);
  copy_int_k<<<gN256, 256, 0, stream>>>(offs, cursor, N);
  scatter_k<<<gE256, 256, 0, stream>>>(ei, E, N, cursor, ssrc);

  // --- layer 1 ---
  gemm_k<<<dim3(gM, 512 / BN), 256, 0, stream>>>(x, W1, buf1, N, 512, 512);
  attn_dots1_k<<<N, 256, 0, stream>>>(buf1, att_src1, att_dst1, as1, ad1, N);
  gat_agg1_k<<<N, 256, 0, stream>>>(buf1, as1, ad1, offs, ssrc, b1, buf2, N);

  // --- layer 2 ---
  gemm_k<<<dim3(gM, 1), 256, 0, stream>>>(buf2, W2, buf1, N, 512, 64);
  attn_dots2_k<<<gNode4, 256, 0, stream>>>(buf1, att_src2, att_dst2, as2, ad2, N);
  gat_agg2_k<<<gNode4, 256, 0, stream>>>(buf1, as2, ad2, offs, ssrc, b2, buf2, N);

  // --- intra attention + heads ---
  score_k<<<gNode4, 256, 0, stream>>>(buf2, Wa, ba, wv, bv, scores, N);
  red_init_k<<<1, 64, 0, stream>>>(red);
  score_max_k<<<gN256, 256, 0, stream>>>(scores, red, N);
  score_sum_k<<<gN256, 256, 0, stream>>>(scores, red, N);
  prep_cn_k<<<1, 256, 0, stream>>>(class_attn, cn);
  finalize_k<<<gNode4, 256, 0, stream>>>(buf2, scores, red, cn, Wc, bc,
                                         (float*)d_out, N);
}

// Round 2
// 723.274 us; speedup vs baseline: 1.3995x; 1.3995x over previous
//
#include <hip/hip_runtime.h>
#include <cstdint>
#include <cstddef>

// ---------------- helpers ----------------
typedef __attribute__((ext_vector_type(8))) short bf16x8;
typedef __attribute__((ext_vector_type(4))) float f32x4;
typedef __attribute__((ext_vector_type(8))) unsigned short u16x8;

__device__ __forceinline__ unsigned encf(float f) {
  unsigned u = __float_as_uint(f);
  return (u & 0x80000000u) ? ~u : (u | 0x80000000u);
}
__device__ __forceinline__ float decf(unsigned u) {
  return (u & 0x80000000u) ? __uint_as_float(u & 0x7FFFFFFFu) : __uint_as_float(~u);
}
__device__ __forceinline__ float lrelu02(float x) { return x > 0.f ? x : 0.2f * x; }
__device__ __forceinline__ unsigned short f2bf(float f) {
  unsigned u = __float_as_uint(f);
  unsigned r = u + 0x7FFFu + ((u >> 16) & 1u);  // RNE
  return (unsigned short)(r >> 16);
}
__device__ __forceinline__ float bf2f(unsigned short b) {
  return __uint_as_float(((unsigned)b) << 16);
}

__device__ __forceinline__ void gll16(const void* g, void* l) {
  __builtin_amdgcn_global_load_lds(
      (const __attribute__((address_space(1))) void*)g,
      (__attribute__((address_space(3))) void*)l, 16, 0, 0);
}

// ---------------- edge sort (counting sort by dst) ----------------
__global__ void zero_int_k(int* __restrict__ p, int n) {
  int i = blockIdx.x * 256 + threadIdx.x;
  if (i < n) p[i] = 0;
}

__global__ void hist_k(const int* __restrict__ ei, int E, int N, int* __restrict__ counts) {
  int i = blockIdx.x * 256 + threadIdx.x;
  int Eall = E + N;
  if (i >= Eall) return;
  int dst = (i < E) ? ei[E + i] : (i - E);
  atomicAdd(&counts[dst], 1);
}

__global__ __launch_bounds__(1024) void scan_k(const int* __restrict__ counts,
                                               int* __restrict__ offs, int N) {
  __shared__ int buf[1024];
  __shared__ int s_carry;
  int tid = threadIdx.x;
  if (tid == 0) { s_carry = 0; offs[0] = 0; }
  __syncthreads();
  for (int base = 0; base < N; base += 1024) {
    int i = base + tid;
    int v = (i < N) ? counts[i] : 0;
    buf[tid] = v;
    __syncthreads();
    for (int off = 1; off < 1024; off <<= 1) {
      int t = (tid >= off) ? buf[tid - off] : 0;
      __syncthreads();
      buf[tid] += t;
      __syncthreads();
    }
    int incl = buf[tid];
    int carry = s_carry;
    if (i < N) offs[i + 1] = carry + incl;
    __syncthreads();
    if (tid == 1023) s_carry = carry + buf[1023];
    __syncthreads();
  }
}

__global__ void copy_int_k(const int* __restrict__ a, int* __restrict__ b, int n) {
  int i = blockIdx.x * 256 + threadIdx.x;
  if (i < n) b[i] = a[i];
}

__global__ void scatter_k(const int* __restrict__ ei, int E, int N,
                          int* __restrict__ cursor, int* __restrict__ ssrc) {
  int i = blockIdx.x * 256 + threadIdx.x;
  int Eall = E + N;
  if (i >= Eall) return;
  int src, dst;
  if (i < E) { src = ei[i]; dst = ei[E + i]; }
  else       { src = i - E; dst = i - E; }
  int pos = atomicAdd(&cursor[dst], 1);
  ssrc[pos] = src;
}

// ---------------- bf16 conversion kernels ----------------
// x [N,512] fp32 -> xb [Mpad,512] bf16 (pad rows zeroed)
__global__ void conv_x_k(const float* __restrict__ x, unsigned short* __restrict__ xb,
                         int N, int Mpad) {
  int i = blockIdx.x * 256 + threadIdx.x;  // octet index (8 elems each)
  int total = Mpad * 64;                   // 512/8 = 64 octets per row
  if (i >= total) return;
  int row = i >> 6;
  u16x8 v;
  if (row < N) {
    const float4* src = (const float4*)(x + (size_t)i * 8);
    float4 a = src[0], b = src[1];
    v[0] = f2bf(a.x); v[1] = f2bf(a.y); v[2] = f2bf(a.z); v[3] = f2bf(a.w);
    v[4] = f2bf(b.x); v[5] = f2bf(b.y); v[6] = f2bf(b.z); v[7] = f2bf(b.w);
  } else {
    v = (u16x8)0;
  }
  *(u16x8*)(xb + (size_t)i * 8) = v;
}

// W [K,Nc] fp32 -> Wt [Nc,K] bf16
__global__ void conv_wt_k(const float* __restrict__ W, unsigned short* __restrict__ Wt,
                          int K, int Nc) {
  int i = blockIdx.x * 256 + threadIdx.x;
  if (i >= K * Nc) return;
  int c = i / K, k = i - c * K;
  Wt[i] = f2bf(W[(size_t)k * Nc + c]);
}

// ---------------- bf16 MFMA GEMM: C[M,Nc] = A[M,K] @ Bt[Nc,K]^T ----------------
// m97 structure: BMxBN tile, BK=64, linear LDS, global_load_lds w=16, 2-barrier loop.
// 4 waves in 2x2; wave tile (BM/2)x(BN/2); 16x16x32 bf16 MFMA.
template <int BM, int BN>
__global__ __launch_bounds__(256) void mfma_gemm_k(const unsigned short* __restrict__ A,
                                                   const unsigned short* __restrict__ Bt,
                                                   float* __restrict__ C,
                                                   int M, int K, int Nc) {
  constexpr int BK = 64;
  constexpr int MR = BM / 32;
  constexpr int NR = BN / 32;
  __shared__ unsigned short As[BM][BK];
  __shared__ unsigned short Bs[BN][BK];
  const int tid = threadIdx.x;
  const int lane = tid & 63;
  const int w = tid >> 6;
  const int wr = w >> 1, wc = w & 1;
  const int l16 = lane & 15, lk = lane >> 4;
  const int row0 = blockIdx.x * BM, col0 = blockIdx.y * BN;

  f32x4 acc[MR][NR];
#pragma unroll
  for (int m = 0; m < MR; m++)
#pragma unroll
    for (int n = 0; n < NR; n++) acc[m][n] = (f32x4)0.f;

  const char* Abase = (const char*)A;
  const char* Bbase = (const char*)Bt;

  for (int k0 = 0; k0 < K; k0 += BK) {
    // stage A tile: BM rows x 64 bf16 (128 B/row), 16B chunks, linear LDS
#pragma unroll
    for (int i = 0; i < BM / 32; i++) {
      int ca = i * 256 + tid;
      int r = ca >> 3, b = (ca & 7) * 16;
      gll16(Abase + ((size_t)(row0 + r) * K + k0) * 2 + b, (char*)&As[0][0] + ca * 16);
    }
#pragma unroll
    for (int i = 0; i < BN / 32; i++) {
      int cb = i * 256 + tid;
      int c = cb >> 3, b = (cb & 7) * 16;
      gll16(Bbase + ((size_t)(col0 + c) * K + k0) * 2 + b, (char*)&Bs[0][0] + cb * 16);
    }
    __syncthreads();
#pragma unroll
    for (int ks = 0; ks < 2; ks++) {
      bf16x8 af[MR], bfr[NR];
#pragma unroll
      for (int m = 0; m < MR; m++)
        af[m] = *(const bf16x8*)&As[wr * (BM / 2) + m * 16 + l16][ks * 32 + lk * 8];
#pragma unroll
      for (int n = 0; n < NR; n++)
        bfr[n] = *(const bf16x8*)&Bs[wc * (BN / 2) + n * 16 + l16][ks * 32 + lk * 8];
#pragma unroll
      for (int m = 0; m < MR; m++)
#pragma unroll
        for (int n = 0; n < NR; n++)
          acc[m][n] = __builtin_amdgcn_mfma_f32_16x16x32_bf16(af[m], bfr[n], acc[m][n], 0, 0, 0);
    }
    __syncthreads();
  }
  // epilogue: C/D layout col=lane&15, row=(lane>>4)*4+reg
#pragma unroll
  for (int m = 0; m < MR; m++) {
    int row_b = row0 + wr * (BM / 2) + m * 16 + lk * 4;
#pragma unroll
    for (int r = 0; r < 4; r++) {
      int row = row_b + r;
      if (row < M) {
#pragma unroll
        for (int n = 0; n < NR; n++) {
          int col = col0 + wc * (BN / 2) + n * 16 + l16;
          C[(size_t)row * Nc + col] = acc[m][n][r];
        }
      }
    }
  }
}

// ---------------- attention score dots ----------------
__global__ __launch_bounds__(256) void attn_dots1_k(const float* __restrict__ h,
                                                    const float* __restrict__ att_s,
                                                    const float* __restrict__ att_d,
                                                    float* __restrict__ a_s,
                                                    float* __restrict__ a_d, int N) {
  int lane = threadIdx.x & 63, hh = threadIdx.x >> 6;
  int n = blockIdx.x;
  const float* row = h + (size_t)n * 512 + hh * 128;
  float v0 = row[lane], v1 = row[lane + 64];
  float ps = v0 * att_s[hh * 128 + lane] + v1 * att_s[hh * 128 + lane + 64];
  float pd = v0 * att_d[hh * 128 + lane] + v1 * att_d[hh * 128 + lane + 64];
#pragma unroll
  for (int o = 32; o; o >>= 1) { ps += __shfl_xor(ps, o); pd += __shfl_xor(pd, o); }
  if (lane == 0) { a_s[n * 4 + hh] = ps; a_d[n * 4 + hh] = pd; }
}

__global__ __launch_bounds__(256) void attn_dots2_k(const float* __restrict__ h,
                                                    const float* __restrict__ att_s,
                                                    const float* __restrict__ att_d,
                                                    float* __restrict__ a_s,
                                                    float* __restrict__ a_d, int N) {
  int lane = threadIdx.x & 63, wave = threadIdx.x >> 6;
  int n = blockIdx.x * 4 + wave;
  if (n >= N) return;
  float v = h[(size_t)n * 64 + lane];
  float ps = v * att_s[lane], pd = v * att_d[lane];
#pragma unroll
  for (int o = 32; o; o >>= 1) { ps += __shfl_xor(ps, o); pd += __shfl_xor(pd, o); }
  if (lane == 0) { a_s[n] = ps; a_d[n] = pd; }
}

// ---------------- GAT layer 1 aggregation (block per dst node) ----------------
// out bf16 [Mpad,512]: elu( sum_e alpha_e * hfeat[src_e, f] + b1[f] )
__global__ __launch_bounds__(256) void gat_agg1_k(const float* __restrict__ hfeat,
                                                  const float* __restrict__ a_s,
                                                  const float* __restrict__ a_d,
                                                  const int* __restrict__ offs,
                                                  const int* __restrict__ ssrc,
                                                  const float* __restrict__ b1,
                                                  unsigned short* __restrict__ h1b, int N) {
  const int n = blockIdx.x;
  const int tid = threadIdx.x;
  const int lane = tid & 63, wave = tid >> 6;
  __shared__ int s_src[256];
  __shared__ float s_ex[256 * 4];
  __shared__ float s_red[16];
  __shared__ float s_m[4], s_sum[4];
  const int start = offs[n], end = offs[n + 1];
  const int len = end - start;
  float ad[4];
#pragma unroll
  for (int h = 0; h < 4; h++) ad[h] = a_d[n * 4 + h];

  float mloc[4] = {-1e30f, -1e30f, -1e30f, -1e30f};
  for (int i = tid; i < len; i += 256) {
    int s = ssrc[start + i];
#pragma unroll
    for (int h = 0; h < 4; h++) mloc[h] = fmaxf(mloc[h], lrelu02(a_s[s * 4 + h] + ad[h]));
  }
#pragma unroll
  for (int h = 0; h < 4; h++)
#pragma unroll
    for (int o = 32; o; o >>= 1) mloc[h] = fmaxf(mloc[h], __shfl_xor(mloc[h], o));
  if (lane == 0)
#pragma unroll
    for (int h = 0; h < 4; h++) s_red[wave * 4 + h] = mloc[h];
  __syncthreads();
  if (tid < 4)
    s_m[tid] = fmaxf(fmaxf(s_red[tid], s_red[4 + tid]), fmaxf(s_red[8 + tid], s_red[12 + tid]));
  __syncthreads();
  float mm[4] = {s_m[0], s_m[1], s_m[2], s_m[3]};

  const int f0 = tid, f1 = tid + 256;
  const int h0 = f0 >> 7, h1 = f1 >> 7;
  float acc0 = 0.f, acc1 = 0.f;
  float sloc[4] = {0.f, 0.f, 0.f, 0.f};
  for (int base = 0; base < len; base += 256) {
    int cnt = min(256, len - base);
    if (tid < cnt) {
      int s = ssrc[start + base + tid];
      s_src[tid] = s;
#pragma unroll
      for (int h = 0; h < 4; h++) {
        float ex = __expf(lrelu02(a_s[s * 4 + h] + ad[h]) - mm[h]);
        s_ex[tid * 4 + h] = ex;
        sloc[h] += ex;
      }
    }
    __syncthreads();
    for (int j = 0; j < cnt; j++) {
      int s = s_src[j];
      acc0 += s_ex[j * 4 + h0] * hfeat[(size_t)s * 512 + f0];
      acc1 += s_ex[j * 4 + h1] * hfeat[(size_t)s * 512 + f1];
    }
    __syncthreads();
  }
#pragma unroll
  for (int h = 0; h < 4; h++)
#pragma unroll
    for (int o = 32; o; o >>= 1) sloc[h] += __shfl_xor(sloc[h], o);
  if (lane == 0)
#pragma unroll
    for (int h = 0; h < 4; h++) s_red[wave * 4 + h] = sloc[h];
  __syncthreads();
  if (tid < 4) s_sum[tid] = s_red[tid] + s_red[4 + tid] + s_red[8 + tid] + s_red[12 + tid];
  __syncthreads();
  float v0 = acc0 / (s_sum[h0] + 1e-16f) + b1[f0];
  float v1 = acc1 / (s_sum[h1] + 1e-16f) + b1[f1];
  v0 = v0 > 0.f ? v0 : (__expf(v0) - 1.f);
  v1 = v1 > 0.f ? v1 : (__expf(v1) - 1.f);
  h1b[(size_t)n * 512 + f0] = f2bf(v0);
  h1b[(size_t)n * 512 + f1] = f2bf(v1);
}

// ---------------- GAT layer 2 aggregation (wave per dst node) ----------------
__global__ __launch_bounds__(256) void gat_agg2_k(const float* __restrict__ h2pre,
                                                  const float* __restrict__ a_s,
                                                  const float* __restrict__ a_d,
                                                  const int* __restrict__ offs,
                                                  const int* __restrict__ ssrc,
                                                  const float* __restrict__ b2,
                                                  float* __restrict__ h2out, int N) {
  int lane = threadIdx.x & 63, wave = threadIdx.x >> 6;
  int n = blockIdx.x * 4 + wave;
  if (n >= N) return;
  int start = offs[n], end = offs[n + 1], len = end - start;
  float ad = a_d[n];
  float mloc = -1e30f;
  for (int i = lane; i < len; i += 64) {
    int s = ssrc[start + i];
    mloc = fmaxf(mloc, lrelu02(a_s[s] + ad));
  }
#pragma unroll
  for (int o = 32; o; o >>= 1) mloc = fmaxf(mloc, __shfl_xor(mloc, o));
  float acc = 0.f, ssum = 0.f;
  for (int base = 0; base < len; base += 64) {
    int i = base + lane;
    int s = 0; float ex = 0.f;
    if (i < len) {
      s = ssrc[start + i];
      ex = __expf(lrelu02(a_s[s] + ad) - mloc);
      ssum += ex;
    }
    int cnt = min(64, len - base);
    for (int j = 0; j < cnt; j++) {
      float exj = __shfl(ex, j);
      int sj = __shfl(s, j);
      acc += exj * h2pre[(size_t)sj * 64 + lane];
    }
  }
#pragma unroll
  for (int o = 32; o; o >>= 1) ssum += __shfl_xor(ssum, o);
  h2out[(size_t)n * 64 + lane] = acc / (ssum + 1e-16f) + b2[lane];
}

// ---------------- intra-attention score ----------------
__global__ __launch_bounds__(256) void score_k(const float* __restrict__ h2,
                                               const float* __restrict__ Wa,
                                               const float* __restrict__ ba,
                                               const float* __restrict__ wv,
                                               const float* __restrict__ bv,
                                               float* __restrict__ scores, int N) {
  int lane = threadIdx.x & 63, wave = threadIdx.x >> 6;
  int n = blockIdx.x * 4 + wave;
  if (n >= N) return;
  float hv = h2[(size_t)n * 64 + lane];
  float t = ba[lane];
  for (int k = 0; k < 64; k++) {
    float hk = __shfl(hv, k);
    t += hk * Wa[k * 64 + lane];
  }
  t = tanhf(t);
  float p = t * wv[lane];
#pragma unroll
  for (int o = 32; o; o >>= 1) p += __shfl_xor(p, o);
  if (lane == 0) scores[n] = p + bv[0];
}

__global__ void red_init_k(unsigned* __restrict__ red) {
  if (threadIdx.x == 0) { red[0] = 0x007FFFFFu; red[1] = 0u; }
}

__global__ void score_max_k(const float* __restrict__ scores, unsigned* __restrict__ red, int N) {
  int i = blockIdx.x * 256 + threadIdx.x;
  float m = (i < N) ? scores[i] : -1e30f;
#pragma unroll
  for (int o = 32; o; o >>= 1) m = fmaxf(m, __shfl_xor(m, o));
  if ((threadIdx.x & 63) == 0) atomicMax(&red[0], encf(m));
}

__global__ void score_sum_k(const float* __restrict__ scores, unsigned* __restrict__ red, int N) {
  float M = decf(red[0]);
  int i = blockIdx.x * 256 + threadIdx.x;
  float s = (i < N) ? __expf(scores[i] - M) : 0.f;
#pragma unroll
  for (int o = 32; o; o >>= 1) s += __shfl_xor(s, o);
  if ((threadIdx.x & 63) == 0) atomicAdd(reinterpret_cast<float*>(red) + 1, s);
}

__global__ void prep_cn_k(const float* __restrict__ ca, float* __restrict__ cn) {
  int lane = threadIdx.x & 63, c = threadIdx.x >> 6;
  float v = ca[c * 64 + lane];
  float p = v * v;
#pragma unroll
  for (int o = 32; o; o >>= 1) p += __shfl_xor(p, o);
  cn[c * 64 + lane] = v / fmaxf(sqrtf(p), 1e-12f);
}

__global__ __launch_bounds__(256) void finalize_k(const float* __restrict__ h2,
                                                  const float* __restrict__ scores,
                                                  const unsigned* __restrict__ red,
                                                  const float* __restrict__ cn,
                                                  const float* __restrict__ Wc,
                                                  const float* __restrict__ bc,
                                                  float* __restrict__ out, int N) {
  int lane = threadIdx.x & 63, wave = threadIdx.x >> 6;
  int n = blockIdx.x * 4 + wave;
  if (n >= N) return;
  float M = decf(red[0]);
  float S = __uint_as_float(red[1]);
  float attw = __expf(scores[n] - M) / S;
  float xw = h2[(size_t)n * 64 + lane] * attw;
  float p = xw * xw;
#pragma unroll
  for (int o = 32; o; o >>= 1) p += __shfl_xor(p, o);
  float xn = xw / fmaxf(sqrtf(p), 1e-12f);
  float i0 = xn * cn[lane],       i1 = xn * cn[64 + lane];
  float i2 = xn * cn[128 + lane], i3 = xn * cn[192 + lane];
  float o0 = xw * Wc[lane * 4 + 0], o1 = xw * Wc[lane * 4 + 1];
  float o2 = xw * Wc[lane * 4 + 2], o3 = xw * Wc[lane * 4 + 3];
#pragma unroll
  for (int o = 32; o; o >>= 1) {
    i0 += __shfl_xor(i0, o); i1 += __shfl_xor(i1, o);
    i2 += __shfl_xor(i2, o); i3 += __shfl_xor(i3, o);
    o0 += __shfl_xor(o0, o); o1 += __shfl_xor(o1, o);
    o2 += __shfl_xor(o2, o); o3 += __shfl_xor(o3, o);
  }
  float* outp   = out;
  float* xwp    = out + (size_t)N * 4;
  float* interp = out + (size_t)N * 68;
  xwp[(size_t)n * 64 + lane] = xw;
  if (lane == 0) {
    outp[n * 4 + 0] = o0 + bc[0]; outp[n * 4 + 1] = o1 + bc[1];
    outp[n * 4 + 2] = o2 + bc[2]; outp[n * 4 + 3] = o3 + bc[3];
    interp[n * 4 + 0] = i0; interp[n * 4 + 1] = i1;
    interp[n * 4 + 2] = i2; interp[n * 4 + 3] = i3;
  }
}

// ---------------- launch ----------------
extern "C" void kernel_launch(void* const* d_in, const int* in_sizes, int n_in,
                              void* d_out, int out_size, void* d_ws, size_t ws_size,
                              hipStream_t stream) {
  const float* x        = (const float*)d_in[0];
  const int*   ei       = (const int*)d_in[1];
  const float* W1       = (const float*)d_in[2];
  const float* att_src1 = (const float*)d_in[3];
  const float* att_dst1 = (const float*)d_in[4];
  const float* b1       = (const float*)d_in[5];
  const float* W2       = (const float*)d_in[6];
  const float* att_src2 = (const float*)d_in[7];
  const float* att_dst2 = (const float*)d_in[8];
  const float* b2       = (const float*)d_in[9];
  const float* Wa       = (const float*)d_in[10];
  const float* ba       = (const float*)d_in[11];
  const float* wv       = (const float*)d_in[12];
  const float* bv       = (const float*)d_in[13];
  const float* class_attn = (const float*)d_in[14];
  const float* Wc       = (const float*)d_in[15];
  const float* bc       = (const float*)d_in[16];

  const int N = in_sizes[0] / 512;
  const int E = in_sizes[1] / 2;
  const int Eall = E + N;
  const int Mpad = ((N + 127) / 128) * 128;

  char* w = (char*)d_ws;
  size_t off = 0;
  auto alloc = [&](size_t bytes) -> void* {
    off = (off + 255) & ~((size_t)255);
    void* p = w + off;
    off += bytes;
    return p;
  };
  float* buf1 = (float*)alloc((size_t)N * 512 * 4);          // h fp32, later h2pre fp32
  unsigned short* xb = (unsigned short*)alloc((size_t)Mpad * 512 * 2);  // xb, later h1b (aliased)
  unsigned short* h1b = xb;
  float* buf2   = (float*)alloc((size_t)N * 64 * 4);         // h2
  unsigned short* W1t = (unsigned short*)alloc((size_t)512 * 512 * 2);
  unsigned short* W2t = (unsigned short*)alloc((size_t)64 * 512 * 2);
  float* as1    = (float*)alloc((size_t)N * 4 * 4);
  float* ad1    = (float*)alloc((size_t)N * 4 * 4);
  float* as2    = (float*)alloc((size_t)N * 4);
  float* ad2    = (float*)alloc((size_t)N * 4);
  int*   counts = (int*)alloc((size_t)N * 4);
  int*   offs   = (int*)alloc((size_t)(N + 1) * 4);
  int*   cursor = (int*)alloc((size_t)N * 4);
  int*   ssrc   = (int*)alloc((size_t)Eall * 4);
  float* scores = (float*)alloc((size_t)N * 4);
  unsigned* red = (unsigned*)alloc(64);
  float* cn     = (float*)alloc(256 * 4);

  const int gN256  = (N + 255) / 256;
  const int gE256  = (Eall + 255) / 256;
  const int gNode4 = (N + 3) / 4;

  // --- build CSR (sorted-by-dst edge list), reused by both layers ---
  zero_int_k<<<gN256, 256, 0, stream>>>(counts, N);
  hist_k<<<gE256, 256, 0, stream>>>(ei, E, N, counts);
  scan_k<<<1, 1024, 0, stream>>>(counts, offs, N);
  copy_int_k<<<gN256, 256, 0, stream>>>(offs, cursor, N);
  scatter_k<<<gE256, 256, 0, stream>>>(ei, E, N, cursor, ssrc);

  // --- bf16 conversions ---
  conv_x_k<<<(Mpad * 64 + 255) / 256, 256, 0, stream>>>(x, xb, N, Mpad);
  conv_wt_k<<<(512 * 512 + 255) / 256, 256, 0, stream>>>(W1, W1t, 512, 512);
  conv_wt_k<<<(64 * 512 + 255) / 256, 256, 0, stream>>>(W2, W2t, 512, 64);

  // --- layer 1 ---
  mfma_gemm_k<128, 128><<<dim3(Mpad / 128, 4), 256, 0, stream>>>(xb, W1t, buf1, N, 512, 512);
  attn_dots1_k<<<N, 256, 0, stream>>>(buf1, att_src1, att_dst1, as1, ad1, N);
  gat_agg1_k<<<N, 256, 0, stream>>>(buf1, as1, ad1, offs, ssrc, b1, h1b, N);

  // --- layer 2 ---
  mfma_gemm_k<64, 64><<<dim3(Mpad / 64, 1), 256, 0, stream>>>(h1b, W2t, buf1, N, 512, 64);
  attn_dots2_k<<<gNode4, 256, 0, stream>>>(buf1, att_src2, att_dst2, as2, ad2, N);
  gat_agg2_k<<<gNode4, 256, 0, stream>>>(buf1, as2, ad2, offs, ssrc, b2, buf2, N);

  // --- intra attention + heads ---
  score_k<<<gNode4, 256, 0, stream>>>(buf2, Wa, ba, wv, bv, scores, N);
  red_init_k<<<1, 64, 0, stream>>>(red);
  score_max_k<<<gN256, 256, 0, stream>>>(scores, red, N);
  score_sum_k<<<gN256, 256, 0, stream>>>(scores, red, N);
  prep_cn_k<<<1, 256, 0, stream>>>(class_attn, cn);
  finalize_k<<<gNode4, 256, 0, stream>>>(buf2, scores, red, cn, Wc, bc,
                                         (float*)d_out, N);
}

// Round 3
// 634.506 us; speedup vs baseline: 1.5953x; 1.1399x over previous
//
#include <hip/hip_runtime.h>
#include <cstdint>
#include <cstddef>

// ---------------- helpers ----------------
typedef __attribute__((ext_vector_type(8))) short bf16x8;
typedef __attribute__((ext_vector_type(4))) float f32x4;
typedef __attribute__((ext_vector_type(8))) unsigned short u16x8;

__device__ __forceinline__ unsigned encf(float f) {
  unsigned u = __float_as_uint(f);
  return (u & 0x80000000u) ? ~u : (u | 0x80000000u);
}
__device__ __forceinline__ float decf(unsigned u) {
  return (u & 0x80000000u) ? __uint_as_float(u & 0x7FFFFFFFu) : __uint_as_float(~u);
}
__device__ __forceinline__ float lrelu02(float x) { return x > 0.f ? x : 0.2f * x; }
__device__ __forceinline__ unsigned short f2bf(float f) {
  unsigned u = __float_as_uint(f);
  unsigned r = u + 0x7FFFu + ((u >> 16) & 1u);  // RNE
  return (unsigned short)(r >> 16);
}
__device__ __forceinline__ float bf2f(unsigned short b) {
  return __uint_as_float(((unsigned)b) << 16);
}

__device__ __forceinline__ void gll16(const void* g, void* l) {
  __builtin_amdgcn_global_load_lds(
      (const __attribute__((address_space(1))) void*)g,
      (__attribute__((address_space(3))) void*)l, 16, 0, 0);
}

// ---------------- edge sort (counting sort by dst) ----------------
__global__ void zero_int_k(int* __restrict__ p, int n) {
  int i = blockIdx.x * 256 + threadIdx.x;
  if (i < n) p[i] = 0;
}

__global__ void hist_k(const int* __restrict__ ei, int E, int N, int* __restrict__ counts) {
  int i = blockIdx.x * 256 + threadIdx.x;
  int Eall = E + N;
  if (i >= Eall) return;
  int dst = (i < E) ? ei[E + i] : (i - E);
  atomicAdd(&counts[dst], 1);
}

__global__ __launch_bounds__(1024) void scan_k(const int* __restrict__ counts,
                                               int* __restrict__ offs, int N) {
  __shared__ int buf[1024];
  __shared__ int s_carry;
  int tid = threadIdx.x;
  if (tid == 0) { s_carry = 0; offs[0] = 0; }
  __syncthreads();
  for (int base = 0; base < N; base += 1024) {
    int i = base + tid;
    int v = (i < N) ? counts[i] : 0;
    buf[tid] = v;
    __syncthreads();
    for (int off = 1; off < 1024; off <<= 1) {
      int t = (tid >= off) ? buf[tid - off] : 0;
      __syncthreads();
      buf[tid] += t;
      __syncthreads();
    }
    int incl = buf[tid];
    int carry = s_carry;
    if (i < N) offs[i + 1] = carry + incl;
    __syncthreads();
    if (tid == 1023) s_carry = carry + buf[1023];
    __syncthreads();
  }
}

__global__ void copy_int_k(const int* __restrict__ a, int* __restrict__ b, int n) {
  int i = blockIdx.x * 256 + threadIdx.x;
  if (i < n) b[i] = a[i];
}

__global__ void scatter_k(const int* __restrict__ ei, int E, int N,
                          int* __restrict__ cursor, int* __restrict__ ssrc) {
  int i = blockIdx.x * 256 + threadIdx.x;
  int Eall = E + N;
  if (i >= Eall) return;
  int src, dst;
  if (i < E) { src = ei[i]; dst = ei[E + i]; }
  else       { src = i - E; dst = i - E; }
  int pos = atomicAdd(&cursor[dst], 1);
  ssrc[pos] = src;
}

// ---------------- bf16 conversion kernels ----------------
__global__ void conv_x_k(const float* __restrict__ x, unsigned short* __restrict__ xb,
                         int N, int Mpad) {
  int i = blockIdx.x * 256 + threadIdx.x;  // octet index (8 elems each)
  int total = Mpad * 64;
  if (i >= total) return;
  int row = i >> 6;
  u16x8 v;
  if (row < N) {
    const float4* src = (const float4*)(x + (size_t)i * 8);
    float4 a = src[0], b = src[1];
    v[0] = f2bf(a.x); v[1] = f2bf(a.y); v[2] = f2bf(a.z); v[3] = f2bf(a.w);
    v[4] = f2bf(b.x); v[5] = f2bf(b.y); v[6] = f2bf(b.z); v[7] = f2bf(b.w);
  } else {
    v = (u16x8)0;
  }
  *(u16x8*)(xb + (size_t)i * 8) = v;
}

__global__ void conv_wt_k(const float* __restrict__ W, unsigned short* __restrict__ Wt,
                          int K, int Nc) {
  int i = blockIdx.x * 256 + threadIdx.x;
  if (i >= K * Nc) return;
  int c = i / K, k = i - c * K;
  Wt[i] = f2bf(W[(size_t)k * Nc + c]);
}

// ---------------- bf16 MFMA GEMM: C[M,Nc] = A[M,K] @ Bt[Nc,K]^T ----------------
// OBF: write C as bf16 instead of fp32.
template <int BM, int BN, bool OBF>
__global__ __launch_bounds__(256) void mfma_gemm_k(const unsigned short* __restrict__ A,
                                                   const unsigned short* __restrict__ Bt,
                                                   void* __restrict__ Cv,
                                                   int M, int K, int Nc) {
  constexpr int BK = 64;
  constexpr int MR = BM / 32;
  constexpr int NR = BN / 32;
  __shared__ unsigned short As[BM][BK];
  __shared__ unsigned short Bs[BN][BK];
  const int tid = threadIdx.x;
  const int lane = tid & 63;
  const int w = tid >> 6;
  const int wr = w >> 1, wc = w & 1;
  const int l16 = lane & 15, lk = lane >> 4;
  const int row0 = blockIdx.x * BM, col0 = blockIdx.y * BN;

  f32x4 acc[MR][NR];
#pragma unroll
  for (int m = 0; m < MR; m++)
#pragma unroll
    for (int n = 0; n < NR; n++) acc[m][n] = (f32x4)0.f;

  const char* Abase = (const char*)A;
  const char* Bbase = (const char*)Bt;

  for (int k0 = 0; k0 < K; k0 += BK) {
#pragma unroll
    for (int i = 0; i < BM / 32; i++) {
      int ca = i * 256 + tid;
      int r = ca >> 3, b = (ca & 7) * 16;
      gll16(Abase + ((size_t)(row0 + r) * K + k0) * 2 + b, (char*)&As[0][0] + ca * 16);
    }
#pragma unroll
    for (int i = 0; i < BN / 32; i++) {
      int cb = i * 256 + tid;
      int c = cb >> 3, b = (cb & 7) * 16;
      gll16(Bbase + ((size_t)(col0 + c) * K + k0) * 2 + b, (char*)&Bs[0][0] + cb * 16);
    }
    __syncthreads();
#pragma unroll
    for (int ks = 0; ks < 2; ks++) {
      bf16x8 af[MR], bfr[NR];
#pragma unroll
      for (int m = 0; m < MR; m++)
        af[m] = *(const bf16x8*)&As[wr * (BM / 2) + m * 16 + l16][ks * 32 + lk * 8];
#pragma unroll
      for (int n = 0; n < NR; n++)
        bfr[n] = *(const bf16x8*)&Bs[wc * (BN / 2) + n * 16 + l16][ks * 32 + lk * 8];
#pragma unroll
      for (int m = 0; m < MR; m++)
#pragma unroll
        for (int n = 0; n < NR; n++)
          acc[m][n] = __builtin_amdgcn_mfma_f32_16x16x32_bf16(af[m], bfr[n], acc[m][n], 0, 0, 0);
    }
    __syncthreads();
  }
  // epilogue: C/D layout col=lane&15, row=(lane>>4)*4+reg
#pragma unroll
  for (int m = 0; m < MR; m++) {
    int row_b = row0 + wr * (BM / 2) + m * 16 + lk * 4;
#pragma unroll
    for (int r = 0; r < 4; r++) {
      int row = row_b + r;
      if (row < M) {
#pragma unroll
        for (int n = 0; n < NR; n++) {
          int col = col0 + wc * (BN / 2) + n * 16 + l16;
          if (OBF)
            ((unsigned short*)Cv)[(size_t)row * Nc + col] = f2bf(acc[m][n][r]);
          else
            ((float*)Cv)[(size_t)row * Nc + col] = acc[m][n][r];
        }
      }
    }
  }
}

// ---------------- attention score dots ----------------
// layer 1: h bf16 [N,512] viewed as [N,4,128]; wave per head, grid=N
__global__ __launch_bounds__(256) void attn_dots1_k(const unsigned short* __restrict__ h,
                                                    const float* __restrict__ att_s,
                                                    const float* __restrict__ att_d,
                                                    float* __restrict__ a_s,
                                                    float* __restrict__ a_d, int N) {
  int lane = threadIdx.x & 63, hh = threadIdx.x >> 6;
  int n = blockIdx.x;
  const unsigned short* row = h + (size_t)n * 512 + hh * 128;
  unsigned pk = *(const unsigned*)(row + 2 * lane);
  float v0 = bf2f((unsigned short)(pk & 0xFFFFu));
  float v1 = bf2f((unsigned short)(pk >> 16));
  int f = hh * 128 + 2 * lane;
  float ps = v0 * att_s[f] + v1 * att_s[f + 1];
  float pd = v0 * att_d[f] + v1 * att_d[f + 1];
#pragma unroll
  for (int o = 32; o; o >>= 1) { ps += __shfl_xor(ps, o); pd += __shfl_xor(pd, o); }
  if (lane == 0) { a_s[n * 4 + hh] = ps; a_d[n * 4 + hh] = pd; }
}

__global__ __launch_bounds__(256) void attn_dots2_k(const float* __restrict__ h,
                                                    const float* __restrict__ att_s,
                                                    const float* __restrict__ att_d,
                                                    float* __restrict__ a_s,
                                                    float* __restrict__ a_d, int N) {
  int lane = threadIdx.x & 63, wave = threadIdx.x >> 6;
  int n = blockIdx.x * 4 + wave;
  if (n >= N) return;
  float v = h[(size_t)n * 64 + lane];
  float ps = v * att_s[lane], pd = v * att_d[lane];
#pragma unroll
  for (int o = 32; o; o >>= 1) { ps += __shfl_xor(ps, o); pd += __shfl_xor(pd, o); }
  if (lane == 0) { a_s[n] = ps; a_d[n] = pd; }
}

// ---------------- GAT layer 1 aggregation (block per dst node) ----------------
// hfeat bf16 [N,512]; thread t handles features {2t, 2t+1} (same head).
// out bf16 [Mpad,512]: elu( sum_e alpha_e * hfeat[src_e, f] + b1[f] )
__global__ __launch_bounds__(256) void gat_agg1_k(const unsigned short* __restrict__ hfeat,
                                                  const float* __restrict__ a_s,
                                                  const float* __restrict__ a_d,
                                                  const int* __restrict__ offs,
                                                  const int* __restrict__ ssrc,
                                                  const float* __restrict__ b1,
                                                  unsigned short* __restrict__ h1b, int N) {
  const int n = blockIdx.x;
  const int tid = threadIdx.x;
  const int lane = tid & 63, wave = tid >> 6;
  __shared__ int s_src[256];
  __shared__ float s_ex[256 * 4];
  __shared__ float s_red[16];
  __shared__ float s_m[4], s_sum[4];
  const int start = offs[n], end = offs[n + 1];
  const int len = end - start;
  float ad[4];
#pragma unroll
  for (int h = 0; h < 4; h++) ad[h] = a_d[n * 4 + h];

  float mloc[4] = {-1e30f, -1e30f, -1e30f, -1e30f};
  for (int i = tid; i < len; i += 256) {
    int s = ssrc[start + i];
#pragma unroll
    for (int h = 0; h < 4; h++) mloc[h] = fmaxf(mloc[h], lrelu02(a_s[s * 4 + h] + ad[h]));
  }
#pragma unroll
  for (int h = 0; h < 4; h++)
#pragma unroll
    for (int o = 32; o; o >>= 1) mloc[h] = fmaxf(mloc[h], __shfl_xor(mloc[h], o));
  if (lane == 0)
#pragma unroll
    for (int h = 0; h < 4; h++) s_red[wave * 4 + h] = mloc[h];
  __syncthreads();
  if (tid < 4)
    s_m[tid] = fmaxf(fmaxf(s_red[tid], s_red[4 + tid]), fmaxf(s_red[8 + tid], s_red[12 + tid]));
  __syncthreads();
  float mm[4] = {s_m[0], s_m[1], s_m[2], s_m[3]};

  // features 2*tid, 2*tid+1 — both in head tid>>6 (= wave index)
  const int f0 = 2 * tid, f1 = 2 * tid + 1;
  const int hh = tid >> 6;  // == wave
  float acc0 = 0.f, acc1 = 0.f;
  float sloc[4] = {0.f, 0.f, 0.f, 0.f};
  for (int base = 0; base < len; base += 256) {
    int cnt = min(256, len - base);
    if (tid < cnt) {
      int s = ssrc[start + base + tid];
      s_src[tid] = s;
#pragma unroll
      for (int h = 0; h < 4; h++) {
        float ex = __expf(lrelu02(a_s[s * 4 + h] + ad[h]) - mm[h]);
        s_ex[tid * 4 + h] = ex;
        sloc[h] += ex;
      }
    }
    __syncthreads();
    for (int j = 0; j < cnt; j++) {
      int s = s_src[j];
      float ex = s_ex[j * 4 + hh];  // wave-uniform -> LDS broadcast
      unsigned pk = *(const unsigned*)(hfeat + (size_t)s * 512 + f0);
      acc0 += ex * bf2f((unsigned short)(pk & 0xFFFFu));
      acc1 += ex * bf2f((unsigned short)(pk >> 16));
    }
    __syncthreads();
  }
#pragma unroll
  for (int h = 0; h < 4; h++)
#pragma unroll
    for (int o = 32; o; o >>= 1) sloc[h] += __shfl_xor(sloc[h], o);
  if (lane == 0)
#pragma unroll
    for (int h = 0; h < 4; h++) s_red[wave * 4 + h] = sloc[h];
  __syncthreads();
  if (tid < 4) s_sum[tid] = s_red[tid] + s_red[4 + tid] + s_red[8 + tid] + s_red[12 + tid];
  __syncthreads();
  float inv = 1.f / (s_sum[hh] + 1e-16f);
  float v0 = acc0 * inv + b1[f0];
  float v1 = acc1 * inv + b1[f1];
  v0 = v0 > 0.f ? v0 : (__expf(v0) - 1.f);
  v1 = v1 > 0.f ? v1 : (__expf(v1) - 1.f);
  unsigned out = (unsigned)f2bf(v0) | ((unsigned)f2bf(v1) << 16);
  *(unsigned*)(h1b + (size_t)n * 512 + f0) = out;
}

// ---------------- GAT layer 2 aggregation (wave per dst node) ----------------
__global__ __launch_bounds__(256) void gat_agg2_k(const float* __restrict__ h2pre,
                                                  const float* __restrict__ a_s,
                                                  const float* __restrict__ a_d,
                                                  const int* __restrict__ offs,
                                                  const int* __restrict__ ssrc,
                                                  const float* __restrict__ b2,
                                                  float* __restrict__ h2out, int N) {
  int lane = threadIdx.x & 63, wave = threadIdx.x >> 6;
  int n = blockIdx.x * 4 + wave;
  if (n >= N) return;
  int start = offs[n], end = offs[n + 1], len = end - start;
  float ad = a_d[n];
  float mloc = -1e30f;
  for (int i = lane; i < len; i += 64) {
    int s = ssrc[start + i];
    mloc = fmaxf(mloc, lrelu02(a_s[s] + ad));
  }
#pragma unroll
  for (int o = 32; o; o >>= 1) mloc = fmaxf(mloc, __shfl_xor(mloc, o));
  float acc = 0.f, ssum = 0.f;
  for (int base = 0; base < len; base += 64) {
    int i = base + lane;
    int s = 0; float ex = 0.f;
    if (i < len) {
      s = ssrc[start + i];
      ex = __expf(lrelu02(a_s[s] + ad) - mloc);
      ssum += ex;
    }
    int cnt = min(64, len - base);
    for (int j = 0; j < cnt; j++) {
      float exj = __shfl(ex, j);
      int sj = __shfl(s, j);
      acc += exj * h2pre[(size_t)sj * 64 + lane];
    }
  }
#pragma unroll
  for (int o = 32; o; o >>= 1) ssum += __shfl_xor(ssum, o);
  h2out[(size_t)n * 64 + lane] = acc / (ssum + 1e-16f) + b2[lane];
}

// ---------------- intra-attention score ----------------
__global__ __launch_bounds__(256) void score_k(const float* __restrict__ h2,
                                               const float* __restrict__ Wa,
                                               const float* __restrict__ ba,
                                               const float* __restrict__ wv,
                                               const float* __restrict__ bv,
                                               float* __restrict__ scores, int N) {
  int lane = threadIdx.x & 63, wave = threadIdx.x >> 6;
  int n = blockIdx.x * 4 + wave;
  if (n >= N) return;
  float hv = h2[(size_t)n * 64 + lane];
  float t = ba[lane];
  for (int k = 0; k < 64; k++) {
    float hk = __shfl(hv, k);
    t += hk * Wa[k * 64 + lane];
  }
  t = tanhf(t);
  float p = t * wv[lane];
#pragma unroll
  for (int o = 32; o; o >>= 1) p += __shfl_xor(p, o);
  if (lane == 0) scores[n] = p + bv[0];
}

__global__ void red_init_k(unsigned* __restrict__ red) {
  if (threadIdx.x == 0) { red[0] = 0x007FFFFFu; red[1] = 0u; }
}

__global__ void score_max_k(const float* __restrict__ scores, unsigned* __restrict__ red, int N) {
  int i = blockIdx.x * 256 + threadIdx.x;
  float m = (i < N) ? scores[i] : -1e30f;
#pragma unroll
  for (int o = 32; o; o >>= 1) m = fmaxf(m, __shfl_xor(m, o));
  if ((threadIdx.x & 63) == 0) atomicMax(&red[0], encf(m));
}

__global__ void score_sum_k(const float* __restrict__ scores, unsigned* __restrict__ red, int N) {
  float M = decf(red[0]);
  int i = blockIdx.x * 256 + threadIdx.x;
  float s = (i < N) ? __expf(scores[i] - M) : 0.f;
#pragma unroll
  for (int o = 32; o; o >>= 1) s += __shfl_xor(s, o);
  if ((threadIdx.x & 63) == 0) atomicAdd(reinterpret_cast<float*>(red) + 1, s);
}

__global__ void prep_cn_k(const float* __restrict__ ca, float* __restrict__ cn) {
  int lane = threadIdx.x & 63, c = threadIdx.x >> 6;
  float v = ca[c * 64 + lane];
  float p = v * v;
#pragma unroll
  for (int o = 32; o; o >>= 1) p += __shfl_xor(p, o);
  cn[c * 64 + lane] = v / fmaxf(sqrtf(p), 1e-12f);
}

__global__ __launch_bounds__(256) void finalize_k(const float* __restrict__ h2,
                                                  const float* __restrict__ scores,
                                                  const unsigned* __restrict__ red,
                                                  const float* __restrict__ cn,
                                                  const float* __restrict__ Wc,
                                                  const float* __restrict__ bc,
                                                  float* __restrict__ out, int N) {
  int lane = threadIdx.x & 63, wave = threadIdx.x >> 6;
  int n = blockIdx.x * 4 + wave;
  if (n >= N) return;
  float M = decf(red[0]);
  float S = __uint_as_float(red[1]);
  float attw = __expf(scores[n] - M) / S;
  float xw = h2[(size_t)n * 64 + lane] * attw;
  float p = xw * xw;
#pragma unroll
  for (int o = 32; o; o >>= 1) p += __shfl_xor(p, o);
  float xn = xw / fmaxf(sqrtf(p), 1e-12f);
  float i0 = xn * cn[lane],       i1 = xn * cn[64 + lane];
  float i2 = xn * cn[128 + lane], i3 = xn * cn[192 + lane];
  float o0 = xw * Wc[lane * 4 + 0], o1 = xw * Wc[lane * 4 + 1];
  float o2 = xw * Wc[lane * 4 + 2], o3 = xw * Wc[lane * 4 + 3];
#pragma unroll
  for (int o = 32; o; o >>= 1) {
    i0 += __shfl_xor(i0, o); i1 += __shfl_xor(i1, o);
    i2 += __shfl_xor(i2, o); i3 += __shfl_xor(i3, o);
    o0 += __shfl_xor(o0, o); o1 += __shfl_xor(o1, o);
    o2 += __shfl_xor(o2, o); o3 += __shfl_xor(o3, o);
  }
  float* outp   = out;
  float* xwp    = out + (size_t)N * 4;
  float* interp = out + (size_t)N * 68;
  xwp[(size_t)n * 64 + lane] = xw;
  if (lane == 0) {
    outp[n * 4 + 0] = o0 + bc[0]; outp[n * 4 + 1] = o1 + bc[1];
    outp[n * 4 + 2] = o2 + bc[2]; outp[n * 4 + 3] = o3 + bc[3];
    interp[n * 4 + 0] = i0; interp[n * 4 + 1] = i1;
    interp[n * 4 + 2] = i2; interp[n * 4 + 3] = i3;
  }
}

// ---------------- launch ----------------
extern "C" void kernel_launch(void* const* d_in, const int* in_sizes, int n_in,
                              void* d_out, int out_size, void* d_ws, size_t ws_size,
                              hipStream_t stream) {
  const float* x        = (const float*)d_in[0];
  const int*   ei       = (const int*)d_in[1];
  const float* W1       = (const float*)d_in[2];
  const float* att_src1 = (const float*)d_in[3];
  const float* att_dst1 = (const float*)d_in[4];
  const float* b1       = (const float*)d_in[5];
  const float* W2       = (const float*)d_in[6];
  const float* att_src2 = (const float*)d_in[7];
  const float* att_dst2 = (const float*)d_in[8];
  const float* b2       = (const float*)d_in[9];
  const float* Wa       = (const float*)d_in[10];
  const float* ba       = (const float*)d_in[11];
  const float* wv       = (const float*)d_in[12];
  const float* bv       = (const float*)d_in[13];
  const float* class_attn = (const float*)d_in[14];
  const float* Wc       = (const float*)d_in[15];
  const float* bc       = (const float*)d_in[16];

  const int N = in_sizes[0] / 512;
  const int E = in_sizes[1] / 2;
  const int Eall = E + N;
  const int Mpad = ((N + 127) / 128) * 128;

  char* w = (char*)d_ws;
  size_t off = 0;
  auto alloc = [&](size_t bytes) -> void* {
    off = (off + 255) & ~((size_t)255);
    void* p = w + off;
    off += bytes;
    return p;
  };
  unsigned short* xb  = (unsigned short*)alloc((size_t)Mpad * 512 * 2);  // xb, later h1b (aliased)
  unsigned short* h1b = xb;
  unsigned short* hb  = (unsigned short*)alloc((size_t)N * 512 * 2);     // h = x@W1, bf16
  float* h2pre  = (float*)alloc((size_t)N * 64 * 4);
  float* h2     = (float*)alloc((size_t)N * 64 * 4);
  unsigned short* W1t = (unsigned short*)alloc((size_t)512 * 512 * 2);
  unsigned short* W2t = (unsigned short*)alloc((size_t)64 * 512 * 2);
  float* as1    = (float*)alloc((size_t)N * 4 * 4);
  float* ad1    = (float*)alloc((size_t)N * 4 * 4);
  float* as2    = (float*)alloc((size_t)N * 4);
  float* ad2    = (float*)alloc((size_t)N * 4);
  int*   counts = (int*)alloc((size_t)N * 4);
  int*   offs   = (int*)alloc((size_t)(N + 1) * 4);
  int*   cursor = (int*)alloc((size_t)N * 4);
  int*   ssrc   = (int*)alloc((size_t)Eall * 4);
  float* scores = (float*)alloc((size_t)N * 4);
  unsigned* red = (unsigned*)alloc(64);
  float* cn     = (float*)alloc(256 * 4);

  const int gN256  = (N + 255) / 256;
  const int gE256  = (Eall + 255) / 256;
  const int gNode4 = (N + 3) / 4;

  // --- build CSR (sorted-by-dst edge list), reused by both layers ---
  zero_int_k<<<gN256, 256, 0, stream>>>(counts, N);
  hist_k<<<gE256, 256, 0, stream>>>(ei, E, N, counts);
  scan_k<<<1, 1024, 0, stream>>>(counts, offs, N);
  copy_int_k<<<gN256, 256, 0, stream>>>(offs, cursor, N);
  scatter_k<<<gE256, 256, 0, stream>>>(ei, E, N, cursor, ssrc);

  // --- bf16 conversions ---
  conv_x_k<<<(Mpad * 64 + 255) / 256, 256, 0, stream>>>(x, xb, N, Mpad);
  conv_wt_k<<<(512 * 512 + 255) / 256, 256, 0, stream>>>(W1, W1t, 512, 512);
  conv_wt_k<<<(64 * 512 + 255) / 256, 256, 0, stream>>>(W2, W2t, 512, 64);

  // --- layer 1 (h kept in bf16) ---
  mfma_gemm_k<128, 128, true><<<dim3(Mpad / 128, 4), 256, 0, stream>>>(xb, W1t, hb, N, 512, 512);
  attn_dots1_k<<<N, 256, 0, stream>>>(hb, att_src1, att_dst1, as1, ad1, N);
  gat_agg1_k<<<N, 256, 0, stream>>>(hb, as1, ad1, offs, ssrc, b1, h1b, N);

  // --- layer 2 ---
  mfma_gemm_k<64, 64, false><<<dim3(Mpad / 64, 1), 256, 0, stream>>>(h1b, W2t, h2pre, N, 512, 64);
  attn_dots2_k<<<gNode4, 256, 0, stream>>>(h2pre, att_src2, att_dst2, as2, ad2, N);
  gat_agg2_k<<<gNode4, 256, 0, stream>>>(h2pre, as2, ad2, offs, ssrc, b2, h2, N);

  // --- intra attention + heads ---
  score_k<<<gNode4, 256, 0, stream>>>(h2, Wa, ba, wv, bv, scores, N);
  red_init_k<<<1, 64, 0, stream>>>(red);
  score_max_k<<<gN256, 256, 0, stream>>>(scores, red, N);
  score_sum_k<<<gN256, 256, 0, stream>>>(scores, red, N);
  prep_cn_k<<<1, 256, 0, stream>>>(class_attn, cn);
  finalize_k<<<gNode4, 256, 0, stream>>>(h2, scores, red, cn, Wc, bc,
                                         (float*)d_out, N);
}

// Round 4
// 564.340 us; speedup vs baseline: 1.7936x; 1.1243x over previous
//
#include <hip/hip_runtime.h>
#include <cstdint>
#include <cstddef>

// ---------------- helpers ----------------
typedef __attribute__((ext_vector_type(8))) short bf16x8;
typedef __attribute__((ext_vector_type(4))) float f32x4;
typedef __attribute__((ext_vector_type(8))) unsigned short u16x8;

__device__ __forceinline__ unsigned encf(float f) {
  unsigned u = __float_as_uint(f);
  return (u & 0x80000000u) ? ~u : (u | 0x80000000u);
}
__device__ __forceinline__ float decf(unsigned u) {
  return (u & 0x80000000u) ? __uint_as_float(u & 0x7FFFFFFFu) : __uint_as_float(~u);
}
__device__ __forceinline__ float lrelu02(float x) { return x > 0.f ? x : 0.2f * x; }
__device__ __forceinline__ unsigned short f2bf(float f) {
  unsigned u = __float_as_uint(f);
  unsigned r = u + 0x7FFFu + ((u >> 16) & 1u);  // RNE
  return (unsigned short)(r >> 16);
}
__device__ __forceinline__ float bf2f(unsigned short b) {
  return __uint_as_float(((unsigned)b) << 16);
}

__device__ __forceinline__ void gll16(const void* g, void* l) {
  __builtin_amdgcn_global_load_lds(
      (const __attribute__((address_space(1))) void*)g,
      (__attribute__((address_space(3))) void*)l, 16, 0, 0);
}

// ---------------- edge sort (counting sort by dst) ----------------
__global__ void zero_int_k(int* __restrict__ p, int n) {
  int i = blockIdx.x * 256 + threadIdx.x;
  if (i < n) p[i] = 0;
}

__global__ void hist_k(const int* __restrict__ ei, int E, int N, int* __restrict__ counts) {
  int i = blockIdx.x * 256 + threadIdx.x;
  int Eall = E + N;
  if (i >= Eall) return;
  int dst = (i < E) ? ei[E + i] : (i - E);
  atomicAdd(&counts[dst], 1);
}

// 3-phase parallel scan: per-256-chunk inclusive scan + chunk sums
__global__ __launch_bounds__(256) void scan1_k(const int* __restrict__ counts,
                                               int* __restrict__ incl,
                                               int* __restrict__ bsum, int N) {
  int b = blockIdx.x, tid = threadIdx.x;
  int lane = tid & 63, wv = tid >> 6;
  int i = b * 256 + tid;
  int v = (i < N) ? counts[i] : 0;
#pragma unroll
  for (int o = 1; o < 64; o <<= 1) {
    int t = __shfl_up(v, o, 64);
    if (lane >= o) v += t;
  }
  __shared__ int wsum[4];
  if (lane == 63) wsum[wv] = v;
  __syncthreads();
  int base = 0;
  for (int wj = 0; wj < wv; wj++) base += wsum[wj];
  v += base;
  if (i < N) incl[i] = v;
  if (tid == 255) bsum[b] = v;
}

// scan chunk sums (nb <= 256) -> exclusive prefix pb
__global__ __launch_bounds__(256) void scan2_k(const int* __restrict__ bsum,
                                               int* __restrict__ pb, int nb) {
  int tid = threadIdx.x;
  int lane = tid & 63, wv = tid >> 6;
  int v = (tid < nb) ? bsum[tid] : 0;
  int orig = v;
#pragma unroll
  for (int o = 1; o < 64; o <<= 1) {
    int t = __shfl_up(v, o, 64);
    if (lane >= o) v += t;
  }
  __shared__ int wsum[4];
  if (lane == 63) wsum[wv] = v;
  __syncthreads();
  int base = 0;
  for (int wj = 0; wj < wv; wj++) base += wsum[wj];
  if (tid < nb) pb[tid] = v + base - orig;
}

// offs[i+1] = incl[i] + pb[chunk]; offs[0]=0; cursor = offs (fused copy)
__global__ void scan3_k(const int* __restrict__ incl, const int* __restrict__ pb,
                        int* __restrict__ offs, int* __restrict__ cursor, int N) {
  int i = blockIdx.x * 256 + threadIdx.x;
  if (i == 0) { offs[0] = 0; cursor[0] = 0; }
  if (i < N) {
    int v = incl[i] + pb[i >> 8];
    offs[i + 1] = v;
    if (i + 1 < N) cursor[i + 1] = v;
  }
}

__global__ void scatter_k(const int* __restrict__ ei, int E, int N,
                          int* __restrict__ cursor, int* __restrict__ ssrc) {
  int i = blockIdx.x * 256 + threadIdx.x;
  int Eall = E + N;
  if (i >= Eall) return;
  int src, dst;
  if (i < E) { src = ei[i]; dst = ei[E + i]; }
  else       { src = i - E; dst = i - E; }
  int pos = atomicAdd(&cursor[dst], 1);
  ssrc[pos] = src;
}

// ---------------- bf16 conversion kernels ----------------
__global__ void conv_x_k(const float* __restrict__ x, unsigned short* __restrict__ xb,
                         int N, int Mpad) {
  int i = blockIdx.x * 256 + threadIdx.x;  // octet index (8 elems each)
  int total = Mpad * 64;
  if (i >= total) return;
  int row = i >> 6;
  u16x8 v;
  if (row < N) {
    const float4* src = (const float4*)(x + (size_t)i * 8);
    float4 a = src[0], b = src[1];
    v[0] = f2bf(a.x); v[1] = f2bf(a.y); v[2] = f2bf(a.z); v[3] = f2bf(a.w);
    v[4] = f2bf(b.x); v[5] = f2bf(b.y); v[6] = f2bf(b.z); v[7] = f2bf(b.w);
  } else {
    v = (u16x8)0;
  }
  *(u16x8*)(xb + (size_t)i * 8) = v;
}

__global__ void conv_wt_k(const float* __restrict__ W, unsigned short* __restrict__ Wt,
                          int K, int Nc) {
  int i = blockIdx.x * 256 + threadIdx.x;
  if (i >= K * Nc) return;
  int c = i / K, k = i - c * K;
  Wt[i] = f2bf(W[(size_t)k * Nc + c]);
}

// ---------------- bf16 MFMA GEMM: C[M,Nc] = A[M,K] @ Bt[Nc,K]^T ----------------
// OBF: write C as bf16. DOTS: fused per-row att dots (requires BN=128, grid.y=head).
template <int BM, int BN, bool OBF, bool DOTS>
__global__ __launch_bounds__(256) void mfma_gemm_k(const unsigned short* __restrict__ A,
                                                   const unsigned short* __restrict__ Bt,
                                                   void* __restrict__ Cv,
                                                   const float* __restrict__ att_s,
                                                   const float* __restrict__ att_d,
                                                   float* __restrict__ as_out,
                                                   float* __restrict__ ad_out,
                                                   int M, int K, int Nc) {
  constexpr int BK = 64;
  constexpr int MR = BM / 32;
  constexpr int NR = BN / 32;
  __shared__ unsigned short As[BM][BK];
  __shared__ unsigned short Bs[BN][BK];
  const int tid = threadIdx.x;
  const int lane = tid & 63;
  const int w = tid >> 6;
  const int wr = w >> 1, wc = w & 1;
  const int l16 = lane & 15, lk = lane >> 4;
  const int row0 = blockIdx.x * BM, col0 = blockIdx.y * BN;

  f32x4 acc[MR][NR];
#pragma unroll
  for (int m = 0; m < MR; m++)
#pragma unroll
    for (int n = 0; n < NR; n++) acc[m][n] = (f32x4)0.f;

  const char* Abase = (const char*)A;
  const char* Bbase = (const char*)Bt;

  for (int k0 = 0; k0 < K; k0 += BK) {
#pragma unroll
    for (int i = 0; i < BM / 32; i++) {
      int ca = i * 256 + tid;
      int r = ca >> 3, b = (ca & 7) * 16;
      gll16(Abase + ((size_t)(row0 + r) * K + k0) * 2 + b, (char*)&As[0][0] + ca * 16);
    }
#pragma unroll
    for (int i = 0; i < BN / 32; i++) {
      int cb = i * 256 + tid;
      int c = cb >> 3, b = (cb & 7) * 16;
      gll16(Bbase + ((size_t)(col0 + c) * K + k0) * 2 + b, (char*)&Bs[0][0] + cb * 16);
    }
    __syncthreads();
#pragma unroll
    for (int ks = 0; ks < 2; ks++) {
      bf16x8 af[MR], bfr[NR];
#pragma unroll
      for (int m = 0; m < MR; m++)
        af[m] = *(const bf16x8*)&As[wr * (BM / 2) + m * 16 + l16][ks * 32 + lk * 8];
#pragma unroll
      for (int n = 0; n < NR; n++)
        bfr[n] = *(const bf16x8*)&Bs[wc * (BN / 2) + n * 16 + l16][ks * 32 + lk * 8];
#pragma unroll
      for (int m = 0; m < MR; m++)
#pragma unroll
        for (int n = 0; n < NR; n++)
          acc[m][n] = __builtin_amdgcn_mfma_f32_16x16x32_bf16(af[m], bfr[n], acc[m][n], 0, 0, 0);
    }
    __syncthreads();
  }
  // epilogue: C/D layout col=lane&15, row=(lane>>4)*4+reg
#pragma unroll
  for (int m = 0; m < MR; m++) {
    int row_b = row0 + wr * (BM / 2) + m * 16 + lk * 4;
#pragma unroll
    for (int r = 0; r < 4; r++) {
      int row = row_b + r;
      if (row < M) {
#pragma unroll
        for (int n = 0; n < NR; n++) {
          int col = col0 + wc * (BN / 2) + n * 16 + l16;
          if (OBF)
            ((unsigned short*)Cv)[(size_t)row * Nc + col] = f2bf(acc[m][n][r]);
          else
            ((float*)Cv)[(size_t)row * Nc + col] = acc[m][n][r];
        }
      }
    }
  }
  // fused attention dots (layer 1): a_s[row,head] = sum_c h[row,c]*att_s[c]
  if constexpr (DOTS) {
    __shared__ float s_ds[2][BM];
    __shared__ float s_dd[2][BM];
    float as_c[NR], ad_c[NR];
#pragma unroll
    for (int n = 0; n < NR; n++) {
      int col = col0 + wc * (BN / 2) + n * 16 + l16;
      as_c[n] = att_s[col];
      ad_c[n] = att_d[col];
    }
#pragma unroll
    for (int m = 0; m < MR; m++) {
#pragma unroll
      for (int r = 0; r < 4; r++) {
        float ps = 0.f, pd = 0.f;
#pragma unroll
        for (int n = 0; n < NR; n++) {
          ps += acc[m][n][r] * as_c[n];
          pd += acc[m][n][r] * ad_c[n];
        }
#pragma unroll
        for (int o = 8; o; o >>= 1) { ps += __shfl_xor(ps, o); pd += __shfl_xor(pd, o); }
        if (l16 == 0) {
          int rr = wr * (BM / 2) + m * 16 + lk * 4 + r;
          s_ds[wc][rr] = ps;
          s_dd[wc][rr] = pd;
        }
      }
    }
    __syncthreads();
    if (tid < BM) {
      int row = row0 + tid;
      if (row < M) {
        as_out[(size_t)row * 4 + blockIdx.y] = s_ds[0][tid] + s_ds[1][tid];
        ad_out[(size_t)row * 4 + blockIdx.y] = s_dd[0][tid] + s_dd[1][tid];
      }
    }
  }
}

// ---------------- attention score dots, layer 2 ----------------
__global__ __launch_bounds__(256) void attn_dots2_k(const float* __restrict__ h,
                                                    const float* __restrict__ att_s,
                                                    const float* __restrict__ att_d,
                                                    float* __restrict__ a_s,
                                                    float* __restrict__ a_d, int N) {
  int lane = threadIdx.x & 63, wave = threadIdx.x >> 6;
  int n = blockIdx.x * 4 + wave;
  if (n >= N) return;
  float v = h[(size_t)n * 64 + lane];
  float ps = v * att_s[lane], pd = v * att_d[lane];
#pragma unroll
  for (int o = 32; o; o >>= 1) { ps += __shfl_xor(ps, o); pd += __shfl_xor(pd, o); }
  if (lane == 0) { a_s[n] = ps; a_d[n] = pd; }
}

// ---------------- GAT layer 1 aggregation (block per dst, wave per edge) ----------------
// hfeat bf16 [N,512]; wave loads full 1KB row via dwordx4 (lane l -> feats 8l..8l+7).
__global__ __launch_bounds__(256) void gat_agg1_k(const unsigned short* __restrict__ hfeat,
                                                  const float* __restrict__ a_s,
                                                  const float* __restrict__ a_d,
                                                  const int* __restrict__ offs,
                                                  const int* __restrict__ ssrc,
                                                  const float* __restrict__ b1,
                                                  unsigned short* __restrict__ h1b, int N) {
  const int n = blockIdx.x;
  const int tid = threadIdx.x;
  const int lane = tid & 63, wave = tid >> 6;
  __shared__ float s_red[16];
  __shared__ float s_m[4], s_inv[4];
  __shared__ float s_part[4][512];
  const int start = offs[n], end = offs[n + 1];
  const int len = end - start;
  float ad[4];
#pragma unroll
  for (int h = 0; h < 4; h++) ad[h] = a_d[n * 4 + h];
  const float4* as4 = (const float4*)a_s;

  // pass A: per-head max (edge-parallel over 256 threads)
  float mloc[4] = {-1e30f, -1e30f, -1e30f, -1e30f};
  for (int i = tid; i < len; i += 256) {
    int s = ssrc[start + i];
    float4 av = as4[s];
    mloc[0] = fmaxf(mloc[0], lrelu02(av.x + ad[0]));
    mloc[1] = fmaxf(mloc[1], lrelu02(av.y + ad[1]));
    mloc[2] = fmaxf(mloc[2], lrelu02(av.z + ad[2]));
    mloc[3] = fmaxf(mloc[3], lrelu02(av.w + ad[3]));
  }
#pragma unroll
  for (int h = 0; h < 4; h++)
#pragma unroll
    for (int o = 32; o; o >>= 1) mloc[h] = fmaxf(mloc[h], __shfl_xor(mloc[h], o));
  if (lane == 0)
#pragma unroll
    for (int h = 0; h < 4; h++) s_red[wave * 4 + h] = mloc[h];
  __syncthreads();
  if (tid < 4)
    s_m[tid] = fmaxf(fmaxf(s_red[tid], s_red[4 + tid]), fmaxf(s_red[8 + tid], s_red[12 + tid]));
  __syncthreads();
  float m0 = s_m[0], m1 = s_m[1], m2 = s_m[2], m3 = s_m[3];

  // pass B: per-head sum of exp
  float sloc[4] = {0.f, 0.f, 0.f, 0.f};
  for (int i = tid; i < len; i += 256) {
    int s = ssrc[start + i];
    float4 av = as4[s];
    sloc[0] += __expf(lrelu02(av.x + ad[0]) - m0);
    sloc[1] += __expf(lrelu02(av.y + ad[1]) - m1);
    sloc[2] += __expf(lrelu02(av.z + ad[2]) - m2);
    sloc[3] += __expf(lrelu02(av.w + ad[3]) - m3);
  }
#pragma unroll
  for (int h = 0; h < 4; h++)
#pragma unroll
    for (int o = 32; o; o >>= 1) sloc[h] += __shfl_xor(sloc[h], o);
  __syncthreads();  // s_red safe to reuse
  if (lane == 0)
#pragma unroll
    for (int h = 0; h < 4; h++) s_red[wave * 4 + h] = sloc[h];
  __syncthreads();
  if (tid < 4)
    s_inv[tid] = 1.f / (s_red[tid] + s_red[4 + tid] + s_red[8 + tid] + s_red[12 + tid] + 1e-16f);
  __syncthreads();

  // main: wave per edge, dwordx4 full-row gather, normalized accumulate
  const int hhl = lane >> 4;
  const float mmv = s_m[hhl], invv = s_inv[hhl], adv = ad[hhl];
  float acc[8] = {0.f, 0.f, 0.f, 0.f, 0.f, 0.f, 0.f, 0.f};
  for (int i = start + wave; i < end; i += 4) {
    int s = ssrc[i];  // wave-uniform
    float sc = a_s[(size_t)s * 4 + hhl] + adv;
    float alpha = __expf(lrelu02(sc) - mmv) * invv;
    uint4 pk = *(const uint4*)(hfeat + (size_t)s * 512 + lane * 8);
    acc[0] += alpha * __uint_as_float(pk.x << 16);
    acc[1] += alpha * __uint_as_float(pk.x & 0xFFFF0000u);
    acc[2] += alpha * __uint_as_float(pk.y << 16);
    acc[3] += alpha * __uint_as_float(pk.y & 0xFFFF0000u);
    acc[4] += alpha * __uint_as_float(pk.z << 16);
    acc[5] += alpha * __uint_as_float(pk.z & 0xFFFF0000u);
    acc[6] += alpha * __uint_as_float(pk.w << 16);
    acc[7] += alpha * __uint_as_float(pk.w & 0xFFFF0000u);
  }
  // transposed store: feat 8*lane+q -> s_part[wave][q*64+lane] (conflict-free b32)
#pragma unroll
  for (int q = 0; q < 8; q++) s_part[wave][q * 64 + lane] = acc[q];
  __syncthreads();
  // combine 4 waves; thread t -> feats {2t, 2t+1}
  const int f0 = 2 * tid, f1 = 2 * tid + 1;
  const int p0 = (f0 & 7) * 64 + (f0 >> 3);
  const int p1 = (f1 & 7) * 64 + (f1 >> 3);
  float v0 = s_part[0][p0] + s_part[1][p0] + s_part[2][p0] + s_part[3][p0];
  float v1 = s_part[0][p1] + s_part[1][p1] + s_part[2][p1] + s_part[3][p1];
  v0 += b1[f0];
  v1 += b1[f1];
  v0 = v0 > 0.f ? v0 : (__expf(v0) - 1.f);
  v1 = v1 > 0.f ? v1 : (__expf(v1) - 1.f);
  unsigned outw = (unsigned)f2bf(v0) | ((unsigned)f2bf(v1) << 16);
  *(unsigned*)(h1b + (size_t)n * 512 + f0) = outw;
}

// ---------------- GAT layer 2 aggregation (wave per dst node) ----------------
__global__ __launch_bounds__(256) void gat_agg2_k(const float* __restrict__ h2pre,
                                                  const float* __restrict__ a_s,
                                                  const float* __restrict__ a_d,
                                                  const int* __restrict__ offs,
                                                  const int* __restrict__ ssrc,
                                                  const float* __restrict__ b2,
                                                  float* __restrict__ h2out, int N) {
  int lane = threadIdx.x & 63, wave = threadIdx.x >> 6;
  int n = blockIdx.x * 4 + wave;
  if (n >= N) return;
  int start = offs[n], end = offs[n + 1], len = end - start;
  float ad = a_d[n];
  float mloc = -1e30f;
  for (int i = lane; i < len; i += 64) {
    int s = ssrc[start + i];
    mloc = fmaxf(mloc, lrelu02(a_s[s] + ad));
  }
#pragma unroll
  for (int o = 32; o; o >>= 1) mloc = fmaxf(mloc, __shfl_xor(mloc, o));
  float acc = 0.f, ssum = 0.f;
  for (int base = 0; base < len; base += 64) {
    int i = base + lane;
    int s = 0; float ex = 0.f;
    if (i < len) {
      s = ssrc[start + i];
      ex = __expf(lrelu02(a_s[s] + ad) - mloc);
      ssum += ex;
    }
    int cnt = min(64, len - base);
    for (int j = 0; j < cnt; j++) {
      float exj = __shfl(ex, j);
      int sj = __shfl(s, j);
      acc += exj * h2pre[(size_t)sj * 64 + lane];
    }
  }
#pragma unroll
  for (int o = 32; o; o >>= 1) ssum += __shfl_xor(ssum, o);
  h2out[(size_t)n * 64 + lane] = acc / (ssum + 1e-16f) + b2[lane];
}

// ---------------- intra-attention score ----------------
__global__ __launch_bounds__(256) void score_k(const float* __restrict__ h2,
                                               const float* __restrict__ Wa,
                                               const float* __restrict__ ba,
                                               const float* __restrict__ wv,
                                               const float* __restrict__ bv,
                                               float* __restrict__ scores, int N) {
  int lane = threadIdx.x & 63, wave = threadIdx.x >> 6;
  int n = blockIdx.x * 4 + wave;
  if (n >= N) return;
  float hv = h2[(size_t)n * 64 + lane];
  float t = ba[lane];
  for (int k = 0; k < 64; k++) {
    float hk = __shfl(hv, k);
    t += hk * Wa[k * 64 + lane];
  }
  t = tanhf(t);
  float p = t * wv[lane];
#pragma unroll
  for (int o = 32; o; o >>= 1) p += __shfl_xor(p, o);
  if (lane == 0) scores[n] = p + bv[0];
}

__global__ void red_init_k(unsigned* __restrict__ red) {
  if (threadIdx.x == 0) { red[0] = 0x007FFFFFu; red[1] = 0u; }
}

__global__ void score_max_k(const float* __restrict__ scores, unsigned* __restrict__ red, int N) {
  int i = blockIdx.x * 256 + threadIdx.x;
  float m = (i < N) ? scores[i] : -1e30f;
#pragma unroll
  for (int o = 32; o; o >>= 1) m = fmaxf(m, __shfl_xor(m, o));
  if ((threadIdx.x & 63) == 0) atomicMax(&red[0], encf(m));
}

__global__ void score_sum_k(const float* __restrict__ scores, unsigned* __restrict__ red, int N) {
  float M = decf(red[0]);
  int i = blockIdx.x * 256 + threadIdx.x;
  float s = (i < N) ? __expf(scores[i] - M) : 0.f;
#pragma unroll
  for (int o = 32; o; o >>= 1) s += __shfl_xor(s, o);
  if ((threadIdx.x & 63) == 0) atomicAdd(reinterpret_cast<float*>(red) + 1, s);
}

__global__ void prep_cn_k(const float* __restrict__ ca, float* __restrict__ cn) {
  int lane = threadIdx.x & 63, c = threadIdx.x >> 6;
  float v = ca[c * 64 + lane];
  float p = v * v;
#pragma unroll
  for (int o = 32; o; o >>= 1) p += __shfl_xor(p, o);
  cn[c * 64 + lane] = v / fmaxf(sqrtf(p), 1e-12f);
}

__global__ __launch_bounds__(256) void finalize_k(const float* __restrict__ h2,
                                                  const float* __restrict__ scores,
                                                  const unsigned* __restrict__ red,
                                                  const float* __restrict__ cn,
                                                  const float* __restrict__ Wc,
                                                  const float* __restrict__ bc,
                                                  float* __restrict__ out, int N) {
  int lane = threadIdx.x & 63, wave = threadIdx.x >> 6;
  int n = blockIdx.x * 4 + wave;
  if (n >= N) return;
  float M = decf(red[0]);
  float S = __uint_as_float(red[1]);
  float attw = __expf(scores[n] - M) / S;
  float xw = h2[(size_t)n * 64 + lane] * attw;
  float p = xw * xw;
#pragma unroll
  for (int o = 32; o; o >>= 1) p += __shfl_xor(p, o);
  float xn = xw / fmaxf(sqrtf(p), 1e-12f);
  float i0 = xn * cn[lane],       i1 = xn * cn[64 + lane];
  float i2 = xn * cn[128 + lane], i3 = xn * cn[192 + lane];
  float o0 = xw * Wc[lane * 4 + 0], o1 = xw * Wc[lane * 4 + 1];
  float o2 = xw * Wc[lane * 4 + 2], o3 = xw * Wc[lane * 4 + 3];
#pragma unroll
  for (int o = 32; o; o >>= 1) {
    i0 += __shfl_xor(i0, o); i1 += __shfl_xor(i1, o);
    i2 += __shfl_xor(i2, o); i3 += __shfl_xor(i3, o);
    o0 += __shfl_xor(o0, o); o1 += __shfl_xor(o1, o);
    o2 += __shfl_xor(o2, o); o3 += __shfl_xor(o3, o);
  }
  float* outp   = out;
  float* xwp    = out + (size_t)N * 4;
  float* interp = out + (size_t)N * 68;
  xwp[(size_t)n * 64 + lane] = xw;
  if (lane == 0) {
    outp[n * 4 + 0] = o0 + bc[0]; outp[n * 4 + 1] = o1 + bc[1];
    outp[n * 4 + 2] = o2 + bc[2]; outp[n * 4 + 3] = o3 + bc[3];
    interp[n * 4 + 0] = i0; interp[n * 4 + 1] = i1;
    interp[n * 4 + 2] = i2; interp[n * 4 + 3] = i3;
  }
}

// ---------------- launch ----------------
extern "C" void kernel_launch(void* const* d_in, const int* in_sizes, int n_in,
                              void* d_out, int out_size, void* d_ws, size_t ws_size,
                              hipStream_t stream) {
  const float* x        = (const float*)d_in[0];
  const int*   ei       = (const int*)d_in[1];
  const float* W1       = (const float*)d_in[2];
  const float* att_src1 = (const float*)d_in[3];
  const float* att_dst1 = (const float*)d_in[4];
  const float* b1       = (const float*)d_in[5];
  const float* W2       = (const float*)d_in[6];
  const float* att_src2 = (const float*)d_in[7];
  const float* att_dst2 = (const float*)d_in[8];
  const float* b2       = (const float*)d_in[9];
  const float* Wa       = (const float*)d_in[10];
  const float* ba       = (const float*)d_in[11];
  const float* wv       = (const float*)d_in[12];
  const float* bv       = (const float*)d_in[13];
  const float* class_attn = (const float*)d_in[14];
  const float* Wc       = (const float*)d_in[15];
  const float* bc       = (const float*)d_in[16];

  const int N = in_sizes[0] / 512;
  const int E = in_sizes[1] / 2;
  const int Eall = E + N;
  const int Mpad = ((N + 127) / 128) * 128;
  const int nb = (N + 255) / 256;

  char* w = (char*)d_ws;
  size_t off = 0;
  auto alloc = [&](size_t bytes) -> void* {
    off = (off + 255) & ~((size_t)255);
    void* p = w + off;
    off += bytes;
    return p;
  };
  unsigned short* xb  = (unsigned short*)alloc((size_t)Mpad * 512 * 2);  // xb, later h1b (aliased)
  unsigned short* h1b = xb;
  unsigned short* hb  = (unsigned short*)alloc((size_t)N * 512 * 2);     // h = x@W1, bf16
  float* h2pre  = (float*)alloc((size_t)N * 64 * 4);
  float* h2     = (float*)alloc((size_t)N * 64 * 4);
  unsigned short* W1t = (unsigned short*)alloc((size_t)512 * 512 * 2);
  unsigned short* W2t = (unsigned short*)alloc((size_t)64 * 512 * 2);
  float* as1    = (float*)alloc((size_t)N * 4 * 4);
  float* ad1    = (float*)alloc((size_t)N * 4 * 4);
  float* as2    = (float*)alloc((size_t)N * 4);
  float* ad2    = (float*)alloc((size_t)N * 4);
  int*   counts = (int*)alloc((size_t)N * 4);
  int*   incl   = (int*)alloc((size_t)N * 4);
  int*   bsum   = (int*)alloc(256 * 4);
  int*   pb     = (int*)alloc(256 * 4);
  int*   offs   = (int*)alloc((size_t)(N + 1) * 4);
  int*   cursor = (int*)alloc((size_t)N * 4);
  int*   ssrc   = (int*)alloc((size_t)Eall * 4);
  float* scores = (float*)alloc((size_t)N * 4);
  unsigned* red = (unsigned*)alloc(64);
  float* cn     = (float*)alloc(256 * 4);

  const int gN256  = (N + 255) / 256;
  const int gE256  = (Eall + 255) / 256;
  const int gNode4 = (N + 3) / 4;

  // --- build CSR (sorted-by-dst edge list), reused by both layers ---
  zero_int_k<<<gN256, 256, 0, stream>>>(counts, N);
  hist_k<<<gE256, 256, 0, stream>>>(ei, E, N, counts);
  scan1_k<<<nb, 256, 0, stream>>>(counts, incl, bsum, N);
  scan2_k<<<1, 256, 0, stream>>>(bsum, pb, nb);
  scan3_k<<<gN256, 256, 0, stream>>>(incl, pb, offs, cursor, N);
  scatter_k<<<gE256, 256, 0, stream>>>(ei, E, N, cursor, ssrc);

  // --- bf16 conversions ---
  conv_x_k<<<(Mpad * 64 + 255) / 256, 256, 0, stream>>>(x, xb, N, Mpad);
  conv_wt_k<<<(512 * 512 + 255) / 256, 256, 0, stream>>>(W1, W1t, 512, 512);
  conv_wt_k<<<(64 * 512 + 255) / 256, 256, 0, stream>>>(W2, W2t, 512, 64);

  // --- layer 1 (h bf16; att dots fused into GEMM epilogue) ---
  mfma_gemm_k<128, 128, true, true><<<dim3(Mpad / 128, 4), 256, 0, stream>>>(
      xb, W1t, hb, att_src1, att_dst1, as1, ad1, N, 512, 512);
  gat_agg1_k<<<N, 256, 0, stream>>>(hb, as1, ad1, offs, ssrc, b1, h1b, N);

  // --- layer 2 ---
  mfma_gemm_k<64, 64, false, false><<<dim3(Mpad / 64, 1), 256, 0, stream>>>(
      h1b, W2t, h2pre, nullptr, nullptr, nullptr, nullptr, N, 512, 64);
  attn_dots2_k<<<gNode4, 256, 0, stream>>>(h2pre, att_src2, att_dst2, as2, ad2, N);
  gat_agg2_k<<<gNode4, 256, 0, stream>>>(h2pre, as2, ad2, offs, ssrc, b2, h2, N);

  // --- intra attention + heads ---
  score_k<<<gNode4, 256, 0, stream>>>(h2, Wa, ba, wv, bv, scores, N);
  red_init_k<<<1, 64, 0, stream>>>(red);
  score_max_k<<<gN256, 256, 0, stream>>>(scores, red, N);
  score_sum_k<<<gN256, 256, 0, stream>>>(scores, red, N);
  prep_cn_k<<<1, 256, 0, stream>>>(class_attn, cn);
  finalize_k<<<gNode4, 256, 0, stream>>>(h2, scores, red, cn, Wc, bc,
                                         (float*)d_out, N);
}

// Round 5
// 481.601 us; speedup vs baseline: 2.1018x; 1.1718x over previous
//
#include <hip/hip_runtime.h>
#include <cstdint>
#include <cstddef>

// ---------------- helpers ----------------
typedef __attribute__((ext_vector_type(8))) short bf16x8;
typedef __attribute__((ext_vector_type(4))) float f32x4;
typedef __attribute__((ext_vector_type(8))) unsigned short u16x8;

__device__ __forceinline__ unsigned encf(float f) {
  unsigned u = __float_as_uint(f);
  return (u & 0x80000000u) ? ~u : (u | 0x80000000u);
}
__device__ __forceinline__ float decf(unsigned u) {
  return (u & 0x80000000u) ? __uint_as_float(u & 0x7FFFFFFFu) : __uint_as_float(~u);
}
__device__ __forceinline__ float lrelu02(float x) { return x > 0.f ? x : 0.2f * x; }
__device__ __forceinline__ unsigned short f2bf(float f) {
  unsigned u = __float_as_uint(f);
  unsigned r = u + 0x7FFFu + ((u >> 16) & 1u);  // RNE
  return (unsigned short)(r >> 16);
}
__device__ __forceinline__ float bf2f(unsigned short b) {
  return __uint_as_float(((unsigned)b) << 16);
}

__device__ __forceinline__ void gll16(const void* g, void* l) {
  __builtin_amdgcn_global_load_lds(
      (const __attribute__((address_space(1))) void*)g,
      (__attribute__((address_space(3))) void*)l, 16, 0, 0);
}

// ---------------- edge sort (counting sort by dst) ----------------
__global__ void zero_int_k(int* __restrict__ p, int n) {
  int i = blockIdx.x * 256 + threadIdx.x;
  if (i < n) p[i] = 0;
}

__global__ void hist_k(const int* __restrict__ ei, int E, int N, int* __restrict__ counts) {
  int i = blockIdx.x * 256 + threadIdx.x;
  int Eall = E + N;
  if (i >= Eall) return;
  int dst = (i < E) ? ei[E + i] : (i - E);
  atomicAdd(&counts[dst], 1);
}

// 3-phase parallel scan
__global__ __launch_bounds__(256) void scan1_k(const int* __restrict__ counts,
                                               int* __restrict__ incl,
                                               int* __restrict__ bsum, int N) {
  int b = blockIdx.x, tid = threadIdx.x;
  int lane = tid & 63, wv = tid >> 6;
  int i = b * 256 + tid;
  int v = (i < N) ? counts[i] : 0;
#pragma unroll
  for (int o = 1; o < 64; o <<= 1) {
    int t = __shfl_up(v, o, 64);
    if (lane >= o) v += t;
  }
  __shared__ int wsum[4];
  if (lane == 63) wsum[wv] = v;
  __syncthreads();
  int base = 0;
  for (int wj = 0; wj < wv; wj++) base += wsum[wj];
  v += base;
  if (i < N) incl[i] = v;
  if (tid == 255) bsum[b] = v;
}

__global__ __launch_bounds__(256) void scan2_k(const int* __restrict__ bsum,
                                               int* __restrict__ pb, int nb) {
  int tid = threadIdx.x;
  int lane = tid & 63, wv = tid >> 6;
  int v = (tid < nb) ? bsum[tid] : 0;
  int orig = v;
#pragma unroll
  for (int o = 1; o < 64; o <<= 1) {
    int t = __shfl_up(v, o, 64);
    if (lane >= o) v += t;
  }
  __shared__ int wsum[4];
  if (lane == 63) wsum[wv] = v;
  __syncthreads();
  int base = 0;
  for (int wj = 0; wj < wv; wj++) base += wsum[wj];
  if (tid < nb) pb[tid] = v + base - orig;
}

__global__ void scan3_k(const int* __restrict__ incl, const int* __restrict__ pb,
                        int* __restrict__ offs, int* __restrict__ cursor, int N) {
  int i = blockIdx.x * 256 + threadIdx.x;
  if (i == 0) { offs[0] = 0; cursor[0] = 0; }
  if (i < N) {
    int v = incl[i] + pb[i >> 8];
    offs[i + 1] = v;
    if (i + 1 < N) cursor[i + 1] = v;
  }
}

__global__ void scatter_k(const int* __restrict__ ei, int E, int N,
                          int* __restrict__ cursor, int* __restrict__ ssrc) {
  int i = blockIdx.x * 256 + threadIdx.x;
  int Eall = E + N;
  if (i >= Eall) return;
  int src, dst;
  if (i < E) { src = ei[i]; dst = ei[E + i]; }
  else       { src = i - E; dst = i - E; }
  int pos = atomicAdd(&cursor[dst], 1);
  ssrc[pos] = src;
}

// ---------------- bf16 conversion kernels ----------------
__global__ void conv_x_k(const float* __restrict__ x, unsigned short* __restrict__ xb,
                         int N, int Mpad) {
  int i = blockIdx.x * 256 + threadIdx.x;  // octet index
  int total = Mpad * 64;
  if (i >= total) return;
  int row = i >> 6;
  u16x8 v;
  if (row < N) {
    const float4* src = (const float4*)(x + (size_t)i * 8);
    float4 a = src[0], b = src[1];
    v[0] = f2bf(a.x); v[1] = f2bf(a.y); v[2] = f2bf(a.z); v[3] = f2bf(a.w);
    v[4] = f2bf(b.x); v[5] = f2bf(b.y); v[6] = f2bf(b.z); v[7] = f2bf(b.w);
  } else {
    v = (u16x8)0;
  }
  *(u16x8*)(xb + (size_t)i * 8) = v;
}

__global__ void conv_wt_k(const float* __restrict__ W, unsigned short* __restrict__ Wt,
                          int K, int Nc) {
  int i = blockIdx.x * 256 + threadIdx.x;
  if (i >= K * Nc) return;
  int c = i / K, k = i - c * K;
  Wt[i] = f2bf(W[(size_t)k * Nc + c]);
}

// ---------------- bf16 MFMA GEMM: C[M,Nc] = A[M,K] @ Bt[Nc,K]^T ----------------
template <int BM, int BN, bool OBF, bool DOTS>
__global__ __launch_bounds__(256) void mfma_gemm_k(const unsigned short* __restrict__ A,
                                                   const unsigned short* __restrict__ Bt,
                                                   void* __restrict__ Cv,
                                                   const float* __restrict__ att_s,
                                                   const float* __restrict__ att_d,
                                                   float* __restrict__ as_out,
                                                   float* __restrict__ ad_out,
                                                   int M, int K, int Nc) {
  constexpr int BK = 64;
  constexpr int MR = BM / 32;
  constexpr int NR = BN / 32;
  __shared__ unsigned short As[BM][BK];
  __shared__ unsigned short Bs[BN][BK];
  const int tid = threadIdx.x;
  const int lane = tid & 63;
  const int w = tid >> 6;
  const int wr = w >> 1, wc = w & 1;
  const int l16 = lane & 15, lk = lane >> 4;
  const int row0 = blockIdx.x * BM, col0 = blockIdx.y * BN;

  f32x4 acc[MR][NR];
#pragma unroll
  for (int m = 0; m < MR; m++)
#pragma unroll
    for (int n = 0; n < NR; n++) acc[m][n] = (f32x4)0.f;

  const char* Abase = (const char*)A;
  const char* Bbase = (const char*)Bt;

  for (int k0 = 0; k0 < K; k0 += BK) {
#pragma unroll
    for (int i = 0; i < BM / 32; i++) {
      int ca = i * 256 + tid;
      int r = ca >> 3, b = (ca & 7) * 16;
      gll16(Abase + ((size_t)(row0 + r) * K + k0) * 2 + b, (char*)&As[0][0] + ca * 16);
    }
#pragma unroll
    for (int i = 0; i < BN / 32; i++) {
      int cb = i * 256 + tid;
      int c = cb >> 3, b = (cb & 7) * 16;
      gll16(Bbase + ((size_t)(col0 + c) * K + k0) * 2 + b, (char*)&Bs[0][0] + cb * 16);
    }
    __syncthreads();
#pragma unroll
    for (int ks = 0; ks < 2; ks++) {
      bf16x8 af[MR], bfr[NR];
#pragma unroll
      for (int m = 0; m < MR; m++)
        af[m] = *(const bf16x8*)&As[wr * (BM / 2) + m * 16 + l16][ks * 32 + lk * 8];
#pragma unroll
      for (int n = 0; n < NR; n++)
        bfr[n] = *(const bf16x8*)&Bs[wc * (BN / 2) + n * 16 + l16][ks * 32 + lk * 8];
#pragma unroll
      for (int m = 0; m < MR; m++)
#pragma unroll
        for (int n = 0; n < NR; n++)
          acc[m][n] = __builtin_amdgcn_mfma_f32_16x16x32_bf16(af[m], bfr[n], acc[m][n], 0, 0, 0);
    }
    __syncthreads();
  }
#pragma unroll
  for (int m = 0; m < MR; m++) {
    int row_b = row0 + wr * (BM / 2) + m * 16 + lk * 4;
#pragma unroll
    for (int r = 0; r < 4; r++) {
      int row = row_b + r;
      if (row < M) {
#pragma unroll
        for (int n = 0; n < NR; n++) {
          int col = col0 + wc * (BN / 2) + n * 16 + l16;
          if (OBF)
            ((unsigned short*)Cv)[(size_t)row * Nc + col] = f2bf(acc[m][n][r]);
          else
            ((float*)Cv)[(size_t)row * Nc + col] = acc[m][n][r];
        }
      }
    }
  }
  if constexpr (DOTS) {
    __shared__ float s_ds[2][BM];
    __shared__ float s_dd[2][BM];
    float as_c[NR], ad_c[NR];
#pragma unroll
    for (int n = 0; n < NR; n++) {
      int col = col0 + wc * (BN / 2) + n * 16 + l16;
      as_c[n] = att_s[col];
      ad_c[n] = att_d[col];
    }
#pragma unroll
    for (int m = 0; m < MR; m++) {
#pragma unroll
      for (int r = 0; r < 4; r++) {
        float ps = 0.f, pd = 0.f;
#pragma unroll
        for (int n = 0; n < NR; n++) {
          ps += acc[m][n][r] * as_c[n];
          pd += acc[m][n][r] * ad_c[n];
        }
#pragma unroll
        for (int o = 8; o; o >>= 1) { ps += __shfl_xor(ps, o); pd += __shfl_xor(pd, o); }
        if (l16 == 0) {
          int rr = wr * (BM / 2) + m * 16 + lk * 4 + r;
          s_ds[wc][rr] = ps;
          s_dd[wc][rr] = pd;
        }
      }
    }
    __syncthreads();
    if (tid < BM) {
      int row = row0 + tid;
      if (row < M) {
        as_out[(size_t)row * 4 + blockIdx.y] = s_ds[0][tid] + s_ds[1][tid];
        ad_out[(size_t)row * 4 + blockIdx.y] = s_dd[0][tid] + s_dd[1][tid];
      }
    }
  }
}

// ---------------- attention score dots, layer 2 ----------------
__global__ __launch_bounds__(256) void attn_dots2_k(const float* __restrict__ h,
                                                    const float* __restrict__ att_s,
                                                    const float* __restrict__ att_d,
                                                    float* __restrict__ a_s,
                                                    float* __restrict__ a_d, int N) {
  int lane = threadIdx.x & 63, wave = threadIdx.x >> 6;
  int n = blockIdx.x * 4 + wave;
  if (n >= N) return;
  float v = h[(size_t)n * 64 + lane];
  float ps = v * att_s[lane], pd = v * att_d[lane];
#pragma unroll
  for (int o = 32; o; o >>= 1) { ps += __shfl_xor(ps, o); pd += __shfl_xor(pd, o); }
  if (lane == 0) { a_s[n] = ps; a_d[n] = pd; }
}

// ---------------- GAT layer 1 aggregation: wave per dst node, barrier-free ----------------
// online-softmax over chunks of 64 edges; lane l owns feats 8l..8l+7 (head l>>4).
__global__ __launch_bounds__(256) void gat_agg1_k(const unsigned short* __restrict__ hfeat,
                                                  const float* __restrict__ a_s,
                                                  const float* __restrict__ a_d,
                                                  const int* __restrict__ offs,
                                                  const int* __restrict__ ssrc,
                                                  const float* __restrict__ b1,
                                                  unsigned short* __restrict__ h1b, int N) {
  const int tid = threadIdx.x;
  const int lane = tid & 63, wave = tid >> 6;
  const int n = blockIdx.x * 4 + wave;
  if (n >= N) return;
  __shared__ int   s_src[4][64];
  __shared__ float s_ex[4][64][4];   // [wave][edge][head] -> head in consecutive banks
  const int start = offs[n], end = offs[n + 1];
  const int hhl = lane >> 4;
  const float4 adv4 = *(const float4*)(a_d + (size_t)n * 4);
  const float4* as4 = (const float4*)a_s;

  float m0 = -1e30f, m1 = -1e30f, m2 = -1e30f, m3 = -1e30f;
  float S0 = 0.f, S1 = 0.f, S2 = 0.f, S3 = 0.f;
  float acc[8] = {0.f, 0.f, 0.f, 0.f, 0.f, 0.f, 0.f, 0.f};

  for (int base = start; base < end; base += 64) {
    const int cnt = min(64, end - base);
    // lane j computes edge j's scores for all 4 heads
    float e0 = -1e30f, e1 = -1e30f, e2 = -1e30f, e3 = -1e30f;
    int s = 0;
    if (lane < cnt) {
      s = ssrc[base + lane];
      float4 av = as4[s];
      e0 = lrelu02(av.x + adv4.x);
      e1 = lrelu02(av.y + adv4.y);
      e2 = lrelu02(av.z + adv4.z);
      e3 = lrelu02(av.w + adv4.w);
    }
    // chunk max per head
    float c0 = e0, c1 = e1, c2 = e2, c3 = e3;
#pragma unroll
    for (int o = 32; o; o >>= 1) {
      c0 = fmaxf(c0, __shfl_xor(c0, o));
      c1 = fmaxf(c1, __shfl_xor(c1, o));
      c2 = fmaxf(c2, __shfl_xor(c2, o));
      c3 = fmaxf(c3, __shfl_xor(c3, o));
    }
    float nm0 = fmaxf(m0, c0), nm1 = fmaxf(m1, c1);
    float nm2 = fmaxf(m2, c2), nm3 = fmaxf(m3, c3);
    float sc0 = __expf(m0 - nm0), sc1 = __expf(m1 - nm1);
    float sc2 = __expf(m2 - nm2), sc3 = __expf(m3 - nm3);
    m0 = nm0; m1 = nm1; m2 = nm2; m3 = nm3;
    float x0 = (lane < cnt) ? __expf(e0 - nm0) : 0.f;
    float x1 = (lane < cnt) ? __expf(e1 - nm1) : 0.f;
    float x2 = (lane < cnt) ? __expf(e2 - nm2) : 0.f;
    float x3 = (lane < cnt) ? __expf(e3 - nm3) : 0.f;
    // stash for gather loop
    s_src[wave][lane] = s;
    s_ex[wave][lane][0] = x0; s_ex[wave][lane][1] = x1;
    s_ex[wave][lane][2] = x2; s_ex[wave][lane][3] = x3;
    // chunk sums
#pragma unroll
    for (int o = 32; o; o >>= 1) {
      x0 += __shfl_xor(x0, o); x1 += __shfl_xor(x1, o);
      x2 += __shfl_xor(x2, o); x3 += __shfl_xor(x3, o);
    }
    S0 = S0 * sc0 + x0; S1 = S1 * sc1 + x1;
    S2 = S2 * sc2 + x2; S3 = S3 * sc3 + x3;
    // rescale accumulator for this lane's head
    float scl = (hhl == 0) ? sc0 : (hhl == 1) ? sc1 : (hhl == 2) ? sc2 : sc3;
#pragma unroll
    for (int q = 0; q < 8; q++) acc[q] *= scl;
    // gather + accumulate (unnormalized)
#pragma unroll 4
    for (int j = 0; j < cnt; j++) {
      int sj = s_src[wave][j];
      float al = s_ex[wave][j][hhl];
      uint4 pk = *(const uint4*)(hfeat + ((size_t)sj << 9) + lane * 8);
      acc[0] += al * __uint_as_float(pk.x << 16);
      acc[1] += al * __uint_as_float(pk.x & 0xFFFF0000u);
      acc[2] += al * __uint_as_float(pk.y << 16);
      acc[3] += al * __uint_as_float(pk.y & 0xFFFF0000u);
      acc[4] += al * __uint_as_float(pk.z << 16);
      acc[5] += al * __uint_as_float(pk.z & 0xFFFF0000u);
      acc[6] += al * __uint_as_float(pk.w << 16);
      acc[7] += al * __uint_as_float(pk.w & 0xFFFF0000u);
    }
  }
  float inv = 1.f / (((hhl == 0) ? S0 : (hhl == 1) ? S1 : (hhl == 2) ? S2 : S3) + 1e-16f);
  const float4 b1a = *(const float4*)(b1 + lane * 8);
  const float4 b1b = *(const float4*)(b1 + lane * 8 + 4);
  float v[8];
  v[0] = acc[0] * inv + b1a.x; v[1] = acc[1] * inv + b1a.y;
  v[2] = acc[2] * inv + b1a.z; v[3] = acc[3] * inv + b1a.w;
  v[4] = acc[4] * inv + b1b.x; v[5] = acc[5] * inv + b1b.y;
  v[6] = acc[6] * inv + b1b.z; v[7] = acc[7] * inv + b1b.w;
  u16x8 outv;
#pragma unroll
  for (int q = 0; q < 8; q++) {
    float t = v[q] > 0.f ? v[q] : (__expf(v[q]) - 1.f);
    outv[q] = f2bf(t);
  }
  *(u16x8*)(h1b + ((size_t)n << 9) + lane * 8) = outv;
}

// ---------------- GAT layer 2 aggregation: wave per dst node, barrier-free ----------------
__global__ __launch_bounds__(256) void gat_agg2_k(const float* __restrict__ h2pre,
                                                  const float* __restrict__ a_s,
                                                  const float* __restrict__ a_d,
                                                  const int* __restrict__ offs,
                                                  const int* __restrict__ ssrc,
                                                  const float* __restrict__ b2,
                                                  float* __restrict__ h2out, int N) {
  const int tid = threadIdx.x;
  const int lane = tid & 63, wave = tid >> 6;
  const int n = blockIdx.x * 4 + wave;
  if (n >= N) return;
  __shared__ int   s_src[4][64];
  __shared__ float s_ex[4][64];
  const int start = offs[n], end = offs[n + 1];
  const float ad = a_d[n];

  float m = -1e30f, S = 0.f, acc = 0.f;
  for (int base = start; base < end; base += 64) {
    const int cnt = min(64, end - base);
    float e = -1e30f;
    int s = 0;
    if (lane < cnt) {
      s = ssrc[base + lane];
      e = lrelu02(a_s[s] + ad);
    }
    float c = e;
#pragma unroll
    for (int o = 32; o; o >>= 1) c = fmaxf(c, __shfl_xor(c, o));
    float nm = fmaxf(m, c);
    float sc = __expf(m - nm);
    m = nm;
    float x = (lane < cnt) ? __expf(e - nm) : 0.f;
    s_src[wave][lane] = s;
    s_ex[wave][lane] = x;
#pragma unroll
    for (int o = 32; o; o >>= 1) x += __shfl_xor(x, o);
    S = S * sc + x;
    acc *= sc;
#pragma unroll 4
    for (int j = 0; j < cnt; j++) {
      int sj = s_src[wave][j];
      float al = s_ex[wave][j];
      acc += al * h2pre[((size_t)sj << 6) + lane];
    }
  }
  h2out[((size_t)n << 6) + lane] = acc / (S + 1e-16f) + b2[lane];
}

// ---------------- intra-attention score ----------------
__global__ __launch_bounds__(256) void score_k(const float* __restrict__ h2,
                                               const float* __restrict__ Wa,
                                               const float* __restrict__ ba,
                                               const float* __restrict__ wv,
                                               const float* __restrict__ bv,
                                               float* __restrict__ scores, int N) {
  int lane = threadIdx.x & 63, wave = threadIdx.x >> 6;
  int n = blockIdx.x * 4 + wave;
  if (n >= N) return;
  float hv = h2[(size_t)n * 64 + lane];
  float t = ba[lane];
  for (int k = 0; k < 64; k++) {
    float hk = __shfl(hv, k);
    t += hk * Wa[k * 64 + lane];
  }
  t = tanhf(t);
  float p = t * wv[lane];
#pragma unroll
  for (int o = 32; o; o >>= 1) p += __shfl_xor(p, o);
  if (lane == 0) scores[n] = p + bv[0];
}

__global__ void red_init_k(unsigned* __restrict__ red) {
  if (threadIdx.x == 0) { red[0] = 0x007FFFFFu; red[1] = 0u; }
}

__global__ void score_max_k(const float* __restrict__ scores, unsigned* __restrict__ red, int N) {
  int i = blockIdx.x * 256 + threadIdx.x;
  float m = (i < N) ? scores[i] : -1e30f;
#pragma unroll
  for (int o = 32; o; o >>= 1) m = fmaxf(m, __shfl_xor(m, o));
  if ((threadIdx.x & 63) == 0) atomicMax(&red[0], encf(m));
}

__global__ void score_sum_k(const float* __restrict__ scores, unsigned* __restrict__ red, int N) {
  float M = decf(red[0]);
  int i = blockIdx.x * 256 + threadIdx.x;
  float s = (i < N) ? __expf(scores[i] - M) : 0.f;
#pragma unroll
  for (int o = 32; o; o >>= 1) s += __shfl_xor(s, o);
  if ((threadIdx.x & 63) == 0) atomicAdd(reinterpret_cast<float*>(red) + 1, s);
}

__global__ void prep_cn_k(const float* __restrict__ ca, float* __restrict__ cn) {
  int lane = threadIdx.x & 63, c = threadIdx.x >> 6;
  float v = ca[c * 64 + lane];
  float p = v * v;
#pragma unroll
  for (int o = 32; o; o >>= 1) p += __shfl_xor(p, o);
  cn[c * 64 + lane] = v / fmaxf(sqrtf(p), 1e-12f);
}

__global__ __launch_bounds__(256) void finalize_k(const float* __restrict__ h2,
                                                  const float* __restrict__ scores,
                                                  const unsigned* __restrict__ red,
                                                  const float* __restrict__ cn,
                                                  const float* __restrict__ Wc,
                                                  const float* __restrict__ bc,
                                                  float* __restrict__ out, int N) {
  int lane = threadIdx.x & 63, wave = threadIdx.x >> 6;
  int n = blockIdx.x * 4 + wave;
  if (n >= N) return;
  float M = decf(red[0]);
  float S = __uint_as_float(red[1]);
  float attw = __expf(scores[n] - M) / S;
  float xw = h2[(size_t)n * 64 + lane] * attw;
  float p = xw * xw;
#pragma unroll
  for (int o = 32; o; o >>= 1) p += __shfl_xor(p, o);
  float xn = xw / fmaxf(sqrtf(p), 1e-12f);
  float i0 = xn * cn[lane],       i1 = xn * cn[64 + lane];
  float i2 = xn * cn[128 + lane], i3 = xn * cn[192 + lane];
  float o0 = xw * Wc[lane * 4 + 0], o1 = xw * Wc[lane * 4 + 1];
  float o2 = xw * Wc[lane * 4 + 2], o3 = xw * Wc[lane * 4 + 3];
#pragma unroll
  for (int o = 32; o; o >>= 1) {
    i0 += __shfl_xor(i0, o); i1 += __shfl_xor(i1, o);
    i2 += __shfl_xor(i2, o); i3 += __shfl_xor(i3, o);
    o0 += __shfl_xor(o0, o); o1 += __shfl_xor(o1, o);
    o2 += __shfl_xor(o2, o); o3 += __shfl_xor(o3, o);
  }
  float* outp   = out;
  float* xwp    = out + (size_t)N * 4;
  float* interp = out + (size_t)N * 68;
  xwp[(size_t)n * 64 + lane] = xw;
  if (lane == 0) {
    outp[n * 4 + 0] = o0 + bc[0]; outp[n * 4 + 1] = o1 + bc[1];
    outp[n * 4 + 2] = o2 + bc[2]; outp[n * 4 + 3] = o3 + bc[3];
    interp[n * 4 + 0] = i0; interp[n * 4 + 1] = i1;
    interp[n * 4 + 2] = i2; interp[n * 4 + 3] = i3;
  }
}

// ---------------- launch ----------------
extern "C" void kernel_launch(void* const* d_in, const int* in_sizes, int n_in,
                              void* d_out, int out_size, void* d_ws, size_t ws_size,
                              hipStream_t stream) {
  const float* x        = (const float*)d_in[0];
  const int*   ei       = (const int*)d_in[1];
  const float* W1       = (const float*)d_in[2];
  const float* att_src1 = (const float*)d_in[3];
  const float* att_dst1 = (const float*)d_in[4];
  const float* b1       = (const float*)d_in[5];
  const float* W2       = (const float*)d_in[6];
  const float* att_src2 = (const float*)d_in[7];
  const float* att_dst2 = (const float*)d_in[8];
  const float* b2       = (const float*)d_in[9];
  const float* Wa       = (const float*)d_in[10];
  const float* ba       = (const float*)d_in[11];
  const float* wv       = (const float*)d_in[12];
  const float* bv       = (const float*)d_in[13];
  const float* class_attn = (const float*)d_in[14];
  const float* Wc       = (const float*)d_in[15];
  const float* bc       = (const float*)d_in[16];

  const int N = in_sizes[0] / 512;
  const int E = in_sizes[1] / 2;
  const int Eall = E + N;
  const int Mpad = ((N + 127) / 128) * 128;
  const int nb = (N + 255) / 256;

  char* w = (char*)d_ws;
  size_t off = 0;
  auto alloc = [&](size_t bytes) -> void* {
    off = (off + 255) & ~((size_t)255);
    void* p = w + off;
    off += bytes;
    return p;
  };
  unsigned short* xb  = (unsigned short*)alloc((size_t)Mpad * 512 * 2);  // xb, later h1b
  unsigned short* h1b = xb;
  unsigned short* hb  = (unsigned short*)alloc((size_t)N * 512 * 2);     // h = x@W1, bf16
  float* h2pre  = (float*)alloc((size_t)N * 64 * 4);
  float* h2     = (float*)alloc((size_t)N * 64 * 4);
  unsigned short* W1t = (unsigned short*)alloc((size_t)512 * 512 * 2);
  unsigned short* W2t = (unsigned short*)alloc((size_t)64 * 512 * 2);
  float* as1    = (float*)alloc((size_t)N * 4 * 4);
  float* ad1    = (float*)alloc((size_t)N * 4 * 4);
  float* as2    = (float*)alloc((size_t)N * 4);
  float* ad2    = (float*)alloc((size_t)N * 4);
  int*   counts = (int*)alloc((size_t)N * 4);
  int*   incl   = (int*)alloc((size_t)N * 4);
  int*   bsum   = (int*)alloc(256 * 4);
  int*   pb     = (int*)alloc(256 * 4);
  int*   offs   = (int*)alloc((size_t)(N + 1) * 4);
  int*   cursor = (int*)alloc((size_t)N * 4);
  int*   ssrc   = (int*)alloc((size_t)Eall * 4);
  float* scores = (float*)alloc((size_t)N * 4);
  unsigned* red = (unsigned*)alloc(64);
  float* cn     = (float*)alloc(256 * 4);

  const int gN256  = (N + 255) / 256;
  const int gE256  = (Eall + 255) / 256;
  const int gNode4 = (N + 3) / 4;

  // --- build CSR ---
  zero_int_k<<<gN256, 256, 0, stream>>>(counts, N);
  hist_k<<<gE256, 256, 0, stream>>>(ei, E, N, counts);
  scan1_k<<<nb, 256, 0, stream>>>(counts, incl, bsum, N);
  scan2_k<<<1, 256, 0, stream>>>(bsum, pb, nb);
  scan3_k<<<gN256, 256, 0, stream>>>(incl, pb, offs, cursor, N);
  scatter_k<<<gE256, 256, 0, stream>>>(ei, E, N, cursor, ssrc);

  // --- bf16 conversions ---
  conv_x_k<<<(Mpad * 64 + 255) / 256, 256, 0, stream>>>(x, xb, N, Mpad);
  conv_wt_k<<<(512 * 512 + 255) / 256, 256, 0, stream>>>(W1, W1t, 512, 512);
  conv_wt_k<<<(64 * 512 + 255) / 256, 256, 0, stream>>>(W2, W2t, 512, 64);

  // --- layer 1 ---
  mfma_gemm_k<128, 128, true, true><<<dim3(Mpad / 128, 4), 256, 0, stream>>>(
      xb, W1t, hb, att_src1, att_dst1, as1, ad1, N, 512, 512);
  gat_agg1_k<<<gNode4, 256, 0, stream>>>(hb, as1, ad1, offs, ssrc, b1, h1b, N);

  // --- layer 2 ---
  mfma_gemm_k<64, 64, false, false><<<dim3(Mpad / 64, 1), 256, 0, stream>>>(
      h1b, W2t, h2pre, nullptr, nullptr, nullptr, nullptr, N, 512, 64);
  attn_dots2_k<<<gNode4, 256, 0, stream>>>(h2pre, att_src2, att_dst2, as2, ad2, N);
  gat_agg2_k<<<gNode4, 256, 0, stream>>>(h2pre, as2, ad2, offs, ssrc, b2, h2, N);

  // --- intra attention + heads ---
  score_k<<<gNode4, 256, 0, stream>>>(h2, Wa, ba, wv, bv, scores, N);
  red_init_k<<<1, 64, 0, stream>>>(red);
  score_max_k<<<gN256, 256, 0, stream>>>(scores, red, N);
  score_sum_k<<<gN256, 256, 0, stream>>>(scores, red, N);
  prep_cn_k<<<1, 256, 0, stream>>>(class_attn, cn);
  finalize_k<<<gNode4, 256, 0, stream>>>(h2, scores, red, cn, Wc, bc,
                                         (float*)d_out, N);
}

// Round 6
// 444.533 us; speedup vs baseline: 2.2770x; 1.0834x over previous
//
#include <hip/hip_runtime.h>
#include <cstdint>
#include <cstddef>

// ---------------- helpers ----------------
typedef __attribute__((ext_vector_type(8))) short bf16x8;
typedef __attribute__((ext_vector_type(4))) float f32x4;
typedef __attribute__((ext_vector_type(8))) unsigned short u16x8;

__device__ __forceinline__ unsigned encf(float f) {
  unsigned u = __float_as_uint(f);
  return (u & 0x80000000u) ? ~u : (u | 0x80000000u);
}
__device__ __forceinline__ float decf(unsigned u) {
  return (u & 0x80000000u) ? __uint_as_float(u & 0x7FFFFFFFu) : __uint_as_float(~u);
}
__device__ __forceinline__ float lrelu02(float x) { return x > 0.f ? x : 0.2f * x; }
__device__ __forceinline__ unsigned short f2bf(float f) {
  unsigned u = __float_as_uint(f);
  unsigned r = u + 0x7FFFu + ((u >> 16) & 1u);  // RNE
  return (unsigned short)(r >> 16);
}
__device__ __forceinline__ float bf2f(unsigned short b) {
  return __uint_as_float(((unsigned)b) << 16);
}

__device__ __forceinline__ void gll16(const void* g, void* l) {
  __builtin_amdgcn_global_load_lds(
      (const __attribute__((address_space(1))) void*)g,
      (__attribute__((address_space(3))) void*)l, 16, 0, 0);
}

// ---------------- edge sort (counting sort by dst) ----------------
__global__ void zero_int_k(int* __restrict__ p, int n) {
  int i = blockIdx.x * 256 + threadIdx.x;
  if (i < n) p[i] = 0;
}

__global__ void hist_k(const int* __restrict__ ei, int E, int N, int* __restrict__ counts) {
  int i = blockIdx.x * 256 + threadIdx.x;
  int Eall = E + N;
  if (i >= Eall) return;
  int dst = (i < E) ? ei[E + i] : (i - E);
  atomicAdd(&counts[dst], 1);
}

__global__ __launch_bounds__(256) void scan1_k(const int* __restrict__ counts,
                                               int* __restrict__ incl,
                                               int* __restrict__ bsum, int N) {
  int b = blockIdx.x, tid = threadIdx.x;
  int lane = tid & 63, wv = tid >> 6;
  int i = b * 256 + tid;
  int v = (i < N) ? counts[i] : 0;
#pragma unroll
  for (int o = 1; o < 64; o <<= 1) {
    int t = __shfl_up(v, o, 64);
    if (lane >= o) v += t;
  }
  __shared__ int wsum[4];
  if (lane == 63) wsum[wv] = v;
  __syncthreads();
  int base = 0;
  for (int wj = 0; wj < wv; wj++) base += wsum[wj];
  v += base;
  if (i < N) incl[i] = v;
  if (tid == 255) bsum[b] = v;
}

__global__ __launch_bounds__(256) void scan2_k(const int* __restrict__ bsum,
                                               int* __restrict__ pb, int nb) {
  int tid = threadIdx.x;
  int lane = tid & 63, wv = tid >> 6;
  int v = (tid < nb) ? bsum[tid] : 0;
  int orig = v;
#pragma unroll
  for (int o = 1; o < 64; o <<= 1) {
    int t = __shfl_up(v, o, 64);
    if (lane >= o) v += t;
  }
  __shared__ int wsum[4];
  if (lane == 63) wsum[wv] = v;
  __syncthreads();
  int base = 0;
  for (int wj = 0; wj < wv; wj++) base += wsum[wj];
  if (tid < nb) pb[tid] = v + base - orig;
}

__global__ void scan3_k(const int* __restrict__ incl, const int* __restrict__ pb,
                        int* __restrict__ offs, int* __restrict__ cursor, int N) {
  int i = blockIdx.x * 256 + threadIdx.x;
  if (i == 0) { offs[0] = 0; cursor[0] = 0; }
  if (i < N) {
    int v = incl[i] + pb[i >> 8];
    offs[i + 1] = v;
    if (i + 1 < N) cursor[i + 1] = v;
  }
}

__global__ void scatter_k(const int* __restrict__ ei, int E, int N,
                          int* __restrict__ cursor, int* __restrict__ ssrc) {
  int i = blockIdx.x * 256 + threadIdx.x;
  int Eall = E + N;
  if (i >= Eall) return;
  int src, dst;
  if (i < E) { src = ei[i]; dst = ei[E + i]; }
  else       { src = i - E; dst = i - E; }
  int pos = atomicAdd(&cursor[dst], 1);
  ssrc[pos] = src;
}

// ---------------- bf16 conversion kernels ----------------
__global__ void conv_x_k(const float* __restrict__ x, unsigned short* __restrict__ xb,
                         int N, int Mpad) {
  int i = blockIdx.x * 256 + threadIdx.x;
  int total = Mpad * 64;
  if (i >= total) return;
  int row = i >> 6;
  u16x8 v;
  if (row < N) {
    const float4* src = (const float4*)(x + (size_t)i * 8);
    float4 a = src[0], b = src[1];
    v[0] = f2bf(a.x); v[1] = f2bf(a.y); v[2] = f2bf(a.z); v[3] = f2bf(a.w);
    v[4] = f2bf(b.x); v[5] = f2bf(b.y); v[6] = f2bf(b.z); v[7] = f2bf(b.w);
  } else {
    v = (u16x8)0;
  }
  *(u16x8*)(xb + (size_t)i * 8) = v;
}

__global__ void conv_wt_k(const float* __restrict__ W, unsigned short* __restrict__ Wt,
                          int K, int Nc) {
  int i = blockIdx.x * 256 + threadIdx.x;
  if (i >= K * Nc) return;
  int c = i / K, k = i - c * K;
  Wt[i] = f2bf(W[(size_t)k * Nc + c]);
}

// ---------------- GEMM1: h[M,512] = A[M,512] @ W1t^T, bf16 out, fused dots ----------------
// BM=128, BN=256, BK=64; 256 thr, waves 2x2, wave tile 64x128 (MR=4, NR=8).
// grid (Mpad/128, 2); blockIdx.y covers heads {2y, 2y+1}; wave wc's 128 cols = head 2y+wc.
__global__ __launch_bounds__(256, 2) void gemm1_k(const unsigned short* __restrict__ A,
                                                  const unsigned short* __restrict__ Bt,
                                                  unsigned short* __restrict__ C,
                                                  const float* __restrict__ att_s,
                                                  const float* __restrict__ att_d,
                                                  float* __restrict__ as_out,
                                                  float* __restrict__ ad_out,
                                                  int M, int K, int Nc) {
  __shared__ unsigned short As[128][64];
  __shared__ unsigned short Bs[256][64];
  __shared__ float s_ds[2][128];
  __shared__ float s_dd[2][128];
  const int tid = threadIdx.x;
  const int lane = tid & 63;
  const int w = tid >> 6;
  const int wr = w >> 1, wc = w & 1;
  const int l16 = lane & 15, lk = lane >> 4;
  const int row0 = blockIdx.x * 128, col0 = blockIdx.y * 256;

  f32x4 acc[4][8];
#pragma unroll
  for (int m = 0; m < 4; m++)
#pragma unroll
    for (int n = 0; n < 8; n++) acc[m][n] = (f32x4)0.f;

  const char* Abase = (const char*)A;
  const char* Bbase = (const char*)Bt;

  for (int k0 = 0; k0 < K; k0 += 64) {
#pragma unroll
    for (int i = 0; i < 4; i++) {  // A: 128 rows x 128B = 1024 chunks
      int ca = i * 256 + tid;
      int r = ca >> 3, b = (ca & 7) * 16;
      gll16(Abase + ((size_t)(row0 + r) * K + k0) * 2 + b, (char*)&As[0][0] + ca * 16);
    }
#pragma unroll
    for (int i = 0; i < 8; i++) {  // B: 256 rows
      int cb = i * 256 + tid;
      int c = cb >> 3, b = (cb & 7) * 16;
      gll16(Bbase + ((size_t)(col0 + c) * K + k0) * 2 + b, (char*)&Bs[0][0] + cb * 16);
    }
    __syncthreads();
#pragma unroll
    for (int ks = 0; ks < 2; ks++) {
      bf16x8 af[4], bfr[8];
#pragma unroll
      for (int m = 0; m < 4; m++)
        af[m] = *(const bf16x8*)&As[wr * 64 + m * 16 + l16][ks * 32 + lk * 8];
#pragma unroll
      for (int n = 0; n < 8; n++)
        bfr[n] = *(const bf16x8*)&Bs[wc * 128 + n * 16 + l16][ks * 32 + lk * 8];
#pragma unroll
      for (int m = 0; m < 4; m++)
#pragma unroll
        for (int n = 0; n < 8; n++)
          acc[m][n] = __builtin_amdgcn_mfma_f32_16x16x32_bf16(af[m], bfr[n], acc[m][n], 0, 0, 0);
    }
    __syncthreads();
  }
  // C write (bf16)
#pragma unroll
  for (int m = 0; m < 4; m++) {
    int row_b = row0 + wr * 64 + m * 16 + lk * 4;
#pragma unroll
    for (int r = 0; r < 4; r++) {
      int row = row_b + r;
      if (row < M) {
#pragma unroll
        for (int n = 0; n < 8; n++) {
          int col = col0 + wc * 128 + n * 16 + l16;
          C[(size_t)row * Nc + col] = f2bf(acc[m][n][r]);
        }
      }
    }
  }
  // fused dots: wave wc's 128 cols = full head (2*blockIdx.y + wc)
  float as_c[8], ad_c[8];
#pragma unroll
  for (int n = 0; n < 8; n++) {
    int col = col0 + wc * 128 + n * 16 + l16;
    as_c[n] = att_s[col];
    ad_c[n] = att_d[col];
  }
#pragma unroll
  for (int m = 0; m < 4; m++) {
#pragma unroll
    for (int r = 0; r < 4; r++) {
      float ps = 0.f, pd = 0.f;
#pragma unroll
      for (int n = 0; n < 8; n++) {
        ps += acc[m][n][r] * as_c[n];
        pd += acc[m][n][r] * ad_c[n];
      }
#pragma unroll
      for (int o = 8; o; o >>= 1) { ps += __shfl_xor(ps, o); pd += __shfl_xor(pd, o); }
      if (l16 == 0) {
        int rr = wr * 64 + m * 16 + lk * 4 + r;
        s_ds[wc][rr] = ps;
        s_dd[wc][rr] = pd;
      }
    }
  }
  __syncthreads();
  if (tid < 128) {
    int row = row0 + tid;
    if (row < M) {
      int hb = 2 * blockIdx.y;
      as_out[(size_t)row * 4 + hb + 0] = s_ds[0][tid];
      as_out[(size_t)row * 4 + hb + 1] = s_ds[1][tid];
      ad_out[(size_t)row * 4 + hb + 0] = s_dd[0][tid];
      ad_out[(size_t)row * 4 + hb + 1] = s_dd[1][tid];
    }
  }
}

// ---------------- GEMM2: h2pre[M,64] = h1b[M,512] @ W2t^T, bf16 out, fused dots ----------------
// BM=64, BN=64, BK=64; 256 thr, waves 2x2, wave tile 32x32 (MR=2, NR=2). grid (Mpad/64, 1).
__global__ __launch_bounds__(256) void gemm2_k(const unsigned short* __restrict__ A,
                                               const unsigned short* __restrict__ Bt,
                                               unsigned short* __restrict__ C,
                                               const float* __restrict__ att_s,
                                               const float* __restrict__ att_d,
                                               float* __restrict__ as_out,
                                               float* __restrict__ ad_out,
                                               int M, int K, int Nc) {
  __shared__ unsigned short As[64][64];
  __shared__ unsigned short Bs[64][64];
  __shared__ float s_ds[2][64];
  __shared__ float s_dd[2][64];
  const int tid = threadIdx.x;
  const int lane = tid & 63;
  const int w = tid >> 6;
  const int wr = w >> 1, wc = w & 1;
  const int l16 = lane & 15, lk = lane >> 4;
  const int row0 = blockIdx.x * 64;

  f32x4 acc[2][2];
#pragma unroll
  for (int m = 0; m < 2; m++)
#pragma unroll
    for (int n = 0; n < 2; n++) acc[m][n] = (f32x4)0.f;

  const char* Abase = (const char*)A;
  const char* Bbase = (const char*)Bt;

  for (int k0 = 0; k0 < K; k0 += 64) {
#pragma unroll
    for (int i = 0; i < 2; i++) {
      int ca = i * 256 + tid;
      int r = ca >> 3, b = (ca & 7) * 16;
      gll16(Abase + ((size_t)(row0 + r) * K + k0) * 2 + b, (char*)&As[0][0] + ca * 16);
    }
#pragma unroll
    for (int i = 0; i < 2; i++) {
      int cb = i * 256 + tid;
      int c = cb >> 3, b = (cb & 7) * 16;
      gll16(Bbase + ((size_t)c * K + k0) * 2 + b, (char*)&Bs[0][0] + cb * 16);
    }
    __syncthreads();
#pragma unroll
    for (int ks = 0; ks < 2; ks++) {
      bf16x8 af[2], bfr[2];
#pragma unroll
      for (int m = 0; m < 2; m++)
        af[m] = *(const bf16x8*)&As[wr * 32 + m * 16 + l16][ks * 32 + lk * 8];
#pragma unroll
      for (int n = 0; n < 2; n++)
        bfr[n] = *(const bf16x8*)&Bs[wc * 32 + n * 16 + l16][ks * 32 + lk * 8];
#pragma unroll
      for (int m = 0; m < 2; m++)
#pragma unroll
        for (int n = 0; n < 2; n++)
          acc[m][n] = __builtin_amdgcn_mfma_f32_16x16x32_bf16(af[m], bfr[n], acc[m][n], 0, 0, 0);
    }
    __syncthreads();
  }
#pragma unroll
  for (int m = 0; m < 2; m++) {
    int row_b = row0 + wr * 32 + m * 16 + lk * 4;
#pragma unroll
    for (int r = 0; r < 4; r++) {
      int row = row_b + r;
      if (row < M) {
#pragma unroll
        for (int n = 0; n < 2; n++) {
          int col = wc * 32 + n * 16 + l16;
          C[(size_t)row * Nc + col] = f2bf(acc[m][n][r]);
        }
      }
    }
  }
  // fused dots over all 64 cols (combine the two wc halves)
  float as_c[2], ad_c[2];
#pragma unroll
  for (int n = 0; n < 2; n++) {
    int col = wc * 32 + n * 16 + l16;
    as_c[n] = att_s[col];
    ad_c[n] = att_d[col];
  }
#pragma unroll
  for (int m = 0; m < 2; m++) {
#pragma unroll
    for (int r = 0; r < 4; r++) {
      float ps = 0.f, pd = 0.f;
#pragma unroll
      for (int n = 0; n < 2; n++) {
        ps += acc[m][n][r] * as_c[n];
        pd += acc[m][n][r] * ad_c[n];
      }
#pragma unroll
      for (int o = 8; o; o >>= 1) { ps += __shfl_xor(ps, o); pd += __shfl_xor(pd, o); }
      if (l16 == 0) {
        int rr = wr * 32 + m * 16 + lk * 4 + r;
        s_ds[wc][rr] = ps;
        s_dd[wc][rr] = pd;
      }
    }
  }
  __syncthreads();
  if (tid < 64) {
    int row = row0 + tid;
    if (row < M) {
      as_out[row] = s_ds[0][tid] + s_ds[1][tid];
      ad_out[row] = s_dd[0][tid] + s_dd[1][tid];
    }
  }
}

// ---------------- GAT layer 1 aggregation: wave per dst node, barrier-free ----------------
__global__ __launch_bounds__(256) void gat_agg1_k(const unsigned short* __restrict__ hfeat,
                                                  const float* __restrict__ a_s,
                                                  const float* __restrict__ a_d,
                                                  const int* __restrict__ offs,
                                                  const int* __restrict__ ssrc,
                                                  const float* __restrict__ b1,
                                                  unsigned short* __restrict__ h1b, int N) {
  const int tid = threadIdx.x;
  const int lane = tid & 63, wave = tid >> 6;
  const int n = blockIdx.x * 4 + wave;
  if (n >= N) return;
  __shared__ int   s_src[4][64];
  __shared__ float s_ex[4][64][4];
  const int start = offs[n], end = offs[n + 1];
  const int hhl = lane >> 4;
  const float4 adv4 = *(const float4*)(a_d + (size_t)n * 4);
  const float4* as4 = (const float4*)a_s;

  float m0 = -1e30f, m1 = -1e30f, m2 = -1e30f, m3 = -1e30f;
  float S0 = 0.f, S1 = 0.f, S2 = 0.f, S3 = 0.f;
  float acc[8] = {0.f, 0.f, 0.f, 0.f, 0.f, 0.f, 0.f, 0.f};

  for (int base = start; base < end; base += 64) {
    const int cnt = min(64, end - base);
    float e0 = -1e30f, e1 = -1e30f, e2 = -1e30f, e3 = -1e30f;
    int s = 0;
    if (lane < cnt) {
      s = ssrc[base + lane];
      float4 av = as4[s];
      e0 = lrelu02(av.x + adv4.x);
      e1 = lrelu02(av.y + adv4.y);
      e2 = lrelu02(av.z + adv4.z);
      e3 = lrelu02(av.w + adv4.w);
    }
    float c0 = e0, c1 = e1, c2 = e2, c3 = e3;
#pragma unroll
    for (int o = 32; o; o >>= 1) {
      c0 = fmaxf(c0, __shfl_xor(c0, o));
      c1 = fmaxf(c1, __shfl_xor(c1, o));
      c2 = fmaxf(c2, __shfl_xor(c2, o));
      c3 = fmaxf(c3, __shfl_xor(c3, o));
    }
    float nm0 = fmaxf(m0, c0), nm1 = fmaxf(m1, c1);
    float nm2 = fmaxf(m2, c2), nm3 = fmaxf(m3, c3);
    float sc0 = __expf(m0 - nm0), sc1 = __expf(m1 - nm1);
    float sc2 = __expf(m2 - nm2), sc3 = __expf(m3 - nm3);
    m0 = nm0; m1 = nm1; m2 = nm2; m3 = nm3;
    float x0 = (lane < cnt) ? __expf(e0 - nm0) : 0.f;
    float x1 = (lane < cnt) ? __expf(e1 - nm1) : 0.f;
    float x2 = (lane < cnt) ? __expf(e2 - nm2) : 0.f;
    float x3 = (lane < cnt) ? __expf(e3 - nm3) : 0.f;
    s_src[wave][lane] = s;
    s_ex[wave][lane][0] = x0; s_ex[wave][lane][1] = x1;
    s_ex[wave][lane][2] = x2; s_ex[wave][lane][3] = x3;
#pragma unroll
    for (int o = 32; o; o >>= 1) {
      x0 += __shfl_xor(x0, o); x1 += __shfl_xor(x1, o);
      x2 += __shfl_xor(x2, o); x3 += __shfl_xor(x3, o);
    }
    S0 = S0 * sc0 + x0; S1 = S1 * sc1 + x1;
    S2 = S2 * sc2 + x2; S3 = S3 * sc3 + x3;
    float scl = (hhl == 0) ? sc0 : (hhl == 1) ? sc1 : (hhl == 2) ? sc2 : sc3;
#pragma unroll
    for (int q = 0; q < 8; q++) acc[q] *= scl;
#pragma unroll 4
    for (int j = 0; j < cnt; j++) {
      int sj = s_src[wave][j];
      float al = s_ex[wave][j][hhl];
      uint4 pk = *(const uint4*)(hfeat + ((size_t)sj << 9) + lane * 8);
      acc[0] += al * __uint_as_float(pk.x << 16);
      acc[1] += al * __uint_as_float(pk.x & 0xFFFF0000u);
      acc[2] += al * __uint_as_float(pk.y << 16);
      acc[3] += al * __uint_as_float(pk.y & 0xFFFF0000u);
      acc[4] += al * __uint_as_float(pk.z << 16);
      acc[5] += al * __uint_as_float(pk.z & 0xFFFF0000u);
      acc[6] += al * __uint_as_float(pk.w << 16);
      acc[7] += al * __uint_as_float(pk.w & 0xFFFF0000u);
    }
  }
  float inv = 1.f / (((hhl == 0) ? S0 : (hhl == 1) ? S1 : (hhl == 2) ? S2 : S3) + 1e-16f);
  const float4 b1a = *(const float4*)(b1 + lane * 8);
  const float4 b1b = *(const float4*)(b1 + lane * 8 + 4);
  float v[8];
  v[0] = acc[0] * inv + b1a.x; v[1] = acc[1] * inv + b1a.y;
  v[2] = acc[2] * inv + b1a.z; v[3] = acc[3] * inv + b1a.w;
  v[4] = acc[4] * inv + b1b.x; v[5] = acc[5] * inv + b1b.y;
  v[6] = acc[6] * inv + b1b.z; v[7] = acc[7] * inv + b1b.w;
  u16x8 outv;
#pragma unroll
  for (int q = 0; q < 8; q++) {
    float t = v[q] > 0.f ? v[q] : (__expf(v[q]) - 1.f);
    outv[q] = f2bf(t);
  }
  *(u16x8*)(h1b + ((size_t)n << 9) + lane * 8) = outv;
}

// ---------------- GAT layer 2 aggregation: wave per node, 2 edges per wave ----------------
// h2b bf16 [N,64] rows (128B); half-wave hw handles edges j%2==hw; lane covers feats {2*l32,+1}.
__global__ __launch_bounds__(256) void gat_agg2_k(const unsigned short* __restrict__ h2b,
                                                  const float* __restrict__ a_s,
                                                  const float* __restrict__ a_d,
                                                  const int* __restrict__ offs,
                                                  const int* __restrict__ ssrc,
                                                  const float* __restrict__ b2,
                                                  float* __restrict__ h2out, int N) {
  const int tid = threadIdx.x;
  const int lane = tid & 63, wave = tid >> 6;
  const int n = blockIdx.x * 4 + wave;
  if (n >= N) return;
  __shared__ int   s_src[4][64];
  __shared__ float s_ex[4][64];
  const int start = offs[n], end = offs[n + 1];
  const float ad = a_d[n];
  const int half = lane >> 5, l32 = lane & 31;

  float m = -1e30f, S = 0.f, acc0 = 0.f, acc1 = 0.f;
  for (int base = start; base < end; base += 64) {
    const int cnt = min(64, end - base);
    float e = -1e30f;
    int s = 0;
    if (lane < cnt) {
      s = ssrc[base + lane];
      e = lrelu02(a_s[s] + ad);
    }
    float c = e;
#pragma unroll
    for (int o = 32; o; o >>= 1) c = fmaxf(c, __shfl_xor(c, o));
    float nm = fmaxf(m, c);
    float sc = __expf(m - nm);
    m = nm;
    float x = (lane < cnt) ? __expf(e - nm) : 0.f;
    s_src[wave][lane] = s;
    s_ex[wave][lane] = x;
    float xs = x;
#pragma unroll
    for (int o = 32; o; o >>= 1) xs += __shfl_xor(xs, o);
    S = S * sc + xs;
    acc0 *= sc; acc1 *= sc;
#pragma unroll 4
    for (int j = half; j < cnt; j += 2) {
      int sj = s_src[wave][j];
      float al = s_ex[wave][j];
      unsigned pk = *(const unsigned*)(h2b + ((size_t)sj << 6) + l32 * 2);
      acc0 += al * __uint_as_float(pk << 16);
      acc1 += al * __uint_as_float(pk & 0xFFFF0000u);
    }
  }
  acc0 += __shfl_xor(acc0, 32);
  acc1 += __shfl_xor(acc1, 32);
  if (half == 0) {
    float inv = 1.f / (S + 1e-16f);
    float2 o;
    o.x = acc0 * inv + b2[l32 * 2];
    o.y = acc1 * inv + b2[l32 * 2 + 1];
    *(float2*)(h2out + ((size_t)n << 6) + l32 * 2) = o;
  }
}

// ---------------- intra-attention score ----------------
__global__ __launch_bounds__(256) void score_k(const float* __restrict__ h2,
                                               const float* __restrict__ Wa,
                                               const float* __restrict__ ba,
                                               const float* __restrict__ wv,
                                               const float* __restrict__ bv,
                                               float* __restrict__ scores, int N) {
  int lane = threadIdx.x & 63, wave = threadIdx.x >> 6;
  int n = blockIdx.x * 4 + wave;
  if (n >= N) return;
  float hv = h2[(size_t)n * 64 + lane];
  float t = ba[lane];
  for (int k = 0; k < 64; k++) {
    float hk = __shfl(hv, k);
    t += hk * Wa[k * 64 + lane];
  }
  t = tanhf(t);
  float p = t * wv[lane];
#pragma unroll
  for (int o = 32; o; o >>= 1) p += __shfl_xor(p, o);
  if (lane == 0) scores[n] = p + bv[0];
}

__global__ void red_init_k(unsigned* __restrict__ red) {
  if (threadIdx.x == 0) { red[0] = 0x007FFFFFu; red[1] = 0u; }
}

__global__ void score_max_k(const float* __restrict__ scores, unsigned* __restrict__ red, int N) {
  int i = blockIdx.x * 256 + threadIdx.x;
  float m = (i < N) ? scores[i] : -1e30f;
#pragma unroll
  for (int o = 32; o; o >>= 1) m = fmaxf(m, __shfl_xor(m, o));
  if ((threadIdx.x & 63) == 0) atomicMax(&red[0], encf(m));
}

__global__ void score_sum_k(const float* __restrict__ scores, unsigned* __restrict__ red, int N) {
  float M = decf(red[0]);
  int i = blockIdx.x * 256 + threadIdx.x;
  float s = (i < N) ? __expf(scores[i] - M) : 0.f;
#pragma unroll
  for (int o = 32; o; o >>= 1) s += __shfl_xor(s, o);
  if ((threadIdx.x & 63) == 0) atomicAdd(reinterpret_cast<float*>(red) + 1, s);
}

__global__ void prep_cn_k(const float* __restrict__ ca, float* __restrict__ cn) {
  int lane = threadIdx.x & 63, c = threadIdx.x >> 6;
  float v = ca[c * 64 + lane];
  float p = v * v;
#pragma unroll
  for (int o = 32; o; o >>= 1) p += __shfl_xor(p, o);
  cn[c * 64 + lane] = v / fmaxf(sqrtf(p), 1e-12f);
}

__global__ __launch_bounds__(256) void finalize_k(const float* __restrict__ h2,
                                                  const float* __restrict__ scores,
                                                  const unsigned* __restrict__ red,
                                                  const float* __restrict__ cn,
                                                  const float* __restrict__ Wc,
                                                  const float* __restrict__ bc,
                                                  float* __restrict__ out, int N) {
  int lane = threadIdx.x & 63, wave = threadIdx.x >> 6;
  int n = blockIdx.x * 4 + wave;
  if (n >= N) return;
  float M = decf(red[0]);
  float S = __uint_as_float(red[1]);
  float attw = __expf(scores[n] - M) / S;
  float xw = h2[(size_t)n * 64 + lane] * attw;
  float p = xw * xw;
#pragma unroll
  for (int o = 32; o; o >>= 1) p += __shfl_xor(p, o);
  float xn = xw / fmaxf(sqrtf(p), 1e-12f);
  float i0 = xn * cn[lane],       i1 = xn * cn[64 + lane];
  float i2 = xn * cn[128 + lane], i3 = xn * cn[192 + lane];
  float o0 = xw * Wc[lane * 4 + 0], o1 = xw * Wc[lane * 4 + 1];
  float o2 = xw * Wc[lane * 4 + 2], o3 = xw * Wc[lane * 4 + 3];
#pragma unroll
  for (int o = 32; o; o >>= 1) {
    i0 += __shfl_xor(i0, o); i1 += __shfl_xor(i1, o);
    i2 += __shfl_xor(i2, o); i3 += __shfl_xor(i3, o);
    o0 += __shfl_xor(o0, o); o1 += __shfl_xor(o1, o);
    o2 += __shfl_xor(o2, o); o3 += __shfl_xor(o3, o);
  }
  float* outp   = out;
  float* xwp    = out + (size_t)N * 4;
  float* interp = out + (size_t)N * 68;
  xwp[(size_t)n * 64 + lane] = xw;
  if (lane == 0) {
    outp[n * 4 + 0] = o0 + bc[0]; outp[n * 4 + 1] = o1 + bc[1];
    outp[n * 4 + 2] = o2 + bc[2]; outp[n * 4 + 3] = o3 + bc[3];
    interp[n * 4 + 0] = i0; interp[n * 4 + 1] = i1;
    interp[n * 4 + 2] = i2; interp[n * 4 + 3] = i3;
  }
}

// ---------------- launch ----------------
extern "C" void kernel_launch(void* const* d_in, const int* in_sizes, int n_in,
                              void* d_out, int out_size, void* d_ws, size_t ws_size,
                              hipStream_t stream) {
  const float* x        = (const float*)d_in[0];
  const int*   ei       = (const int*)d_in[1];
  const float* W1       = (const float*)d_in[2];
  const float* att_src1 = (const float*)d_in[3];
  const float* att_dst1 = (const float*)d_in[4];
  const float* b1       = (const float*)d_in[5];
  const float* W2       = (const float*)d_in[6];
  const float* att_src2 = (const float*)d_in[7];
  const float* att_dst2 = (const float*)d_in[8];
  const float* b2       = (const float*)d_in[9];
  const float* Wa       = (const float*)d_in[10];
  const float* ba       = (const float*)d_in[11];
  const float* wv       = (const float*)d_in[12];
  const float* bv       = (const float*)d_in[13];
  const float* class_attn = (const float*)d_in[14];
  const float* Wc       = (const float*)d_in[15];
  const float* bc       = (const float*)d_in[16];

  const int N = in_sizes[0] / 512;
  const int E = in_sizes[1] / 2;
  const int Eall = E + N;
  const int Mpad = ((N + 127) / 128) * 128;
  const int nb = (N + 255) / 256;

  char* w = (char*)d_ws;
  size_t off = 0;
  auto alloc = [&](size_t bytes) -> void* {
    off = (off + 255) & ~((size_t)255);
    void* p = w + off;
    off += bytes;
    return p;
  };
  unsigned short* xb  = (unsigned short*)alloc((size_t)Mpad * 512 * 2);  // xb, later h1b
  unsigned short* h1b = xb;
  unsigned short* hb  = (unsigned short*)alloc((size_t)N * 512 * 2);     // h = x@W1, bf16
  unsigned short* h2b = (unsigned short*)alloc((size_t)N * 64 * 2);      // h2pre bf16
  float* h2     = (float*)alloc((size_t)N * 64 * 4);
  unsigned short* W1t = (unsigned short*)alloc((size_t)512 * 512 * 2);
  unsigned short* W2t = (unsigned short*)alloc((size_t)64 * 512 * 2);
  float* as1    = (float*)alloc((size_t)N * 4 * 4);
  float* ad1    = (float*)alloc((size_t)N * 4 * 4);
  float* as2    = (float*)alloc((size_t)N * 4);
  float* ad2    = (float*)alloc((size_t)N * 4);
  int*   counts = (int*)alloc((size_t)N * 4);
  int*   incl   = (int*)alloc((size_t)N * 4);
  int*   bsum   = (int*)alloc(256 * 4);
  int*   pb     = (int*)alloc(256 * 4);
  int*   offs   = (int*)alloc((size_t)(N + 1) * 4);
  int*   cursor = (int*)alloc((size_t)N * 4);
  int*   ssrc   = (int*)alloc((size_t)Eall * 4);
  float* scores = (float*)alloc((size_t)N * 4);
  unsigned* red = (unsigned*)alloc(64);
  float* cn     = (float*)alloc(256 * 4);

  const int gN256  = (N + 255) / 256;
  const int gE256  = (Eall + 255) / 256;
  const int gNode4 = (N + 3) / 4;

  // --- build CSR ---
  zero_int_k<<<gN256, 256, 0, stream>>>(counts, N);
  hist_k<<<gE256, 256, 0, stream>>>(ei, E, N, counts);
  scan1_k<<<nb, 256, 0, stream>>>(counts, incl, bsum, N);
  scan2_k<<<1, 256, 0, stream>>>(bsum, pb, nb);
  scan3_k<<<gN256, 256, 0, stream>>>(incl, pb, offs, cursor, N);
  scatter_k<<<gE256, 256, 0, stream>>>(ei, E, N, cursor, ssrc);

  // --- bf16 conversions ---
  conv_x_k<<<(Mpad * 64 + 255) / 256, 256, 0, stream>>>(x, xb, N, Mpad);
  conv_wt_k<<<(512 * 512 + 255) / 256, 256, 0, stream>>>(W1, W1t, 512, 512);
  conv_wt_k<<<(64 * 512 + 255) / 256, 256, 0, stream>>>(W2, W2t, 512, 64);

  // --- layer 1 ---
  gemm1_k<<<dim3(Mpad / 128, 2), 256, 0, stream>>>(
      xb, W1t, hb, att_src1, att_dst1, as1, ad1, N, 512, 512);
  gat_agg1_k<<<gNode4, 256, 0, stream>>>(hb, as1, ad1, offs, ssrc, b1, h1b, N);

  // --- layer 2 ---
  gemm2_k<<<dim3(Mpad / 64, 1), 256, 0, stream>>>(
      h1b, W2t, h2b, att_src2, att_dst2, as2, ad2, N, 512, 64);
  gat_agg2_k<<<gNode4, 256, 0, stream>>>(h2b, as2, ad2, offs, ssrc, b2, h2, N);

  // --- intra attention + heads ---
  score_k<<<gNode4, 256, 0, stream>>>(h2, Wa, ba, wv, bv, scores, N);
  red_init_k<<<1, 64, 0, stream>>>(red);
  score_max_k<<<gN256, 256, 0, stream>>>(scores, red, N);
  score_sum_k<<<gN256, 256, 0, stream>>>(scores, red, N);
  prep_cn_k<<<1, 256, 0, stream>>>(class_attn, cn);
  finalize_k<<<gNode4, 256, 0, stream>>>(h2, scores, red, cn, Wc, bc,
                                         (float*)d_out, N);
}

// Round 7
// 432.464 us; speedup vs baseline: 2.3406x; 1.0279x over previous
//
#include <hip/hip_runtime.h>
#include <cstdint>
#include <cstddef>

// ---------------- helpers ----------------
typedef __attribute__((ext_vector_type(8))) short bf16x8;
typedef __attribute__((ext_vector_type(4))) float f32x4;
typedef __attribute__((ext_vector_type(8))) unsigned short u16x8;

__device__ __forceinline__ unsigned encf(float f) {
  unsigned u = __float_as_uint(f);
  return (u & 0x80000000u) ? ~u : (u | 0x80000000u);
}
__device__ __forceinline__ float decf(unsigned u) {
  return (u & 0x80000000u) ? __uint_as_float(u & 0x7FFFFFFFu) : __uint_as_float(~u);
}
__device__ __forceinline__ float lrelu02(float x) { return x > 0.f ? x : 0.2f * x; }
__device__ __forceinline__ unsigned short f2bf(float f) {
  unsigned u = __float_as_uint(f);
  unsigned r = u + 0x7FFFu + ((u >> 16) & 1u);  // RNE
  return (unsigned short)(r >> 16);
}
__device__ __forceinline__ float bf2f(unsigned short b) {
  return __uint_as_float(((unsigned)b) << 16);
}

__device__ __forceinline__ void gll16(const void* g, void* l) {
  __builtin_amdgcn_global_load_lds(
      (const __attribute__((address_space(1))) void*)g,
      (__attribute__((address_space(3))) void*)l, 16, 0, 0);
}

// ---------------- edge sort (counting sort by dst) ----------------
__global__ void hist_k(const int* __restrict__ ei, int E, int N, int* __restrict__ counts) {
  int i = blockIdx.x * 256 + threadIdx.x;
  int Eall = E + N;
  if (i >= Eall) return;
  int dst = (i < E) ? ei[E + i] : (i - E);
  atomicAdd(&counts[dst], 1);
}

__global__ __launch_bounds__(256) void scan1_k(const int* __restrict__ counts,
                                               int* __restrict__ incl,
                                               int* __restrict__ bsum, int N) {
  int b = blockIdx.x, tid = threadIdx.x;
  int lane = tid & 63, wv = tid >> 6;
  int i = b * 256 + tid;
  int v = (i < N) ? counts[i] : 0;
#pragma unroll
  for (int o = 1; o < 64; o <<= 1) {
    int t = __shfl_up(v, o, 64);
    if (lane >= o) v += t;
  }
  __shared__ int wsum[4];
  if (lane == 63) wsum[wv] = v;
  __syncthreads();
  int base = 0;
  for (int wj = 0; wj < wv; wj++) base += wsum[wj];
  v += base;
  if (i < N) incl[i] = v;
  if (tid == 255) bsum[b] = v;
}

__global__ __launch_bounds__(256) void scan2_k(const int* __restrict__ bsum,
                                               int* __restrict__ pb, int nb) {
  int tid = threadIdx.x;
  int lane = tid & 63, wv = tid >> 6;
  int v = (tid < nb) ? bsum[tid] : 0;
  int orig = v;
#pragma unroll
  for (int o = 1; o < 64; o <<= 1) {
    int t = __shfl_up(v, o, 64);
    if (lane >= o) v += t;
  }
  __shared__ int wsum[4];
  if (lane == 63) wsum[wv] = v;
  __syncthreads();
  int base = 0;
  for (int wj = 0; wj < wv; wj++) base += wsum[wj];
  if (tid < nb) pb[tid] = v + base - orig;
}

__global__ void scan3_k(const int* __restrict__ incl, const int* __restrict__ pb,
                        int* __restrict__ offs, int* __restrict__ cursor, int N) {
  int i = blockIdx.x * 256 + threadIdx.x;
  if (i == 0) { offs[0] = 0; cursor[0] = 0; }
  if (i < N) {
    int v = incl[i] + pb[i >> 8];
    offs[i + 1] = v;
    if (i + 1 < N) cursor[i + 1] = v;
  }
}

__global__ void scatter_k(const int* __restrict__ ei, int E, int N,
                          int* __restrict__ cursor, int* __restrict__ ssrc) {
  int i = blockIdx.x * 256 + threadIdx.x;
  int Eall = E + N;
  if (i >= Eall) return;
  int src, dst;
  if (i < E) { src = ei[i]; dst = ei[E + i]; }
  else       { src = i - E; dst = i - E; }
  int pos = atomicAdd(&cursor[dst], 1);
  ssrc[pos] = src;
}

// ---------------- prep: W1t, W2t (transposed bf16), cn (normalized), red init ----------------
__global__ void prep_k(const float* __restrict__ W1, unsigned short* __restrict__ W1t,
                       const float* __restrict__ W2, unsigned short* __restrict__ W2t,
                       const float* __restrict__ ca, float* __restrict__ cn,
                       unsigned* __restrict__ red) {
  const int b = blockIdx.x;
  const int tid = threadIdx.x;
  const int NB1 = 1024;  // 512*512/256
  const int NB2 = 128;   // 64*512/256
  if (b < NB1) {
    int i = b * 256 + tid;
    int c = i >> 9, k = i & 511;
    W1t[i] = f2bf(W1[(size_t)k * 512 + c]);
  } else if (b < NB1 + NB2) {
    int i = (b - NB1) * 256 + tid;
    int c = i >> 9, k = i & 511;
    W2t[i] = f2bf(W2[(size_t)k * 64 + c]);
  } else {
    int lane = tid & 63, c = tid >> 6;
    float v = ca[c * 64 + lane];
    float p = v * v;
#pragma unroll
    for (int o = 32; o; o >>= 1) p += __shfl_xor(p, o);
    cn[c * 64 + lane] = v / fmaxf(sqrtf(p), 1e-12f);
    if (tid == 0) { red[0] = 0x007FFFFFu; red[1] = 0u; }
  }
}

// ---------------- GEMM1: h[M,512] = x_fp32[M,512] @ W1t^T, bf16 out, fused dots ----------------
// BM=128, BN=256, BK=64; 256 thr, waves 2x2, wave tile 64x128 (MR=4, NR=8).
// grid (Mpad/128, 2); wave wc's 128 cols = head 2*blockIdx.y + wc.
// A staged from fp32 via reg-load + f2bf + ds_write (conv_x fused).
__global__ __launch_bounds__(256, 2) void gemm1_k(const float* __restrict__ X,
                                                  const unsigned short* __restrict__ Bt,
                                                  unsigned short* __restrict__ C,
                                                  const float* __restrict__ att_s,
                                                  const float* __restrict__ att_d,
                                                  float* __restrict__ as_out,
                                                  float* __restrict__ ad_out,
                                                  int M, int K, int Nc) {
  __shared__ unsigned short As[128][64];
  __shared__ unsigned short Bs[256][64];
  __shared__ float s_ds[2][128];
  __shared__ float s_dd[2][128];
  const int tid = threadIdx.x;
  const int lane = tid & 63;
  const int w = tid >> 6;
  const int wr = w >> 1, wc = w & 1;
  const int l16 = lane & 15, lk = lane >> 4;
  const int row0 = blockIdx.x * 128, col0 = blockIdx.y * 256;

  f32x4 acc[4][8];
#pragma unroll
  for (int m = 0; m < 4; m++)
#pragma unroll
    for (int n = 0; n < 8; n++) acc[m][n] = (f32x4)0.f;

  const char* Bbase = (const char*)Bt;

  for (int k0 = 0; k0 < K; k0 += 64) {
    // B tile: 256 rows x 128B via global_load_lds
#pragma unroll
    for (int i = 0; i < 8; i++) {
      int cb = i * 256 + tid;
      int c = cb >> 3, b = (cb & 7) * 16;
      gll16(Bbase + ((size_t)(col0 + c) * K + k0) * 2 + b, (char*)&Bs[0][0] + cb * 16);
    }
    // A tile: 128x64 fp32 -> bf16 (fused conversion); 1024 chunks of 8, 4/thread
#pragma unroll
    for (int i = 0; i < 4; i++) {
      int id = i * 256 + tid;
      int r = id >> 3, c = (id & 7) * 8;
      int row = row0 + r;
      if (row >= M) row = M - 1;
      const float* src = X + (size_t)row * K + k0 + c;
      float4 a0 = *(const float4*)src;
      float4 a1 = *(const float4*)(src + 4);
      u16x8 pk;
      pk[0] = f2bf(a0.x); pk[1] = f2bf(a0.y); pk[2] = f2bf(a0.z); pk[3] = f2bf(a0.w);
      pk[4] = f2bf(a1.x); pk[5] = f2bf(a1.y); pk[6] = f2bf(a1.z); pk[7] = f2bf(a1.w);
      *(u16x8*)&As[r][c] = pk;
    }
    __syncthreads();
#pragma unroll
    for (int ks = 0; ks < 2; ks++) {
      bf16x8 af[4], bfr[8];
#pragma unroll
      for (int m = 0; m < 4; m++)
        af[m] = *(const bf16x8*)&As[wr * 64 + m * 16 + l16][ks * 32 + lk * 8];
#pragma unroll
      for (int n = 0; n < 8; n++)
        bfr[n] = *(const bf16x8*)&Bs[wc * 128 + n * 16 + l16][ks * 32 + lk * 8];
#pragma unroll
      for (int m = 0; m < 4; m++)
#pragma unroll
        for (int n = 0; n < 8; n++)
          acc[m][n] = __builtin_amdgcn_mfma_f32_16x16x32_bf16(af[m], bfr[n], acc[m][n], 0, 0, 0);
    }
    __syncthreads();
  }
  // C write (bf16); C/D layout col=lane&15, row=(lane>>4)*4+reg
#pragma unroll
  for (int m = 0; m < 4; m++) {
    int row_b = row0 + wr * 64 + m * 16 + lk * 4;
#pragma unroll
    for (int r = 0; r < 4; r++) {
      int row = row_b + r;
      if (row < M) {
#pragma unroll
        for (int n = 0; n < 8; n++) {
          int col = col0 + wc * 128 + n * 16 + l16;
          C[(size_t)row * Nc + col] = f2bf(acc[m][n][r]);
        }
      }
    }
  }
  // fused dots: wave wc's 128 cols = full head (2*blockIdx.y + wc)
  float as_c[8], ad_c[8];
#pragma unroll
  for (int n = 0; n < 8; n++) {
    int col = col0 + wc * 128 + n * 16 + l16;
    as_c[n] = att_s[col];
    ad_c[n] = att_d[col];
  }
#pragma unroll
  for (int m = 0; m < 4; m++) {
#pragma unroll
    for (int r = 0; r < 4; r++) {
      float ps = 0.f, pd = 0.f;
#pragma unroll
      for (int n = 0; n < 8; n++) {
        ps += acc[m][n][r] * as_c[n];
        pd += acc[m][n][r] * ad_c[n];
      }
#pragma unroll
      for (int o = 8; o; o >>= 1) { ps += __shfl_xor(ps, o); pd += __shfl_xor(pd, o); }
      if (l16 == 0) {
        int rr = wr * 64 + m * 16 + lk * 4 + r;
        s_ds[wc][rr] = ps;
        s_dd[wc][rr] = pd;
      }
    }
  }
  __syncthreads();
  if (tid < 128) {
    int row = row0 + tid;
    if (row < M) {
      int hb = 2 * blockIdx.y;
      as_out[(size_t)row * 4 + hb + 0] = s_ds[0][tid];
      as_out[(size_t)row * 4 + hb + 1] = s_ds[1][tid];
      ad_out[(size_t)row * 4 + hb + 0] = s_dd[0][tid];
      ad_out[(size_t)row * 4 + hb + 1] = s_dd[1][tid];
    }
  }
}

// ---------------- GEMM2: h2pre[M,64] = h1b[M,512] @ W2t^T, bf16 out, fused dots ----------------
__global__ __launch_bounds__(256) void gemm2_k(const unsigned short* __restrict__ A,
                                               const unsigned short* __restrict__ Bt,
                                               unsigned short* __restrict__ C,
                                               const float* __restrict__ att_s,
                                               const float* __restrict__ att_d,
                                               float* __restrict__ as_out,
                                               float* __restrict__ ad_out,
                                               int M, int K, int Nc) {
  __shared__ unsigned short As[64][64];
  __shared__ unsigned short Bs[64][64];
  __shared__ float s_ds[2][64];
  __shared__ float s_dd[2][64];
  const int tid = threadIdx.x;
  const int lane = tid & 63;
  const int w = tid >> 6;
  const int wr = w >> 1, wc = w & 1;
  const int l16 = lane & 15, lk = lane >> 4;
  const int row0 = blockIdx.x * 64;

  f32x4 acc[2][2];
#pragma unroll
  for (int m = 0; m < 2; m++)
#pragma unroll
    for (int n = 0; n < 2; n++) acc[m][n] = (f32x4)0.f;

  const char* Abase = (const char*)A;
  const char* Bbase = (const char*)Bt;

  for (int k0 = 0; k0 < K; k0 += 64) {
#pragma unroll
    for (int i = 0; i < 2; i++) {
      int ca = i * 256 + tid;
      int r = ca >> 3, b = (ca & 7) * 16;
      gll16(Abase + ((size_t)(row0 + r) * K + k0) * 2 + b, (char*)&As[0][0] + ca * 16);
    }
#pragma unroll
    for (int i = 0; i < 2; i++) {
      int cb = i * 256 + tid;
      int c = cb >> 3, b = (cb & 7) * 16;
      gll16(Bbase + ((size_t)c * K + k0) * 2 + b, (char*)&Bs[0][0] + cb * 16);
    }
    __syncthreads();
#pragma unroll
    for (int ks = 0; ks < 2; ks++) {
      bf16x8 af[2], bfr[2];
#pragma unroll
      for (int m = 0; m < 2; m++)
        af[m] = *(const bf16x8*)&As[wr * 32 + m * 16 + l16][ks * 32 + lk * 8];
#pragma unroll
      for (int n = 0; n < 2; n++)
        bfr[n] = *(const bf16x8*)&Bs[wc * 32 + n * 16 + l16][ks * 32 + lk * 8];
#pragma unroll
      for (int m = 0; m < 2; m++)
#pragma unroll
        for (int n = 0; n < 2; n++)
          acc[m][n] = __builtin_amdgcn_mfma_f32_16x16x32_bf16(af[m], bfr[n], acc[m][n], 0, 0, 0);
    }
    __syncthreads();
  }
#pragma unroll
  for (int m = 0; m < 2; m++) {
    int row_b = row0 + wr * 32 + m * 16 + lk * 4;
#pragma unroll
    for (int r = 0; r < 4; r++) {
      int row = row_b + r;
      if (row < M) {
#pragma unroll
        for (int n = 0; n < 2; n++) {
          int col = wc * 32 + n * 16 + l16;
          C[(size_t)row * Nc + col] = f2bf(acc[m][n][r]);
        }
      }
    }
  }
  // fused dots over all 64 cols (combine the two wc halves)
  float as_c[2], ad_c[2];
#pragma unroll
  for (int n = 0; n < 2; n++) {
    int col = wc * 32 + n * 16 + l16;
    as_c[n] = att_s[col];
    ad_c[n] = att_d[col];
  }
#pragma unroll
  for (int m = 0; m < 2; m++) {
#pragma unroll
    for (int r = 0; r < 4; r++) {
      float ps = 0.f, pd = 0.f;
#pragma unroll
      for (int n = 0; n < 2; n++) {
        ps += acc[m][n][r] * as_c[n];
        pd += acc[m][n][r] * ad_c[n];
      }
#pragma unroll
      for (int o = 8; o; o >>= 1) { ps += __shfl_xor(ps, o); pd += __shfl_xor(pd, o); }
      if (l16 == 0) {
        int rr = wr * 32 + m * 16 + lk * 4 + r;
        s_ds[wc][rr] = ps;
        s_dd[wc][rr] = pd;
      }
    }
  }
  __syncthreads();
  if (tid < 64) {
    int row = row0 + tid;
    if (row < M) {
      as_out[row] = s_ds[0][tid] + s_ds[1][tid];
      ad_out[row] = s_dd[0][tid] + s_dd[1][tid];
    }
  }
}

// ---------------- GAT layer 1 aggregation: wave per dst node, barrier-free ----------------
__global__ __launch_bounds__(256) void gat_agg1_k(const unsigned short* __restrict__ hfeat,
                                                  const float* __restrict__ a_s,
                                                  const float* __restrict__ a_d,
                                                  const int* __restrict__ offs,
                                                  const int* __restrict__ ssrc,
                                                  const float* __restrict__ b1,
                                                  unsigned short* __restrict__ h1b, int N) {
  const int tid = threadIdx.x;
  const int lane = tid & 63, wave = tid >> 6;
  const int n = blockIdx.x * 4 + wave;
  if (n >= N) return;
  __shared__ int   s_src[4][64];
  __shared__ float s_ex[4][64][4];
  const int start = offs[n], end = offs[n + 1];
  const int hhl = lane >> 4;
  const float4 adv4 = *(const float4*)(a_d + (size_t)n * 4);
  const float4* as4 = (const float4*)a_s;

  float m0 = -1e30f, m1 = -1e30f, m2 = -1e30f, m3 = -1e30f;
  float S0 = 0.f, S1 = 0.f, S2 = 0.f, S3 = 0.f;
  float acc[8] = {0.f, 0.f, 0.f, 0.f, 0.f, 0.f, 0.f, 0.f};

  for (int base = start; base < end; base += 64) {
    const int cnt = min(64, end - base);
    float e0 = -1e30f, e1 = -1e30f, e2 = -1e30f, e3 = -1e30f;
    int s = 0;
    if (lane < cnt) {
      s = ssrc[base + lane];
      float4 av = as4[s];
      e0 = lrelu02(av.x + adv4.x);
      e1 = lrelu02(av.y + adv4.y);
      e2 = lrelu02(av.z + adv4.z);
      e3 = lrelu02(av.w + adv4.w);
    }
    float c0 = e0, c1 = e1, c2 = e2, c3 = e3;
#pragma unroll
    for (int o = 32; o; o >>= 1) {
      c0 = fmaxf(c0, __shfl_xor(c0, o));
      c1 = fmaxf(c1, __shfl_xor(c1, o));
      c2 = fmaxf(c2, __shfl_xor(c2, o));
      c3 = fmaxf(c3, __shfl_xor(c3, o));
    }
    float nm0 = fmaxf(m0, c0), nm1 = fmaxf(m1, c1);
    float nm2 = fmaxf(m2, c2), nm3 = fmaxf(m3, c3);
    float sc0 = __expf(m0 - nm0), sc1 = __expf(m1 - nm1);
    float sc2 = __expf(m2 - nm2), sc3 = __expf(m3 - nm3);
    m0 = nm0; m1 = nm1; m2 = nm2; m3 = nm3;
    float x0 = (lane < cnt) ? __expf(e0 - nm0) : 0.f;
    float x1 = (lane < cnt) ? __expf(e1 - nm1) : 0.f;
    float x2 = (lane < cnt) ? __expf(e2 - nm2) : 0.f;
    float x3 = (lane < cnt) ? __expf(e3 - nm3) : 0.f;
    s_src[wave][lane] = s;
    s_ex[wave][lane][0] = x0; s_ex[wave][lane][1] = x1;
    s_ex[wave][lane][2] = x2; s_ex[wave][lane][3] = x3;
#pragma unroll
    for (int o = 32; o; o >>= 1) {
      x0 += __shfl_xor(x0, o); x1 += __shfl_xor(x1, o);
      x2 += __shfl_xor(x2, o); x3 += __shfl_xor(x3, o);
    }
    S0 = S0 * sc0 + x0; S1 = S1 * sc1 + x1;
    S2 = S2 * sc2 + x2; S3 = S3 * sc3 + x3;
    float scl = (hhl == 0) ? sc0 : (hhl == 1) ? sc1 : (hhl == 2) ? sc2 : sc3;
#pragma unroll
    for (int q = 0; q < 8; q++) acc[q] *= scl;
    // gather: 8 independent dwordx4 in flight (MLP=8)
#pragma unroll 8
    for (int j = 0; j < cnt; j++) {
      int sj = s_src[wave][j];
      float al = s_ex[wave][j][hhl];
      uint4 pk = *(const uint4*)(hfeat + ((size_t)sj << 9) + lane * 8);
      acc[0] += al * __uint_as_float(pk.x << 16);
      acc[1] += al * __uint_as_float(pk.x & 0xFFFF0000u);
      acc[2] += al * __uint_as_float(pk.y << 16);
      acc[3] += al * __uint_as_float(pk.y & 0xFFFF0000u);
      acc[4] += al * __uint_as_float(pk.z << 16);
      acc[5] += al * __uint_as_float(pk.z & 0xFFFF0000u);
      acc[6] += al * __uint_as_float(pk.w << 16);
      acc[7] += al * __uint_as_float(pk.w & 0xFFFF0000u);
    }
  }
  float inv = 1.f / (((hhl == 0) ? S0 : (hhl == 1) ? S1 : (hhl == 2) ? S2 : S3) + 1e-16f);
  const float4 b1a = *(const float4*)(b1 + lane * 8);
  const float4 b1b = *(const float4*)(b1 + lane * 8 + 4);
  float v[8];
  v[0] = acc[0] * inv + b1a.x; v[1] = acc[1] * inv + b1a.y;
  v[2] = acc[2] * inv + b1a.z; v[3] = acc[3] * inv + b1a.w;
  v[4] = acc[4] * inv + b1b.x; v[5] = acc[5] * inv + b1b.y;
  v[6] = acc[6] * inv + b1b.z; v[7] = acc[7] * inv + b1b.w;
  u16x8 outv;
#pragma unroll
  for (int q = 0; q < 8; q++) {
    float t = v[q] > 0.f ? v[q] : (__expf(v[q]) - 1.f);
    outv[q] = f2bf(t);
  }
  *(u16x8*)(h1b + ((size_t)n << 9) + lane * 8) = outv;
}

// ---------------- GAT layer 2 aggregation + fused intra-attention score ----------------
// h2b bf16 [N,64]; half-wave handles alternating edges; lane covers feats {2*l32, +1}.
// epilogue: scores[n] = tanh(h2 @ Wa + ba) @ wv + bv  (shfl-broadcast matvec, no barrier)
__global__ __launch_bounds__(256) void gat_agg2_k(const unsigned short* __restrict__ h2b,
                                                  const float* __restrict__ a_s,
                                                  const float* __restrict__ a_d,
                                                  const int* __restrict__ offs,
                                                  const int* __restrict__ ssrc,
                                                  const float* __restrict__ b2,
                                                  const float* __restrict__ Wa,
                                                  const float* __restrict__ ba,
                                                  const float* __restrict__ wv,
                                                  const float* __restrict__ bv,
                                                  float* __restrict__ h2out,
                                                  float* __restrict__ scores, int N) {
  const int tid = threadIdx.x;
  const int lane = tid & 63, wave = tid >> 6;
  const int n = blockIdx.x * 4 + wave;
  if (n >= N) return;
  __shared__ int   s_src[4][64];
  __shared__ float s_ex[4][64];
  const int start = offs[n], end = offs[n + 1];
  const float ad = a_d[n];
  const int half = lane >> 5, l32 = lane & 31;

  float m = -1e30f, S = 0.f, acc0 = 0.f, acc1 = 0.f;
  for (int base = start; base < end; base += 64) {
    const int cnt = min(64, end - base);
    float e = -1e30f;
    int s = 0;
    if (lane < cnt) {
      s = ssrc[base + lane];
      e = lrelu02(a_s[s] + ad);
    }
    float c = e;
#pragma unroll
    for (int o = 32; o; o >>= 1) c = fmaxf(c, __shfl_xor(c, o));
    float nm = fmaxf(m, c);
    float sc = __expf(m - nm);
    m = nm;
    float x = (lane < cnt) ? __expf(e - nm) : 0.f;
    s_src[wave][lane] = s;
    s_ex[wave][lane] = x;
    float xs = x;
#pragma unroll
    for (int o = 32; o; o >>= 1) xs += __shfl_xor(xs, o);
    S = S * sc + xs;
    acc0 *= sc; acc1 *= sc;
#pragma unroll 8
    for (int j = half; j < cnt; j += 2) {
      int sj = s_src[wave][j];
      float al = s_ex[wave][j];
      unsigned pk = *(const unsigned*)(h2b + ((size_t)sj << 6) + l32 * 2);
      acc0 += al * __uint_as_float(pk << 16);
      acc1 += al * __uint_as_float(pk & 0xFFFF0000u);
    }
  }
  acc0 += __shfl_xor(acc0, 32);
  acc1 += __shfl_xor(acc1, 32);
  float inv = 1.f / (S + 1e-16f);
  float hx = acc0 * inv + b2[l32 * 2];
  float hy = acc1 * inv + b2[l32 * 2 + 1];
  if (half == 0) {
    float2 o;
    o.x = hx; o.y = hy;
    *(float2*)(h2out + ((size_t)n << 6) + l32 * 2) = o;
  }
  // fused score: t[lane] = ba[lane] + sum_k h2[k]*Wa[k][lane]
  float t = ba[lane];
#pragma unroll 8
  for (int k = 0; k < 32; k++) {
    float a = __shfl(hx, k);
    float b = __shfl(hy, k);
    t += a * Wa[(2 * k) * 64 + lane] + b * Wa[(2 * k + 1) * 64 + lane];
  }
  t = tanhf(t);
  float p = t * wv[lane];
#pragma unroll
  for (int o = 32; o; o >>= 1) p += __shfl_xor(p, o);
  if (lane == 0) scores[n] = p + bv[0];
}

// ---------------- global softmax reductions ----------------
__global__ void score_max_k(const float* __restrict__ scores, unsigned* __restrict__ red, int N) {
  int i = blockIdx.x * 256 + threadIdx.x;
  float m = (i < N) ? scores[i] : -1e30f;
#pragma unroll
  for (int o = 32; o; o >>= 1) m = fmaxf(m, __shfl_xor(m, o));
  if ((threadIdx.x & 63) == 0) atomicMax(&red[0], encf(m));
}

__global__ void score_sum_k(const float* __restrict__ scores, unsigned* __restrict__ red, int N) {
  float M = decf(red[0]);
  int i = blockIdx.x * 256 + threadIdx.x;
  float s = (i < N) ? __expf(scores[i] - M) : 0.f;
#pragma unroll
  for (int o = 32; o; o >>= 1) s += __shfl_xor(s, o);
  if ((threadIdx.x & 63) == 0) atomicAdd(reinterpret_cast<float*>(red) + 1, s);
}

__global__ __launch_bounds__(256) void finalize_k(const float* __restrict__ h2,
                                                  const float* __restrict__ scores,
                                                  const unsigned* __restrict__ red,
                                                  const float* __restrict__ cn,
                                                  const float* __restrict__ Wc,
                                                  const float* __restrict__ bc,
                                                  float* __restrict__ out, int N) {
  int lane = threadIdx.x & 63, wave = threadIdx.x >> 6;
  int n = blockIdx.x * 4 + wave;
  if (n >= N) return;
  float M = decf(red[0]);
  float S = __uint_as_float(red[1]);
  float attw = __expf(scores[n] - M) / S;
  float xw = h2[(size_t)n * 64 + lane] * attw;
  float p = xw * xw;
#pragma unroll
  for (int o = 32; o; o >>= 1) p += __shfl_xor(p, o);
  float xn = xw / fmaxf(sqrtf(p), 1e-12f);
  float i0 = xn * cn[lane],       i1 = xn * cn[64 + lane];
  float i2 = xn * cn[128 + lane], i3 = xn * cn[192 + lane];
  float o0 = xw * Wc[lane * 4 + 0], o1 = xw * Wc[lane * 4 + 1];
  float o2 = xw * Wc[lane * 4 + 2], o3 = xw * Wc[lane * 4 + 3];
#pragma unroll
  for (int o = 32; o; o >>= 1) {
    i0 += __shfl_xor(i0, o); i1 += __shfl_xor(i1, o);
    i2 += __shfl_xor(i2, o); i3 += __shfl_xor(i3, o);
    o0 += __shfl_xor(o0, o); o1 += __shfl_xor(o1, o);
    o2 += __shfl_xor(o2, o); o3 += __shfl_xor(o3, o);
  }
  float* outp   = out;
  float* xwp    = out + (size_t)N * 4;
  float* interp = out + (size_t)N * 68;
  xwp[(size_t)n * 64 + lane] = xw;
  if (lane == 0) {
    outp[n * 4 + 0] = o0 + bc[0]; outp[n * 4 + 1] = o1 + bc[1];
    outp[n * 4 + 2] = o2 + bc[2]; outp[n * 4 + 3] = o3 + bc[3];
    interp[n * 4 + 0] = i0; interp[n * 4 + 1] = i1;
    interp[n * 4 + 2] = i2; interp[n * 4 + 3] = i3;
  }
}

// ---------------- launch ----------------
extern "C" void kernel_launch(void* const* d_in, const int* in_sizes, int n_in,
                              void* d_out, int out_size, void* d_ws, size_t ws_size,
                              hipStream_t stream) {
  const float* x        = (const float*)d_in[0];
  const int*   ei       = (const int*)d_in[1];
  const float* W1       = (const float*)d_in[2];
  const float* att_src1 = (const float*)d_in[3];
  const float* att_dst1 = (const float*)d_in[4];
  const float* b1       = (const float*)d_in[5];
  const float* W2       = (const float*)d_in[6];
  const float* att_src2 = (const float*)d_in[7];
  const float* att_dst2 = (const float*)d_in[8];
  const float* b2       = (const float*)d_in[9];
  const float* Wa       = (const float*)d_in[10];
  const float* ba       = (const float*)d_in[11];
  const float* wv       = (const float*)d_in[12];
  const float* bv       = (const float*)d_in[13];
  const float* class_attn = (const float*)d_in[14];
  const float* Wc       = (const float*)d_in[15];
  const float* bc       = (const float*)d_in[16];

  const int N = in_sizes[0] / 512;
  const int E = in_sizes[1] / 2;
  const int Eall = E + N;
  const int Mpad = ((N + 127) / 128) * 128;
  const int nb = (N + 255) / 256;

  char* w = (char*)d_ws;
  size_t off = 0;
  auto alloc = [&](size_t bytes) -> void* {
    off = (off + 255) & ~((size_t)255);
    void* p = w + off;
    off += bytes;
    return p;
  };
  unsigned short* h1b = (unsigned short*)alloc((size_t)Mpad * 512 * 2);
  unsigned short* hb  = (unsigned short*)alloc((size_t)N * 512 * 2);     // h = x@W1, bf16
  unsigned short* h2b = (unsigned short*)alloc((size_t)N * 64 * 2);      // h2pre bf16
  float* h2     = (float*)alloc((size_t)N * 64 * 4);
  unsigned short* W1t = (unsigned short*)alloc((size_t)512 * 512 * 2);
  unsigned short* W2t = (unsigned short*)alloc((size_t)64 * 512 * 2);
  float* as1    = (float*)alloc((size_t)N * 4 * 4);
  float* ad1    = (float*)alloc((size_t)N * 4 * 4);
  float* as2    = (float*)alloc((size_t)N * 4);
  float* ad2    = (float*)alloc((size_t)N * 4);
  int*   counts = (int*)alloc((size_t)N * 4);
  int*   incl   = (int*)alloc((size_t)N * 4);
  int*   bsum   = (int*)alloc(256 * 4);
  int*   pb     = (int*)alloc(256 * 4);
  int*   offs   = (int*)alloc((size_t)(N + 1) * 4);
  int*   cursor = (int*)alloc((size_t)N * 4);
  int*   ssrc   = (int*)alloc((size_t)Eall * 4);
  float* scores = (float*)alloc((size_t)N * 4);
  unsigned* red = (unsigned*)alloc(64);
  float* cn     = (float*)alloc(256 * 4);

  const int gN256  = (N + 255) / 256;
  const int gE256  = (Eall + 255) / 256;
  const int gNode4 = (N + 3) / 4;

  // --- build CSR ---
  hipMemsetAsync(counts, 0, (size_t)N * 4, stream);
  hist_k<<<gE256, 256, 0, stream>>>(ei, E, N, counts);
  scan1_k<<<nb, 256, 0, stream>>>(counts, incl, bsum, N);
  scan2_k<<<1, 256, 0, stream>>>(bsum, pb, nb);
  scan3_k<<<gN256, 256, 0, stream>>>(incl, pb, offs, cursor, N);
  scatter_k<<<gE256, 256, 0, stream>>>(ei, E, N, cursor, ssrc);

  // --- weight conversions + cn + red init (one fused kernel) ---
  prep_k<<<1024 + 128 + 1, 256, 0, stream>>>(W1, W1t, W2, W2t, class_attn, cn, red);

  // --- layer 1 (conv_x fused into GEMM1's A-staging) ---
  gemm1_k<<<dim3(Mpad / 128, 2), 256, 0, stream>>>(
      x, W1t, hb, att_src1, att_dst1, as1, ad1, N, 512, 512);
  gat_agg1_k<<<gNode4, 256, 0, stream>>>(hb, as1, ad1, offs, ssrc, b1, h1b, N);

  // --- layer 2 ---
  gemm2_k<<<dim3(Mpad / 64, 1), 256, 0, stream>>>(
      h1b, W2t, h2b, att_src2, att_dst2, as2, ad2, N, 512, 64);
  gat_agg2_k<<<gNode4, 256, 0, stream>>>(h2b, as2, ad2, offs, ssrc, b2,
                                         Wa, ba, wv, bv, h2, scores, N);

  // --- global softmax + finalize ---
  score_max_k<<<gN256, 256, 0, stream>>>(scores, red, N);
  score_sum_k<<<gN256, 256, 0, stream>>>(scores, red, N);
  finalize_k<<<gNode4, 256, 0, stream>>>(h2, scores, red, cn, Wc, bc,
                                         (float*)d_out, N);
}

// Round 8
// 424.586 us; speedup vs baseline: 2.3840x; 1.0186x over previous
//
#include <hip/hip_runtime.h>
#include <cstdint>
#include <cstddef>

// ---------------- helpers ----------------
typedef __attribute__((ext_vector_type(8))) short bf16x8;
typedef __attribute__((ext_vector_type(4))) float f32x4;
typedef __attribute__((ext_vector_type(8))) unsigned short u16x8;

__device__ __forceinline__ float lrelu02(float x) { return x > 0.f ? x : 0.2f * x; }
__device__ __forceinline__ unsigned short f2bf(float f) {
  unsigned u = __float_as_uint(f);
  unsigned r = u + 0x7FFFu + ((u >> 16) & 1u);  // RNE
  return (unsigned short)(r >> 16);
}
__device__ __forceinline__ float bf2f(unsigned short b) {
  return __uint_as_float(((unsigned)b) << 16);
}

__device__ __forceinline__ void gll16(const void* g, void* l) {
  __builtin_amdgcn_global_load_lds(
      (const __attribute__((address_space(1))) void*)g,
      (__attribute__((address_space(3))) void*)l, 16, 0, 0);
}

// ---------------- edge sort (counting sort by dst) ----------------
__global__ void hist_k(const int* __restrict__ ei, int E, int N, int* __restrict__ counts) {
  int i = blockIdx.x * 256 + threadIdx.x;
  int Eall = E + N;
  if (i >= Eall) return;
  int dst = (i < E) ? ei[E + i] : (i - E);
  atomicAdd(&counts[dst], 1);
}

__global__ __launch_bounds__(256) void scan1_k(const int* __restrict__ counts,
                                               int* __restrict__ incl,
                                               int* __restrict__ bsum, int N) {
  int b = blockIdx.x, tid = threadIdx.x;
  int lane = tid & 63, wv = tid >> 6;
  int i = b * 256 + tid;
  int v = (i < N) ? counts[i] : 0;
#pragma unroll
  for (int o = 1; o < 64; o <<= 1) {
    int t = __shfl_up(v, o, 64);
    if (lane >= o) v += t;
  }
  __shared__ int wsum[4];
  if (lane == 63) wsum[wv] = v;
  __syncthreads();
  int base = 0;
  for (int wj = 0; wj < wv; wj++) base += wsum[wj];
  v += base;
  if (i < N) incl[i] = v;
  if (tid == 255) bsum[b] = v;
}

__global__ __launch_bounds__(256) void scan2_k(const int* __restrict__ bsum,
                                               int* __restrict__ pb, int nb) {
  int tid = threadIdx.x;
  int lane = tid & 63, wv = tid >> 6;
  int v = (tid < nb) ? bsum[tid] : 0;
  int orig = v;
#pragma unroll
  for (int o = 1; o < 64; o <<= 1) {
    int t = __shfl_up(v, o, 64);
    if (lane >= o) v += t;
  }
  __shared__ int wsum[4];
  if (lane == 63) wsum[wv] = v;
  __syncthreads();
  int base = 0;
  for (int wj = 0; wj < wv; wj++) base += wsum[wj];
  if (tid < nb) pb[tid] = v + base - orig;
}

__global__ void scan3_k(const int* __restrict__ incl, const int* __restrict__ pb,
                        int* __restrict__ offs, int* __restrict__ cursor, int N) {
  int i = blockIdx.x * 256 + threadIdx.x;
  if (i == 0) { offs[0] = 0; cursor[0] = 0; }
  if (i < N) {
    int v = incl[i] + pb[i >> 8];
    offs[i + 1] = v;
    if (i + 1 < N) cursor[i + 1] = v;
  }
}

__global__ void scatter_k(const int* __restrict__ ei, int E, int N,
                          int* __restrict__ cursor, int* __restrict__ ssrc) {
  int i = blockIdx.x * 256 + threadIdx.x;
  int Eall = E + N;
  if (i >= Eall) return;
  int src, dst;
  if (i < E) { src = ei[i]; dst = ei[E + i]; }
  else       { src = i - E; dst = i - E; }
  int pos = atomicAdd(&cursor[dst], 1);
  ssrc[pos] = src;
}

// ---------------- prep: W1t, W2t (transposed bf16), cn (normalized), red init ----------------
__global__ void prep_k(const float* __restrict__ W1, unsigned short* __restrict__ W1t,
                       const float* __restrict__ W2, unsigned short* __restrict__ W2t,
                       const float* __restrict__ ca, float* __restrict__ cn,
                       unsigned* __restrict__ red) {
  const int b = blockIdx.x;
  const int tid = threadIdx.x;
  const int NB1 = 1024;  // 512*512/256
  const int NB2 = 128;   // 64*512/256
  if (b < NB1) {
    int i = b * 256 + tid;
    int c = i >> 9, k = i & 511;
    W1t[i] = f2bf(W1[(size_t)k * 512 + c]);
  } else if (b < NB1 + NB2) {
    int i = (b - NB1) * 256 + tid;
    int c = i >> 9, k = i & 511;
    W2t[i] = f2bf(W2[(size_t)k * 64 + c]);
  } else {
    int lane = tid & 63, c = tid >> 6;
    float v = ca[c * 64 + lane];
    float p = v * v;
#pragma unroll
    for (int o = 32; o; o >>= 1) p += __shfl_xor(p, o);
    cn[c * 64 + lane] = v / fmaxf(sqrtf(p), 1e-12f);
    if (tid == 0) { red[0] = 0u; red[1] = 0u; }
  }
}

// ---------------- GEMM1: h[M,512] = x_fp32[M,512] @ W1t^T, bf16 out, fused dots ----------------
// BM=128, BN=512 (full width, single col-pass), BK=64; 512 thr, 8 waves (2 row x 4 col).
// Wave (wr,wc): rows wr*64..+64, cols wc*128..+128 = exactly head wc. grid (Mpad/128).
// A staged from fp32 via reg-load + f2bf + ds_write (conv fused). LDS = 16+64+4 = 84 KB.
__global__ __launch_bounds__(512, 1) void gemm1_k(const float* __restrict__ X,
                                                  const unsigned short* __restrict__ Bt,
                                                  unsigned short* __restrict__ C,
                                                  const float* __restrict__ att_s,
                                                  const float* __restrict__ att_d,
                                                  float* __restrict__ as_out,
                                                  float* __restrict__ ad_out,
                                                  int M, int K, int Nc) {
  __shared__ unsigned short As[128][64];
  __shared__ unsigned short Bs[512][64];
  __shared__ float s_ds[4][128];
  __shared__ float s_dd[4][128];
  const int tid = threadIdx.x;
  const int lane = tid & 63;
  const int w = tid >> 6;
  const int wr = w >> 2, wc = w & 3;
  const int l16 = lane & 15, lk = lane >> 4;
  const int row0 = blockIdx.x * 128;

  f32x4 acc[4][8];
#pragma unroll
  for (int m = 0; m < 4; m++)
#pragma unroll
    for (int n = 0; n < 8; n++) acc[m][n] = (f32x4)0.f;

  const char* Bbase = (const char*)Bt;

  for (int k0 = 0; k0 < K; k0 += 64) {
    // B tile: 512 rows x 128B = 4096 16B-chunks, 8 per thread
#pragma unroll
    for (int i = 0; i < 8; i++) {
      int cb = i * 512 + tid;
      int c = cb >> 3, b = (cb & 7) * 16;
      gll16(Bbase + ((size_t)c * K + k0) * 2 + b, (char*)&Bs[0][0] + cb * 16);
    }
    // A tile: 128x64 fp32 -> bf16; 1024 octets, 2 per thread
#pragma unroll
    for (int i = 0; i < 2; i++) {
      int id = i * 512 + tid;
      int r = id >> 3, c = (id & 7) * 8;
      int row = row0 + r;
      if (row >= M) row = M - 1;
      const float* src = X + (size_t)row * K + k0 + c;
      float4 a0 = *(const float4*)src;
      float4 a1 = *(const float4*)(src + 4);
      u16x8 pk;
      pk[0] = f2bf(a0.x); pk[1] = f2bf(a0.y); pk[2] = f2bf(a0.z); pk[3] = f2bf(a0.w);
      pk[4] = f2bf(a1.x); pk[5] = f2bf(a1.y); pk[6] = f2bf(a1.z); pk[7] = f2bf(a1.w);
      *(u16x8*)&As[r][c] = pk;
    }
    __syncthreads();
#pragma unroll
    for (int ks = 0; ks < 2; ks++) {
      bf16x8 af[4], bfr[8];
#pragma unroll
      for (int m = 0; m < 4; m++)
        af[m] = *(const bf16x8*)&As[wr * 64 + m * 16 + l16][ks * 32 + lk * 8];
#pragma unroll
      for (int n = 0; n < 8; n++)
        bfr[n] = *(const bf16x8*)&Bs[wc * 128 + n * 16 + l16][ks * 32 + lk * 8];
#pragma unroll
      for (int m = 0; m < 4; m++)
#pragma unroll
        for (int n = 0; n < 8; n++)
          acc[m][n] = __builtin_amdgcn_mfma_f32_16x16x32_bf16(af[m], bfr[n], acc[m][n], 0, 0, 0);
    }
    __syncthreads();
  }
  // C write (bf16); C/D layout col=lane&15, row=(lane>>4)*4+reg
#pragma unroll
  for (int m = 0; m < 4; m++) {
    int row_b = row0 + wr * 64 + m * 16 + lk * 4;
#pragma unroll
    for (int r = 0; r < 4; r++) {
      int row = row_b + r;
      if (row < M) {
#pragma unroll
        for (int n = 0; n < 8; n++) {
          int col = wc * 128 + n * 16 + l16;
          C[(size_t)row * Nc + col] = f2bf(acc[m][n][r]);
        }
      }
    }
  }
  // fused dots: wave wc's 128 cols = full head wc (no cross-wave combine)
  float as_c[8], ad_c[8];
#pragma unroll
  for (int n = 0; n < 8; n++) {
    int col = wc * 128 + n * 16 + l16;
    as_c[n] = att_s[col];
    ad_c[n] = att_d[col];
  }
#pragma unroll
  for (int m = 0; m < 4; m++) {
#pragma unroll
    for (int r = 0; r < 4; r++) {
      float ps = 0.f, pd = 0.f;
#pragma unroll
      for (int n = 0; n < 8; n++) {
        ps += acc[m][n][r] * as_c[n];
        pd += acc[m][n][r] * ad_c[n];
      }
#pragma unroll
      for (int o = 8; o; o >>= 1) { ps += __shfl_xor(ps, o); pd += __shfl_xor(pd, o); }
      if (l16 == 0) {
        int rr = wr * 64 + m * 16 + lk * 4 + r;
        s_ds[wc][rr] = ps;
        s_dd[wc][rr] = pd;
      }
    }
  }
  __syncthreads();
  if (tid < 128) {
    int row = row0 + tid;
    if (row < M) {
#pragma unroll
      for (int h = 0; h < 4; h++) {
        as_out[(size_t)row * 4 + h] = s_ds[h][tid];
        ad_out[(size_t)row * 4 + h] = s_dd[h][tid];
      }
    }
  }
}

// ---------------- GEMM2: h2pre[M,64] = h1b[M,512] @ W2t^T, bf16 out, fused dots ----------------
__global__ __launch_bounds__(256) void gemm2_k(const unsigned short* __restrict__ A,
                                               const unsigned short* __restrict__ Bt,
                                               unsigned short* __restrict__ C,
                                               const float* __restrict__ att_s,
                                               const float* __restrict__ att_d,
                                               float* __restrict__ as_out,
                                               float* __restrict__ ad_out,
                                               int M, int K, int Nc) {
  __shared__ unsigned short As[64][64];
  __shared__ unsigned short Bs[64][64];
  __shared__ float s_ds[2][64];
  __shared__ float s_dd[2][64];
  const int tid = threadIdx.x;
  const int lane = tid & 63;
  const int w = tid >> 6;
  const int wr = w >> 1, wc = w & 1;
  const int l16 = lane & 15, lk = lane >> 4;
  const int row0 = blockIdx.x * 64;

  f32x4 acc[2][2];
#pragma unroll
  for (int m = 0; m < 2; m++)
#pragma unroll
    for (int n = 0; n < 2; n++) acc[m][n] = (f32x4)0.f;

  const char* Abase = (const char*)A;
  const char* Bbase = (const char*)Bt;

  for (int k0 = 0; k0 < K; k0 += 64) {
#pragma unroll
    for (int i = 0; i < 2; i++) {
      int ca = i * 256 + tid;
      int r = ca >> 3, b = (ca & 7) * 16;
      gll16(Abase + ((size_t)(row0 + r) * K + k0) * 2 + b, (char*)&As[0][0] + ca * 16);
    }
#pragma unroll
    for (int i = 0; i < 2; i++) {
      int cb = i * 256 + tid;
      int c = cb >> 3, b = (cb & 7) * 16;
      gll16(Bbase + ((size_t)c * K + k0) * 2 + b, (char*)&Bs[0][0] + cb * 16);
    }
    __syncthreads();
#pragma unroll
    for (int ks = 0; ks < 2; ks++) {
      bf16x8 af[2], bfr[2];
#pragma unroll
      for (int m = 0; m < 2; m++)
        af[m] = *(const bf16x8*)&As[wr * 32 + m * 16 + l16][ks * 32 + lk * 8];
#pragma unroll
      for (int n = 0; n < 2; n++)
        bfr[n] = *(const bf16x8*)&Bs[wc * 32 + n * 16 + l16][ks * 32 + lk * 8];
#pragma unroll
      for (int m = 0; m < 2; m++)
#pragma unroll
        for (int n = 0; n < 2; n++)
          acc[m][n] = __builtin_amdgcn_mfma_f32_16x16x32_bf16(af[m], bfr[n], acc[m][n], 0, 0, 0);
    }
    __syncthreads();
  }
#pragma unroll
  for (int m = 0; m < 2; m++) {
    int row_b = row0 + wr * 32 + m * 16 + lk * 4;
#pragma unroll
    for (int r = 0; r < 4; r++) {
      int row = row_b + r;
      if (row < M) {
#pragma unroll
        for (int n = 0; n < 2; n++) {
          int col = wc * 32 + n * 16 + l16;
          C[(size_t)row * Nc + col] = f2bf(acc[m][n][r]);
        }
      }
    }
  }
  float as_c[2], ad_c[2];
#pragma unroll
  for (int n = 0; n < 2; n++) {
    int col = wc * 32 + n * 16 + l16;
    as_c[n] = att_s[col];
    ad_c[n] = att_d[col];
  }
#pragma unroll
  for (int m = 0; m < 2; m++) {
#pragma unroll
    for (int r = 0; r < 4; r++) {
      float ps = 0.f, pd = 0.f;
#pragma unroll
      for (int n = 0; n < 2; n++) {
        ps += acc[m][n][r] * as_c[n];
        pd += acc[m][n][r] * ad_c[n];
      }
#pragma unroll
      for (int o = 8; o; o >>= 1) { ps += __shfl_xor(ps, o); pd += __shfl_xor(pd, o); }
      if (l16 == 0) {
        int rr = wr * 32 + m * 16 + lk * 4 + r;
        s_ds[wc][rr] = ps;
        s_dd[wc][rr] = pd;
      }
    }
  }
  __syncthreads();
  if (tid < 64) {
    int row = row0 + tid;
    if (row < M) {
      as_out[row] = s_ds[0][tid] + s_ds[1][tid];
      ad_out[row] = s_dd[0][tid] + s_dd[1][tid];
    }
  }
}

// ---------------- GAT layer 1 aggregation: wave per dst node, barrier-free ----------------
__global__ __launch_bounds__(256) void gat_agg1_k(const unsigned short* __restrict__ hfeat,
                                                  const float* __restrict__ a_s,
                                                  const float* __restrict__ a_d,
                                                  const int* __restrict__ offs,
                                                  const int* __restrict__ ssrc,
                                                  const float* __restrict__ b1,
                                                  unsigned short* __restrict__ h1b, int N) {
  const int tid = threadIdx.x;
  const int lane = tid & 63, wave = tid >> 6;
  const int n = blockIdx.x * 4 + wave;
  if (n >= N) return;
  __shared__ int   s_src[4][64];
  __shared__ float s_ex[4][64][4];
  const int start = offs[n], end = offs[n + 1];
  const int hhl = lane >> 4;
  const float4 adv4 = *(const float4*)(a_d + (size_t)n * 4);
  const float4* as4 = (const float4*)a_s;

  float m0 = -1e30f, m1 = -1e30f, m2 = -1e30f, m3 = -1e30f;
  float S0 = 0.f, S1 = 0.f, S2 = 0.f, S3 = 0.f;
  float acc[8] = {0.f, 0.f, 0.f, 0.f, 0.f, 0.f, 0.f, 0.f};

  for (int base = start; base < end; base += 64) {
    const int cnt = min(64, end - base);
    float e0 = -1e30f, e1 = -1e30f, e2 = -1e30f, e3 = -1e30f;
    int s = 0;
    if (lane < cnt) {
      s = ssrc[base + lane];
      float4 av = as4[s];
      e0 = lrelu02(av.x + adv4.x);
      e1 = lrelu02(av.y + adv4.y);
      e2 = lrelu02(av.z + adv4.z);
      e3 = lrelu02(av.w + adv4.w);
    }
    float c0 = e0, c1 = e1, c2 = e2, c3 = e3;
#pragma unroll
    for (int o = 32; o; o >>= 1) {
      c0 = fmaxf(c0, __shfl_xor(c0, o));
      c1 = fmaxf(c1, __shfl_xor(c1, o));
      c2 = fmaxf(c2, __shfl_xor(c2, o));
      c3 = fmaxf(c3, __shfl_xor(c3, o));
    }
    float nm0 = fmaxf(m0, c0), nm1 = fmaxf(m1, c1);
    float nm2 = fmaxf(m2, c2), nm3 = fmaxf(m3, c3);
    float sc0 = __expf(m0 - nm0), sc1 = __expf(m1 - nm1);
    float sc2 = __expf(m2 - nm2), sc3 = __expf(m3 - nm3);
    m0 = nm0; m1 = nm1; m2 = nm2; m3 = nm3;
    float x0 = (lane < cnt) ? __expf(e0 - nm0) : 0.f;
    float x1 = (lane < cnt) ? __expf(e1 - nm1) : 0.f;
    float x2 = (lane < cnt) ? __expf(e2 - nm2) : 0.f;
    float x3 = (lane < cnt) ? __expf(e3 - nm3) : 0.f;
    s_src[wave][lane] = s;
    s_ex[wave][lane][0] = x0; s_ex[wave][lane][1] = x1;
    s_ex[wave][lane][2] = x2; s_ex[wave][lane][3] = x3;
#pragma unroll
    for (int o = 32; o; o >>= 1) {
      x0 += __shfl_xor(x0, o); x1 += __shfl_xor(x1, o);
      x2 += __shfl_xor(x2, o); x3 += __shfl_xor(x3, o);
    }
    S0 = S0 * sc0 + x0; S1 = S1 * sc1 + x1;
    S2 = S2 * sc2 + x2; S3 = S3 * sc3 + x3;
    float scl = (hhl == 0) ? sc0 : (hhl == 1) ? sc1 : (hhl == 2) ? sc2 : sc3;
#pragma unroll
    for (int q = 0; q < 8; q++) acc[q] *= scl;
#pragma unroll 4
    for (int j = 0; j < cnt; j++) {
      int sj = s_src[wave][j];
      float al = s_ex[wave][j][hhl];
      uint4 pk = *(const uint4*)(hfeat + ((size_t)sj << 9) + lane * 8);
      acc[0] += al * __uint_as_float(pk.x << 16);
      acc[1] += al * __uint_as_float(pk.x & 0xFFFF0000u);
      acc[2] += al * __uint_as_float(pk.y << 16);
      acc[3] += al * __uint_as_float(pk.y & 0xFFFF0000u);
      acc[4] += al * __uint_as_float(pk.z << 16);
      acc[5] += al * __uint_as_float(pk.z & 0xFFFF0000u);
      acc[6] += al * __uint_as_float(pk.w << 16);
      acc[7] += al * __uint_as_float(pk.w & 0xFFFF0000u);
    }
  }
  float inv = 1.f / (((hhl == 0) ? S0 : (hhl == 1) ? S1 : (hhl == 2) ? S2 : S3) + 1e-16f);
  const float4 b1a = *(const float4*)(b1 + lane * 8);
  const float4 b1b = *(const float4*)(b1 + lane * 8 + 4);
  float v[8];
  v[0] = acc[0] * inv + b1a.x; v[1] = acc[1] * inv + b1a.y;
  v[2] = acc[2] * inv + b1a.z; v[3] = acc[3] * inv + b1a.w;
  v[4] = acc[4] * inv + b1b.x; v[5] = acc[5] * inv + b1b.y;
  v[6] = acc[6] * inv + b1b.z; v[7] = acc[7] * inv + b1b.w;
  u16x8 outv;
#pragma unroll
  for (int q = 0; q < 8; q++) {
    float t = v[q] > 0.f ? v[q] : (__expf(v[q]) - 1.f);
    outv[q] = f2bf(t);
  }
  // nontemporal: don't displace the h-table in L2 with this 51 MB stream
  __builtin_nontemporal_store(outv, (u16x8*)(h1b + ((size_t)n << 9) + lane * 8));
}

// ---------------- GAT layer 2 aggregation + fused intra-attention score ----------------
__global__ __launch_bounds__(256) void gat_agg2_k(const unsigned short* __restrict__ h2b,
                                                  const float* __restrict__ a_s,
                                                  const float* __restrict__ a_d,
                                                  const int* __restrict__ offs,
                                                  const int* __restrict__ ssrc,
                                                  const float* __restrict__ b2,
                                                  const float* __restrict__ Wa,
                                                  const float* __restrict__ ba,
                                                  const float* __restrict__ wv,
                                                  const float* __restrict__ bv,
                                                  float* __restrict__ h2out,
                                                  float* __restrict__ scores, int N) {
  const int tid = threadIdx.x;
  const int lane = tid & 63, wave = tid >> 6;
  const int n = blockIdx.x * 4 + wave;
  if (n >= N) return;
  __shared__ int   s_src[4][64];
  __shared__ float s_ex[4][64];
  const int start = offs[n], end = offs[n + 1];
  const float ad = a_d[n];
  const int half = lane >> 5, l32 = lane & 31;

  float m = -1e30f, S = 0.f, acc0 = 0.f, acc1 = 0.f;
  for (int base = start; base < end; base += 64) {
    const int cnt = min(64, end - base);
    float e = -1e30f;
    int s = 0;
    if (lane < cnt) {
      s = ssrc[base + lane];
      e = lrelu02(a_s[s] + ad);
    }
    float c = e;
#pragma unroll
    for (int o = 32; o; o >>= 1) c = fmaxf(c, __shfl_xor(c, o));
    float nm = fmaxf(m, c);
    float sc = __expf(m - nm);
    m = nm;
    float x = (lane < cnt) ? __expf(e - nm) : 0.f;
    s_src[wave][lane] = s;
    s_ex[wave][lane] = x;
    float xs = x;
#pragma unroll
    for (int o = 32; o; o >>= 1) xs += __shfl_xor(xs, o);
    S = S * sc + xs;
    acc0 *= sc; acc1 *= sc;
#pragma unroll 8
    for (int j = half; j < cnt; j += 2) {
      int sj = s_src[wave][j];
      float al = s_ex[wave][j];
      unsigned pk = *(const unsigned*)(h2b + ((size_t)sj << 6) + l32 * 2);
      acc0 += al * __uint_as_float(pk << 16);
      acc1 += al * __uint_as_float(pk & 0xFFFF0000u);
    }
  }
  acc0 += __shfl_xor(acc0, 32);
  acc1 += __shfl_xor(acc1, 32);
  float inv = 1.f / (S + 1e-16f);
  float hx = acc0 * inv + b2[l32 * 2];
  float hy = acc1 * inv + b2[l32 * 2 + 1];
  if (half == 0) {
    float2 o;
    o.x = hx; o.y = hy;
    *(float2*)(h2out + ((size_t)n << 6) + l32 * 2) = o;
  }
  // fused score: t[lane] = ba[lane] + sum_k h2[k]*Wa[k][lane]
  float t = ba[lane];
#pragma unroll 8
  for (int k = 0; k < 32; k++) {
    float a = __shfl(hx, k);
    float b = __shfl(hy, k);
    t += a * Wa[(2 * k) * 64 + lane] + b * Wa[(2 * k + 1) * 64 + lane];
  }
  t = tanhf(t);
  float p = t * wv[lane];
#pragma unroll
  for (int o = 32; o; o >>= 1) p += __shfl_xor(p, o);
  if (lane == 0) scores[n] = p + bv[0];
}

// ---------------- global softmax sum (scores are tanh-bounded: no max-shift needed) ----------------
__global__ void score_sum_k(const float* __restrict__ scores, unsigned* __restrict__ red, int N) {
  int i = blockIdx.x * 256 + threadIdx.x;
  float s = (i < N) ? __expf(scores[i]) : 0.f;
#pragma unroll
  for (int o = 32; o; o >>= 1) s += __shfl_xor(s, o);
  if ((threadIdx.x & 63) == 0) atomicAdd(reinterpret_cast<float*>(red) + 1, s);
}

__global__ __launch_bounds__(256) void finalize_k(const float* __restrict__ h2,
                                                  const float* __restrict__ scores,
                                                  const unsigned* __restrict__ red,
                                                  const float* __restrict__ cn,
                                                  const float* __restrict__ Wc,
                                                  const float* __restrict__ bc,
                                                  float* __restrict__ out, int N) {
  int lane = threadIdx.x & 63, wave = threadIdx.x >> 6;
  int n = blockIdx.x * 4 + wave;
  if (n >= N) return;
  float S = __uint_as_float(red[1]);
  float attw = __expf(scores[n]) / S;
  float xw = h2[(size_t)n * 64 + lane] * attw;
  float p = xw * xw;
#pragma unroll
  for (int o = 32; o; o >>= 1) p += __shfl_xor(p, o);
  float xn = xw / fmaxf(sqrtf(p), 1e-12f);
  float i0 = xn * cn[lane],       i1 = xn * cn[64 + lane];
  float i2 = xn * cn[128 + lane], i3 = xn * cn[192 + lane];
  float o0 = xw * Wc[lane * 4 + 0], o1 = xw * Wc[lane * 4 + 1];
  float o2 = xw * Wc[lane * 4 + 2], o3 = xw * Wc[lane * 4 + 3];
#pragma unroll
  for (int o = 32; o; o >>= 1) {
    i0 += __shfl_xor(i0, o); i1 += __shfl_xor(i1, o);
    i2 += __shfl_xor(i2, o); i3 += __shfl_xor(i3, o);
    o0 += __shfl_xor(o0, o); o1 += __shfl_xor(o1, o);
    o2 += __shfl_xor(o2, o); o3 += __shfl_xor(o3, o);
  }
  float* outp   = out;
  float* xwp    = out + (size_t)N * 4;
  float* interp = out + (size_t)N * 68;
  xwp[(size_t)n * 64 + lane] = xw;
  if (lane == 0) {
    outp[n * 4 + 0] = o0 + bc[0]; outp[n * 4 + 1] = o1 + bc[1];
    outp[n * 4 + 2] = o2 + bc[2]; outp[n * 4 + 3] = o3 + bc[3];
    interp[n * 4 + 0] = i0; interp[n * 4 + 1] = i1;
    interp[n * 4 + 2] = i2; interp[n * 4 + 3] = i3;
  }
}

// ---------------- launch ----------------
extern "C" void kernel_launch(void* const* d_in, const int* in_sizes, int n_in,
                              void* d_out, int out_size, void* d_ws, size_t ws_size,
                              hipStream_t stream) {
  const float* x        = (const float*)d_in[0];
  const int*   ei       = (const int*)d_in[1];
  const float* W1       = (const float*)d_in[2];
  const float* att_src1 = (const float*)d_in[3];
  const float* att_dst1 = (const float*)d_in[4];
  const float* b1       = (const float*)d_in[5];
  const float* W2       = (const float*)d_in[6];
  const float* att_src2 = (const float*)d_in[7];
  const float* att_dst2 = (const float*)d_in[8];
  const float* b2       = (const float*)d_in[9];
  const float* Wa       = (const float*)d_in[10];
  const float* ba       = (const float*)d_in[11];
  const float* wv       = (const float*)d_in[12];
  const float* bv       = (const float*)d_in[13];
  const float* class_attn = (const float*)d_in[14];
  const float* Wc       = (const float*)d_in[15];
  const float* bc       = (const float*)d_in[16];

  const int N = in_sizes[0] / 512;
  const int E = in_sizes[1] / 2;
  const int Eall = E + N;
  const int Mpad = ((N + 127) / 128) * 128;
  const int nb = (N + 255) / 256;

  char* w = (char*)d_ws;
  size_t off = 0;
  auto alloc = [&](size_t bytes) -> void* {
    off = (off + 255) & ~((size_t)255);
    void* p = w + off;
    off += bytes;
    return p;
  };
  unsigned short* h1b = (unsigned short*)alloc((size_t)Mpad * 512 * 2);
  unsigned short* hb  = (unsigned short*)alloc((size_t)N * 512 * 2);     // h = x@W1, bf16
  unsigned short* h2b = (unsigned short*)alloc((size_t)N * 64 * 2);      // h2pre bf16
  float* h2     = (float*)alloc((size_t)N * 64 * 4);
  unsigned short* W1t = (unsigned short*)alloc((size_t)512 * 512 * 2);
  unsigned short* W2t = (unsigned short*)alloc((size_t)64 * 512 * 2);
  float* as1    = (float*)alloc((size_t)N * 4 * 4);
  float* ad1    = (float*)alloc((size_t)N * 4 * 4);
  float* as2    = (float*)alloc((size_t)N * 4);
  float* ad2    = (float*)alloc((size_t)N * 4);
  int*   counts = (int*)alloc((size_t)N * 4);
  int*   incl   = (int*)alloc((size_t)N * 4);
  int*   bsum   = (int*)alloc(256 * 4);
  int*   pb     = (int*)alloc(256 * 4);
  int*   offs   = (int*)alloc((size_t)(N + 1) * 4);
  int*   cursor = (int*)alloc((size_t)N * 4);
  int*   ssrc   = (int*)alloc((size_t)Eall * 4);
  float* scores = (float*)alloc((size_t)N * 4);
  unsigned* red = (unsigned*)alloc(64);
  float* cn     = (float*)alloc(256 * 4);

  const int gN256  = (N + 255) / 256;
  const int gE256  = (Eall + 255) / 256;
  const int gNode4 = (N + 3) / 4;

  // --- build CSR ---
  hipMemsetAsync(counts, 0, (size_t)N * 4, stream);
  hist_k<<<gE256, 256, 0, stream>>>(ei, E, N, counts);
  scan1_k<<<nb, 256, 0, stream>>>(counts, incl, bsum, N);
  scan2_k<<<1, 256, 0, stream>>>(bsum, pb, nb);
  scan3_k<<<gN256, 256, 0, stream>>>(incl, pb, offs, cursor, N);
  scatter_k<<<gE256, 256, 0, stream>>>(ei, E, N, cursor, ssrc);

  // --- weight conversions + cn + red init (one fused kernel) ---
  prep_k<<<1024 + 128 + 1, 256, 0, stream>>>(W1, W1t, W2, W2t, class_attn, cn, red);

  // --- layer 1 (single col-pass GEMM, conv fused into A-staging) ---
  gemm1_k<<<Mpad / 128, 512, 0, stream>>>(
      x, W1t, hb, att_src1, att_dst1, as1, ad1, N, 512, 512);
  gat_agg1_k<<<gNode4, 256, 0, stream>>>(hb, as1, ad1, offs, ssrc, b1, h1b, N);

  // --- layer 2 ---
  gemm2_k<<<dim3(Mpad / 64, 1), 256, 0, stream>>>(
      h1b, W2t, h2b, att_src2, att_dst2, as2, ad2, N, 512, 64);
  gat_agg2_k<<<gNode4, 256, 0, stream>>>(h2b, as2, ad2, offs, ssrc, b2,
                                         Wa, ba, wv, bv, h2, scores, N);

  // --- global softmax + finalize ---
  score_sum_k<<<gN256, 256, 0, stream>>>(scores, red, N);
  finalize_k<<<gNode4, 256, 0, stream>>>(h2, scores, red, cn, Wc, bc,
                                         (float*)d_out, N);
}